// Round 11
// baseline (1585.045 us; speedup 1.0000x reference)
//
#include <hip/hip_runtime.h>

#define NW    10000
#define INDIM 300
#define SZ    256
#define BB    16
#define LL    128
#define NLEM  3000
#define FH    1024   // 4*SZ
#define NCAP  8192

typedef short  bf16x8 __attribute__((ext_vector_type(8)));
typedef float  f32x4  __attribute__((ext_vector_type(4)));

__device__ __forceinline__ float sigf(float x){
  return __builtin_amdgcn_rcpf(1.f+__builtin_amdgcn_exp2f(-1.442695041f*x));
}
__device__ __forceinline__ float tanhf_(float x){
  return fmaf(-2.f, __builtin_amdgcn_rcpf(1.f+__builtin_amdgcn_exp2f(2.885390082f*x)), 1.f);
}
__device__ __forceinline__ short f2b(float f){
  unsigned u=__float_as_uint(f); u += 0x7FFFu + ((u>>16)&1u); return (short)(u>>16);
}
__device__ __forceinline__ int pack2(float a, float b){
  return ((int)(unsigned short)f2b(a)) | (((int)(unsigned short)f2b(b))<<16);
}
#define B2F(s) __uint_as_float(((unsigned)(unsigned short)(s))<<16)
#define MFA(a,b,c) __builtin_amdgcn_mfma_f32_16x16x32_bf16(a,b,c,0,0,0)

// ---------------- we = relu(emb @ Wp + bp) : [10000,300]@[300,256] ----------
__global__ void k_we(const float* __restrict__ emb, const float* __restrict__ Wp,
                     const float* __restrict__ bp, float* __restrict__ we){
  __shared__ __align__(16) float As[16][INDIM];
  int r0 = blockIdx.x*16, tid = threadIdx.x;
  for(int i=tid;i<16*INDIM;i+=256){int lr=i/INDIM,d=i-lr*INDIM;
    As[lr][d]=emb[(long)(r0+lr)*INDIM+d];}
  __syncthreads();
  int cl=tid&63, rg=tid>>6;
  float acc[4][4];
  #pragma unroll
  for(int i=0;i<4;i++){acc[i][0]=acc[i][1]=acc[i][2]=acc[i][3]=0.f;}
  for(int k=0;k<INDIM;k+=4){
    float4 a4[4];
    #pragma unroll
    for(int i=0;i<4;i++) a4[i]=*(const float4*)&As[rg*4+i][k];
    #pragma unroll
    for(int j=0;j<4;j++){
      const float* wr=Wp+(long)(k+j)*SZ+cl;
      float w0=wr[0],w1=wr[64],w2=wr[128],w3=wr[192];
      #pragma unroll
      for(int i=0;i<4;i++){
        float a=(j==0)?a4[i].x:(j==1)?a4[i].y:(j==2)?a4[i].z:a4[i].w;
        acc[i][0]=fmaf(a,w0,acc[i][0]);acc[i][1]=fmaf(a,w1,acc[i][1]);
        acc[i][2]=fmaf(a,w2,acc[i][2]);acc[i][3]=fmaf(a,w3,acc[i][3]);
      }
    }
  }
  #pragma unroll
  for(int i=0;i<4;i++){
    int r=r0+rg*4+i;
    #pragma unroll
    for(int cc=0;cc<4;cc++){int col=cl+cc*64;
      we[(long)r*SZ+col]=fmaxf(acc[i][cc]+bp[col],0.f);}
  }
}

// ---- prep: Wh -> bf16 MFMA B-fragments, (dir,w,T2=s*4+g,ks,lane) tiling ----
__global__ void k_prep(const float* __restrict__ Wh_f, const float* __restrict__ Wh_b,
                       short* __restrict__ frag){
  int tid = blockIdx.x*256 + threadIdx.x;   // 65536 total
  int l=tid&63, f=(tid>>6)&63, w=(tid>>12)&7, dir=tid>>15;
  const float* Wh = dir? Wh_b : Wh_f;
  int ks=f&7, T2=f>>3, s2=T2>>2, g=T2&3;
  int col = g*256 + w*32 + s2*16 + (l&15);
  int k0  = ks*32 + (l>>4)*8;
  short v[8];
  #pragma unroll
  for(int j=0;j<8;j++) v[j]=f2b(Wh[(long)(k0+j)*FH + col]);
  *(bf16x8*)(frag + (long)tid*8) = *(bf16x8*)v;
}

// ---- prep: Wi -> bf16 B-frags: wf[((dir*64+ct)*8+ks)*512 + l*8 + j] --------
__global__ void k_prepwi(const float* __restrict__ Wi_f, const float* __restrict__ Wi_b,
                         short* __restrict__ wf){
  int tid = blockIdx.x*256 + threadIdx.x;   // 65536
  int l=tid&63, ks=(tid>>6)&7, ct=(tid>>9)&63, dir=tid>>15;
  const float* Wi = dir? Wi_b : Wi_f;
  int col = ct*16 + (l&15);
  int k0  = ks*32 + (l>>4)*8;
  short v[8];
  #pragma unroll
  for(int j=0;j<8;j++) v[j]=f2b(Wi[(long)(k0+j)*FH + col]);
  *(bf16x8*)(wf + (long)tid*8) = *(bf16x8*)v;
}

// ---- prep: Wenc -> bf16 B-frags: wef[(ct*16+ks)*512 + l*8 + j], K=512 ------
__global__ void k_prepenc(const float* __restrict__ Wenc, short* __restrict__ wef){
  int tid = blockIdx.x*256 + threadIdx.x;   // 16384
  int l=tid&63, ks=(tid>>6)&15, ct=tid>>10;
  int col = ct*16 + (l&15);
  int k0  = ks*32 + (l>>4)*8;
  short v[8];
  #pragma unroll
  for(int j=0;j<8;j++) v[j]=f2b(Wenc[(long)(k0+j)*SZ + col]);
  *(bf16x8*)(wef + (long)tid*8) = *(bf16x8*)v;
}

// ---- MFMA xwi: [64 rows]@[256x1024] bf16, epilogue writes LSTM frag layout -
__global__ void k_xwi_mfma(const int* __restrict__ seq, const int* __restrict__ len,
                      const float* __restrict__ srcw, long bstride,
                      const float* __restrict__ ctxtT, const int* __restrict__ idxmap,
                      const float* __restrict__ Wi_f, const float* __restrict__ bvf,
                      const float* __restrict__ Wi_b, const float* __restrict__ bvb,
                      const short* __restrict__ wf, int iseq, short* __restrict__ xwo){
  __shared__ __align__(16) short As[64*264];
  __shared__ const float* rowp[64];
  int bx=blockIdx.x, dir=bx>>5, blk=bx&31, tid=threadIdx.x;
  int w=tid>>6, l=tid&63;
  if(tid<64){
    int t = blk*4 + (tid>>4), b = tid&15;
    int lb=len[b];
    int tt=(dir==0)? t : ((t<lb)? (lb-1-t) : t);
    int tok=seq[b*LL+tt];
    const float* rp;
    if(idxmap){
      int im=idxmap[b*NW+tok];
      rp = (im>=0)? ctxtT+(long)im*SZ : srcw+(long)tok*SZ;
    }else{
      rp = srcw + (long)b*bstride + (long)tok*SZ;
    }
    rowp[tid]=rp;
  }
  __syncthreads();
  for(int i2=tid;i2<64*64;i2+=256){
    int lr=i2>>6, c4=(i2&63)*4;
    float4 v=*(const float4*)(rowp[lr]+c4);
    int2 pk; pk.x=pack2(v.x,v.y); pk.y=pack2(v.z,v.w);
    *(int2*)&As[lr*264+c4]=pk;
  }
  __syncthreads();
  const float* __restrict__ Wi = dir? Wi_b : Wi_f;
  const float* __restrict__ bv = dir? bvb : bvf;
  const short* wfd = wf + (long)dir*262144;
  for(int n2=0;n2<16;n2++){
    int ct = w*16 + n2;
    const short* bfp = wfd + ((long)ct*8)*512 + l*8;
    f32x4 Z={0.f,0.f,0.f,0.f};
    f32x4 C0=Z,C1=Z,C2=Z,C3=Z;
    #pragma unroll
    for(int ks=0;ks<8;ks++){
      bf16x8 bb=*(const bf16x8*)(bfp + ks*512);
      int ao = ks*32 + (l>>4)*8;
      bf16x8 a0=*(const bf16x8*)(&As[((l&15)    )*264 + ao]);
      bf16x8 a1=*(const bf16x8*)(&As[((l&15)+16 )*264 + ao]);
      bf16x8 a2=*(const bf16x8*)(&As[((l&15)+32 )*264 + ao]);
      bf16x8 a3=*(const bf16x8*)(&As[((l&15)+48 )*264 + ao]);
      C0=MFA(a0,bb,C0); C1=MFA(a1,bb,C1); C2=MFA(a2,bb,C2); C3=MFA(a3,bb,C3);
    }
    int g=ct>>4, w2=(ct&15)>>1, s2=ct&1;
    int col = g*256 + w2*32 + s2*16 + (l&15);
    float be = Wi[(long)(SZ+iseq)*FH+col] + bv[col];
    #pragma unroll
    for(int m=0;m<4;m++){
      f32x4 Cm = (m==0)?C0:(m==1)?C1:(m==2)?C2:C3;
      long base=((((long)dir*128 + blk*4 + m)*8 + w2)*64 + (l>>4)*16 + (l&15))*32
                + s2*16 + g*4;
      int2 pk; pk.x=pack2(Cm[0]+be,Cm[1]+be); pk.y=pack2(Cm[2]+be,Cm[3]+be);
      *(int2*)(xwo+base)=pk;
    }
  }
}

// --------- single-CU-per-dir persistent LSTM: 512 thr, 8 waves, 2/SIMD ------
#define LDFW(f)    (*(const bf16x8*)(fr + (long)(f)*512 + l*8))
#define LDLW(i2,ks) (*(const bf16x8*)(bl + ((i2)*8+(ks))*512 + l*8))
#define DECLWT(T) bf16x8 W##T##_0=LDFW((T)*8+0),W##T##_1=LDFW((T)*8+1),W##T##_2=LDFW((T)*8+2),W##T##_3=LDFW((T)*8+3),W##T##_4=LDFW((T)*8+4),W##T##_5=LDFW((T)*8+5),W##T##_6=LDFW((T)*8+6),W##T##_7=LDFW((T)*8+7);
#define MMRT(T,Cv) { Cv=MFA(A0,W##T##_0,Cv); Cv=MFA(A1,W##T##_1,Cv); Cv=MFA(A2,W##T##_2,Cv); Cv=MFA(A3,W##T##_3,Cv); Cv=MFA(A4,W##T##_4,Cv); Cv=MFA(A5,W##T##_5,Cv); Cv=MFA(A6,W##T##_6,Cv); Cv=MFA(A7,W##T##_7,Cv); }
#define MMLT(i2,Cv) { Cv=MFA(A0,LDLW(i2,0),Cv); Cv=MFA(A1,LDLW(i2,1),Cv); Cv=MFA(A2,LDLW(i2,2),Cv); Cv=MFA(A3,LDLW(i2,3),Cv); Cv=MFA(A4,LDLW(i2,4),Cv); Cv=MFA(A5,LDLW(i2,5),Cv); Cv=MFA(A6,LDLW(i2,6),Cv); Cv=MFA(A7,LDLW(i2,7),Cv); }
#define MMST(Cv) { Cv=MFA(A0,S0,Cv); Cv=MFA(A1,S1,Cv); Cv=MFA(A2,S2,Cv); Cv=MFA(A3,S3,Cv); Cv=MFA(A4,S4,Cv); Cv=MFA(A5,S5,Cv); Cv=MFA(A6,S6,Cv); Cv=MFA(A7,S7,Cv); }
#define LOADST(f0) S0=LDFW((f0)+0); S1=LDFW((f0)+1); S2=LDFW((f0)+2); S3=LDFW((f0)+3); S4=LDFW((f0)+4); S5=LDFW((f0)+5); S6=LDFW((f0)+6); S7=LDFW((f0)+7);
#define G1(s,r,CA,CB,CC,CD,XA,XB) { \
  float zi=CA[r]+B2F(XA[r]), zf=CB[r]+B2F(XA[4+(r)]), zg=CC[r]+B2F(XB[r]), zo=CD[r]+B2F(XB[4+(r)]); \
  cst_##s##_##r = sigf(zf)*cst_##s##_##r + sigf(zi)*tanhf_(zg); \
  float hv = sigf(zo)*tanhf_(cst_##s##_##r); \
  int b_=4*(l>>4)+(r); int u_=w*32+(s)*16+(l&15); \
  hbn[b_*264+u_]=f2b(hv); }
#define GP(s,CA,CB,CC,CD,XA,XB) \
  G1(s,0,CA,CB,CC,CD,XA,XB) G1(s,1,CA,CB,CC,CD,XA,XB) \
  G1(s,2,CA,CB,CC,CD,XA,XB) G1(s,3,CA,CB,CC,CD,XA,XB)

extern __shared__ char smem_raw[];

__global__ __launch_bounds__(512,2) void k_lstm_w8(
    const short* __restrict__ frag, const short* __restrict__ xq,
    short* __restrict__ hgs){
  const int dir=blockIdx.x, tid=threadIdx.x, w=tid>>6, l=tid&63;
  short* hb=(short*)smem_raw;                      // 2 x 16 x 264 shorts
  short* bl=(short*)(smem_raw+16896)+w*8192;       // per-wave LDS frags T2=4,5
  const short* fr = frag + (long)(dir*8+w)*32768;  // 64 frags * 512
  for(int i=tid;i<4224;i+=512) ((int*)smem_raw)[i]=0;
  #pragma unroll
  for(int c2=0;c2<16;c2++)
    *(f32x4*)(bl+c2*512+l*8) = *(const f32x4*)(fr+(long)(32+c2)*512+l*8);
  DECLWT(0) DECLWT(1) DECLWT(2) DECLWT(3)          // 32 resident frags
  float cst_0_0=0,cst_0_1=0,cst_0_2=0,cst_0_3=0,
        cst_1_0=0,cst_1_1=0,cst_1_2=0,cst_1_3=0;
  __syncthreads();
  const short* xwb = xq + ((long)dir*128*8 + w)*2048 + (long)l*32;
  short* hgb = hgs + (long)dir*524288;             // bf16 h-out [t][16][256]
  const int db=tid>>5, du=(tid&31)*8;              // dump coords
  bf16x8 S0,S1,S2,S3,S4,S5,S6,S7;
  for(int t=0;t<LL;t++){
    const int cur=t&1, nxt=cur^1;
    LOADST(48)                                     // stream T2=6 (early issue)
    const short* xp = xwb + (long)t*16384;
    bf16x8 X0=*(const bf16x8*)(xp+0), X1=*(const bf16x8*)(xp+8);
    const short* hr = hb + cur*4224 + (l&15)*264 + (l>>4)*8;
    bf16x8 A0=*(const bf16x8*)(hr+0),   A1=*(const bf16x8*)(hr+32),
           A2=*(const bf16x8*)(hr+64),  A3=*(const bf16x8*)(hr+96),
           A4=*(const bf16x8*)(hr+128), A5=*(const bf16x8*)(hr+160),
           A6=*(const bf16x8*)(hr+192), A7=*(const bf16x8*)(hr+224);
    f32x4 Z={0.f,0.f,0.f,0.f};
    f32x4 C00=Z,C01=Z,C02=Z,C03=Z,C10=Z,C11=Z,C12=Z,C13=Z;
    __builtin_amdgcn_s_setprio(1);
    MMRT(0,C00) MMRT(1,C01) MMRT(2,C02) MMRT(3,C03)   // resident (32 MFMA)
    MMLT(0,C10) MMLT(1,C11)                           // LDS tiles (16 MFMA)
    MMST(C12)                                         // T2=6 streamed
    __builtin_amdgcn_s_setprio(0);
    LOADST(56)                                        // stream T2=7 (issue)
    bf16x8 X2=*(const bf16x8*)(xp+16), X3=*(const bf16x8*)(xp+24);
    short* hbn = hb + nxt*4224;
    GP(0, C00,C01,C02,C03, X0,X1)                     // hides T2=7 latency
    __builtin_amdgcn_s_setprio(1);
    MMST(C13)                                         // T2=7 streamed
    __builtin_amdgcn_s_setprio(0);
    GP(1, C10,C11,C12,C13, X2,X3)
    __syncthreads();
    // coalesced bf16 h dump; store retires during next step (no drain stall)
    f32x4 hv4 = *(const f32x4*)(hbn + db*264 + du);
    *(f32x4*)(hgb + ((long)t*16 + db)*256 + du) = hv4;
  }
}

// ---- MFMA enc: [64 rows][K=512] @ Wenc frags -> relu(max) atomic scatter ---
__global__ void k_enc_mfma(const int* __restrict__ seq, const int* __restrict__ len,
                      const int* __restrict__ u2l, const short* __restrict__ hgs,
                      const short* __restrict__ wef, const float* __restrict__ benc,
                      unsigned int* __restrict__ lembuf, unsigned int* __restrict__ flags){
  __shared__ __align__(16) short As[64*520];
  __shared__ const short* pf16[64]; __shared__ const short* pb16[64];
  __shared__ int lem_s[64], val_s[64], b_s[64];
  int r0=blockIdx.x*64, tid=threadIdx.x, w=tid>>6, l=tid&63;
  if(tid<64){
    int r=r0+tid, b=r>>7, t=r&127, lb=len[b];
    int v=(t<lb); val_s[tid]=v; b_s[tid]=b;
    int lem=u2l[seq[r]]; lem_s[tid]=lem;
    pf16[tid]=hgs+((long)t*BB+b)*SZ;
    int tr=v? (lb-1-t) : t;
    pb16[tid]=hgs+((long)(LL+tr)*BB+b)*SZ;
    if(v) flags[(long)b*NLEM+lem]=1u;
  }
  __syncthreads();
  for(int i2=tid;i2<64*128;i2+=256){
    int lr=i2>>7, cc=(i2&127)*4;
    const short* sp=(cc<256)? pf16[lr]+cc : pb16[lr]+(cc-256);
    *(int2*)&As[lr*520+cc]=*(const int2*)sp;
  }
  __syncthreads();
  for(int n2=0;n2<4;n2++){
    int ct=w*4+n2;
    f32x4 Z={0.f,0.f,0.f,0.f};
    f32x4 C0=Z,C1=Z,C2=Z,C3=Z;
    #pragma unroll
    for(int ks=0;ks<16;ks++){
      bf16x8 bb=*(const bf16x8*)(wef+((long)(ct*16+ks))*512+l*8);
      int ao=ks*32+(l>>4)*8;
      bf16x8 a0=*(const bf16x8*)(&As[((l&15)    )*520+ao]);
      bf16x8 a1=*(const bf16x8*)(&As[((l&15)+16 )*520+ao]);
      bf16x8 a2=*(const bf16x8*)(&As[((l&15)+32 )*520+ao]);
      bf16x8 a3=*(const bf16x8*)(&As[((l&15)+48 )*520+ao]);
      C0=MFA(a0,bb,C0); C1=MFA(a1,bb,C1); C2=MFA(a2,bb,C2); C3=MFA(a3,bb,C3);
    }
    int col=ct*16+(l&15);
    float be=benc[col];
    #pragma unroll
    for(int m=0;m<4;m++){
      f32x4 Cm=(m==0)?C0:(m==1)?C1:(m==2)?C2:C3;
      #pragma unroll
      for(int reg=0;reg<4;reg++){
        int row=m*16+(l>>4)*4+reg;
        if(val_s[row]){
          float e=fmaxf(Cm[reg]+be,0.f);
          atomicMax(&lembuf[((long)b_s[row]*NLEM+lem_s[row])*SZ+col], __float_as_uint(e));
        }
      }
    }
  }
}

// ------------ generic C[r] = A[r] @ W  (K=256), optional touched-flags ------
__global__ void k_rowgemm(const float* __restrict__ A, const float* __restrict__ W,
                          float* __restrict__ C, const unsigned int* __restrict__ flags){
  __shared__ __align__(16) float As[16][SZ];
  __shared__ int any_s;
  int r0=blockIdx.x*16, tid=threadIdx.x;
  if(tid==0){
    int a = flags? 0 : 1;
    if(flags){ for(int i=0;i<16;i++) a |= (int)flags[r0+i]; }
    any_s=a;
  }
  __syncthreads();
  if(!any_s) return;
  for(int i=tid;i<16*SZ;i+=256){int lr=i>>8,j=i&(SZ-1);As[lr][j]=A[(long)(r0+lr)*SZ+j];}
  __syncthreads();
  int cl=tid&63, rg=tid>>6;
  float acc[4][4];
  #pragma unroll
  for(int i=0;i<4;i++){acc[i][0]=acc[i][1]=acc[i][2]=acc[i][3]=0.f;}
  for(int k=0;k<SZ;k+=4){
    float4 a4[4];
    #pragma unroll
    for(int i=0;i<4;i++) a4[i]=*(const float4*)&As[rg*4+i][k];
    #pragma unroll
    for(int j=0;j<4;j++){
      const float* wr=W+(long)(k+j)*SZ+cl;
      float w0=wr[0],w1=wr[64],w2=wr[128],w3=wr[192];
      #pragma unroll
      for(int i=0;i<4;i++){
        float a=(j==0)?a4[i].x:(j==1)?a4[i].y:(j==2)?a4[i].z:a4[i].w;
        acc[i][0]=fmaf(a,w0,acc[i][0]);acc[i][1]=fmaf(a,w1,acc[i][1]);
        acc[i][2]=fmaf(a,w2,acc[i][2]);acc[i][3]=fmaf(a,w3,acc[i][3]);
      }
    }
  }
  #pragma unroll
  for(int i=0;i<4;i++){
    int r=r0+rg*4+i;
    #pragma unroll
    for(int cc=0;cc<4;cc++) C[(long)r*SZ+cl+cc*64]=acc[i][cc];
  }
}

// ------------ rowgemm over *cnt rows (compacted): C[i] = A[i] @ W -----------
__global__ void k_rowgemm_n(const float* __restrict__ A, const float* __restrict__ W,
                            float* __restrict__ C, const int* __restrict__ cnt, int ncap){
  __shared__ __align__(16) float As[16][SZ];
  int n=*cnt; if(n>ncap)n=ncap;
  int r0=blockIdx.x*16, tid=threadIdx.x;
  if(r0>=n) return;
  for(int i=tid;i<16*SZ;i+=256){int lr=i>>8,j=i&(SZ-1);
    As[lr][j]= (r0+lr<n)? A[(long)(r0+lr)*SZ+j] : 0.f;}
  __syncthreads();
  int cl=tid&63, rg=tid>>6;
  float acc[4][4];
  #pragma unroll
  for(int i=0;i<4;i++){acc[i][0]=acc[i][1]=acc[i][2]=acc[i][3]=0.f;}
  for(int k=0;k<SZ;k+=4){
    float4 a4[4];
    #pragma unroll
    for(int i=0;i<4;i++) a4[i]=*(const float4*)&As[rg*4+i][k];
    #pragma unroll
    for(int j=0;j<4;j++){
      const float* wr=W+(long)(k+j)*SZ+cl;
      float w0=wr[0],w1=wr[64],w2=wr[128],w3=wr[192];
      #pragma unroll
      for(int i=0;i<4;i++){
        float a=(j==0)?a4[i].x:(j==1)?a4[i].y:(j==2)?a4[i].z:a4[i].w;
        acc[i][0]=fmaf(a,w0,acc[i][0]);acc[i][1]=fmaf(a,w1,acc[i][1]);
        acc[i][2]=fmaf(a,w2,acc[i][2]);acc[i][3]=fmaf(a,w3,acc[i][3]);
      }
    }
  }
  #pragma unroll
  for(int i=0;i<4;i++){
    int r=r0+rg*4+i;
    if(r<n){
      #pragma unroll
      for(int cc=0;cc<4;cc++) C[(long)r*SZ+cl+cc*64]=acc[i][cc];
    }
  }
}

// ---- compact list of rows whose lemma was touched in iter 0 ----------------
__global__ void k_compact(const int* __restrict__ u2l, const unsigned int* __restrict__ flags,
                          int* __restrict__ cnt, int* __restrict__ list,
                          int* __restrict__ idxmap, int ncap){
  int r = blockIdx.x*256+threadIdx.x;
  if(r>=BB*NW) return;
  int b=r/NW, w=r-b*NW;
  int im=-1;
  if(flags[(long)b*NLEM+u2l[w]]){
    int idx=atomicAdd(cnt,1);
    if(idx<ncap){ list[idx]=r; im=idx; }
  }
  idxmap[r]=im;
}

// ---- gate for touched-only rows -> compact ctxtT ---------------------------
__global__ void k_gate0c(const float* __restrict__ we, const float* __restrict__ P0,
                         const float* __restrict__ Q, const float* __restrict__ lembuf,
                         const int* __restrict__ u2l, const float* __restrict__ bg,
                         const int* __restrict__ cnt, const int* __restrict__ list,
                         float* __restrict__ ctxtT, int ncap){
  int n=*cnt; if(n>ncap)n=ncap;
  long idx=(long)blockIdx.x*256+threadIdx.x;
  long i=idx>>6; int k4=(int)(idx&63);
  if(i>=n) return;
  int r=list[i]; int b=r/NW, w=r-b*NW;
  int lem=u2l[w];
  long qb=((long)b*NLEM+lem)*SZ;
  float4 p =((const float4*)(P0+(long)w*SZ))[k4];
  float4 wv=((const float4*)(we+(long)w*SZ))[k4];
  float4 bgv=((const float4*)bg)[k4];
  float4 q =((const float4*)(Q+qb))[k4];
  float4 nw=((const float4*)(lembuf+qb))[k4];
  float4 o;
  { float g=sigf(p.x+q.x+bgv.x); o.x=wv.x*g+(1.f-g)*nw.x; }
  { float g=sigf(p.y+q.y+bgv.y); o.y=wv.y*g+(1.f-g)*nw.y; }
  { float g=sigf(p.z+q.z+bgv.z); o.z=wv.z*g+(1.f-g)*nw.z; }
  { float g=sigf(p.w+q.w+bgv.w); o.w=wv.w*g+(1.f-g)*nw.w; }
  ((float4*)ctxtT)[i*64+k4]=o;
}

// ---- we <- we*sig(P0+bg)  (base0 in place; run after gate0c) ---------------
__global__ void k_base0ip(float* __restrict__ we, const float* __restrict__ P0,
                          const float* __restrict__ bg){
  long idx=(long)blockIdx.x*256+threadIdx.x;
  if(idx>=(long)NW*SZ/4) return;
  int k4=(int)(idx&63);
  float4 wv=((float4*)we)[idx];
  float4 p =((const float4*)P0)[idx];
  float4 bgv=((const float4*)bg)[k4];
  wv.x*=sigf(p.x+bgv.x); wv.y*=sigf(p.y+bgv.y);
  wv.z*=sigf(p.z+bgv.z); wv.w*=sigf(p.w+bgv.w);
  ((float4*)we)[idx]=wv;
}

// ------- iter-0 gate DENSE (fallback): full out write -----------------------
__global__ void k_gate0(const float* __restrict__ we, const float* __restrict__ P0,
                        const float* __restrict__ Q, const float* __restrict__ lembuf,
                        const int* __restrict__ u2l, const unsigned int* __restrict__ flags,
                        const float* __restrict__ bg, float* __restrict__ out){
  long idx=(long)blockIdx.x*256+threadIdx.x;
  const long TOTAL4=(long)BB*NW*SZ/4;
  if(idx>=TOTAL4) return;
  long row=idx>>6; int k4=(int)(idx&63);
  int r32=(int)row;
  int b=r32/NW, w=r32-b*NW;
  int lem=u2l[w];
  long qb=((long)b*NLEM+lem)*SZ;
  unsigned int fl=flags[(long)b*NLEM+lem];
  float4 p =((const float4*)(P0+(long)w*SZ))[k4];
  float4 wv=((const float4*)(we+(long)w*SZ))[k4];
  float4 bgv=((const float4*)bg)[k4];
  float4 q, nw;
  if(fl){ q=((const float4*)(Q+qb))[k4]; nw=((const float4*)(lembuf+qb))[k4]; }
  else  { q=make_float4(0.f,0.f,0.f,0.f); nw=q; }
  float4 o;
  { float g=sigf(p.x+q.x+bgv.x); o.x=wv.x*g+(1.f-g)*nw.x; }
  { float g=sigf(p.y+q.y+bgv.y); o.y=wv.y*g+(1.f-g)*nw.y; }
  { float g=sigf(p.z+q.z+bgv.z); o.z=wv.z*g+(1.f-g)*nw.z; }
  { float g=sigf(p.w+q.w+bgv.w); o.w=wv.w*g+(1.f-g)*nw.w; }
  ((float4*)out)[idx]=o;
}

// ------- iter-1 gate: cv from base0/ctxtT, p from P1b/Pt, write final out ---
__global__ void k_gate1e(const float* __restrict__ base0, const float* __restrict__ ctxtT,
                         const float* __restrict__ P1b, const float* __restrict__ Pt,
                         const int* __restrict__ idxmap,
                         const float* __restrict__ Q, const float* __restrict__ lembuf,
                         const int* __restrict__ u2l, const unsigned int* __restrict__ flags,
                         const float* __restrict__ bg, float* __restrict__ out){
  long idx=(long)blockIdx.x*256+threadIdx.x;
  const long TOTAL4=(long)BB*NW*SZ/4;
  if(idx>=TOTAL4) return;
  long row=idx>>6; int k4=(int)(idx&63);
  int r32=(int)row;
  int b=r32/NW, w=r32-b*NW;
  int im=idxmap[r32];
  int lem=u2l[w];
  long qb=((long)b*NLEM+lem)*SZ;
  unsigned int fl=flags[(long)b*NLEM+lem];
  float4 p, cv;
  if(im>=0){ p=((const float4*)(Pt+(long)im*SZ))[k4]; cv=((const float4*)(ctxtT+(long)im*SZ))[k4]; }
  else     { p=((const float4*)(P1b+(long)w*SZ))[k4]; cv=((const float4*)(base0+(long)w*SZ))[k4]; }
  float4 bgv=((const float4*)bg)[k4];
  float4 q, nw;
  if(fl){ q=((const float4*)(Q+qb))[k4]; nw=((const float4*)(lembuf+qb))[k4]; }
  else  { q=make_float4(0.f,0.f,0.f,0.f); nw=q; }
  float4 o;
  { float g=sigf(p.x+q.x+bgv.x); o.x=cv.x*g+(1.f-g)*nw.x; }
  { float g=sigf(p.y+q.y+bgv.y); o.y=cv.y*g+(1.f-g)*nw.y; }
  { float g=sigf(p.z+q.z+bgv.z); o.z=cv.z*g+(1.f-g)*nw.z; }
  { float g=sigf(p.w+q.w+bgv.w); o.w=cv.w*g+(1.f-g)*nw.w; }
  ((float4*)out)[idx]=o;
}

// ------- legacy dense iter-1 gate (fallback if ws too small) ----------------
__global__ void k_gate1(const float* __restrict__ ctxt, const float* __restrict__ Wg,
                        const float* __restrict__ Q, const float* __restrict__ lembuf,
                        const int* __restrict__ u2l, const unsigned int* __restrict__ flags,
                        const float* __restrict__ bg, float* __restrict__ out){
  __shared__ __align__(16) float As[64][SZ];
  __shared__ __align__(16) float Ws[64][SZ];
  __shared__ int lem_s[64];
  int r0=blockIdx.x*64, tid=threadIdx.x;
  for(int i=tid;i<64*SZ;i+=256){int lr=i>>8,j=i&(SZ-1);
    As[lr][j]=ctxt[(long)(r0+lr)*SZ+j];}
  if(tid<64){int r=r0+tid; lem_s[tid]=u2l[r%NW];}
  int cl=tid&63, rg=tid>>6;
  float acc[16][4];
  #pragma unroll
  for(int i=0;i<16;i++){acc[i][0]=acc[i][1]=acc[i][2]=acc[i][3]=0.f;}
  for(int kb=0;kb<4;kb++){
    __syncthreads();
    for(int i=tid;i<64*SZ;i+=256){int lr=i>>8,j=i&(SZ-1);
      Ws[lr][j]=Wg[(long)(kb*64+lr)*SZ+j];}
    __syncthreads();
    for(int k=0;k<64;k+=4){
      float4 a4[16];
      #pragma unroll
      for(int i=0;i<16;i++) a4[i]=*(const float4*)&As[rg*16+i][kb*64+k];
      #pragma unroll
      for(int j=0;j<4;j++){
        float w0=Ws[k+j][cl],w1=Ws[k+j][cl+64],w2=Ws[k+j][cl+128],w3=Ws[k+j][cl+192];
        #pragma unroll
        for(int i=0;i<16;i++){
          float a=(j==0)?a4[i].x:(j==1)?a4[i].y:(j==2)?a4[i].z:a4[i].w;
          acc[i][0]=fmaf(a,w0,acc[i][0]);acc[i][1]=fmaf(a,w1,acc[i][1]);
          acc[i][2]=fmaf(a,w2,acc[i][2]);acc[i][3]=fmaf(a,w3,acc[i][3]);
        }
      }
    }
  }
  #pragma unroll
  for(int i=0;i<16;i++){
    int lr=rg*16+i, r=r0+lr, b=r/NW;
    long base=((long)b*NLEM+lem_s[lr])*SZ;
    unsigned int fl=flags[(long)b*NLEM+lem_s[lr]];
    #pragma unroll
    for(int cc=0;cc<4;cc++){
      int col=cl+cc*64;
      float qv=0.f, nw=0.f;
      if(fl){ qv=Q[base+col]; nw=lembuf[base+col]; }
      float g=sigf(acc[i][cc]+qv+bg[col]);
      out[(long)r*SZ+col]=As[lr][col]*g+(1.f-g)*nw;
    }
  }
}

extern "C" void kernel_launch(void* const* d_in, const int* in_sizes, int n_in,
                              void* d_out, int out_size, void* d_ws, size_t ws_size,
                              hipStream_t stream){
  const float* emb  =(const float*)d_in[0];
  const float* Wp   =(const float*)d_in[1];
  const float* bp   =(const float*)d_in[2];
  const float* Wi_f =(const float*)d_in[3];
  const float* Wh_f =(const float*)d_in[4];
  const float* b_f  =(const float*)d_in[5];
  const float* Wi_b =(const float*)d_in[6];
  const float* Wh_b =(const float*)d_in[7];
  const float* b_b  =(const float*)d_in[8];
  const float* Wenc =(const float*)d_in[9];
  const float* benc =(const float*)d_in[10];
  const float* Wg   =(const float*)d_in[11];
  const float* bg   =(const float*)d_in[12];
  const int*   seq0 =(const int*)d_in[13];
  const int*   seq1 =(const int*)d_in[14];
  const int*   len0 =(const int*)d_in[15];
  const int*   len1 =(const int*)d_in[16];
  const int*   u2l  =(const int*)d_in[17];

  float* ws    = (float*)d_ws;
  float* we    = ws;                       // 2,560,000 (becomes base0 after iter0)
  float* xwi   = we    + 2560000;          // region 4,194,304 floats:
  float* ctxtT = xwi   + 2097152;          //   xq bf16 first half; ctxtT second
  float* hglob = xwi   + 4194304;          // 1,048,576 (bf16 h uses half)
  float* lembuf= hglob + 1048576;          // 12,288,000
  float* flags = lembuf+ 12288000;         // 48,000 (uint)
  float* Q     = flags + 48000;            // 12,288,000
  float* P0    = Q     + 12288000;         // 2,560,000 (becomes P1b after iter0)
  short* whb   = (short*)(P0 + 2560000);   // 524,288 shorts = 262,144 floats
  short* wifrag= whb + 524288;             // 524,288 shorts = 262,144 floats
  short* wefrag= wifrag + 524288;          // 131,072 shorts = 65,536 floats
  int*   idxmap= (int*)(P0 + 2560000 + 262144 + 262144 + 65536);   // 160,000
  int*   list  = idxmap + 160000;          // NCAP
  int*   cnt   = list + NCAP;              // 1 (+3 pad)
  float* Ptouch= (float*)(cnt + 4);        // NCAP*256
  long base_floats = (long)(Ptouch - ws);
  long avail = ((long)(ws_size/4) - base_floats)/SZ;
  int sparse_ok = (avail >= NCAP);
  float* out   = (float*)d_out;

  hipFuncSetAttribute((const void*)k_lstm_w8,
                      hipFuncAttributeMaxDynamicSharedMemorySize, 147968);

  k_we<<<NW/16,256,0,stream>>>(emb,Wp,bp,we);
  k_rowgemm<<<NW/16,256,0,stream>>>(we,Wg,P0,nullptr);            // P0 = we@Wg1
  k_prep<<<256,256,0,stream>>>(Wh_f,Wh_b,whb);
  k_prepwi<<<256,256,0,stream>>>(Wi_f,Wi_b,wifrag);
  k_prepenc<<<64,256,0,stream>>>(Wenc,wefrag);

  // ---------------- iteration 0 ----------------
  hipMemsetAsync(lembuf,0,(size_t)(12288000+48000)*4,stream);
  k_xwi_mfma<<<64,256,0,stream>>>(seq0,len0,we,0L,nullptr,nullptr,
                                  Wi_f,b_f,Wi_b,b_b,wifrag,0,(short*)xwi);
  k_lstm_w8<<<2,512,147968,stream>>>(whb,(const short*)xwi,(short*)hglob);
  k_enc_mfma<<<BB*LL/64,256,0,stream>>>(seq0,len0,u2l,(const short*)hglob,wefrag,benc,
                                        (unsigned int*)lembuf,(unsigned int*)flags);
  k_rowgemm<<<BB*NLEM/16,256,0,stream>>>(lembuf,Wg+(long)SZ*SZ,Q,
                                         (const unsigned int*)flags);  // Q = nw@Wg2
  if(sparse_ok){
    hipMemsetAsync(cnt,0,4,stream);
    k_compact<<<(BB*NW+255)/256,256,0,stream>>>(u2l,(const unsigned int*)flags,
                                                cnt,list,idxmap,NCAP);
    k_gate0c<<<NCAP*64/256,256,0,stream>>>(we,P0,Q,lembuf,u2l,bg,cnt,list,ctxtT,NCAP);
    k_rowgemm_n<<<NCAP/16,256,0,stream>>>(ctxtT,Wg,Ptouch,cnt,NCAP); // Pt=ctxtT@Wg1
    k_base0ip<<<(NW*SZ/4+255)/256,256,0,stream>>>(we,P0,bg);         // we <- base0
    k_rowgemm<<<NW/16,256,0,stream>>>(we,Wg,P0,nullptr);             // P0 <- base0@Wg1
  }else{
    long nb=((long)BB*NW*SZ/4+255)/256;
    k_gate0<<<(int)nb,256,0,stream>>>(we,P0,Q,lembuf,u2l,
                                      (const unsigned int*)flags,bg,out);
  }

  // ---------------- iteration 1 ----------------
  hipMemsetAsync(lembuf,0,(size_t)(12288000+48000)*4,stream);
  if(sparse_ok){
    k_xwi_mfma<<<64,256,0,stream>>>(seq1,len1,we,0L,ctxtT,idxmap,
                                    Wi_f,b_f,Wi_b,b_b,wifrag,1,(short*)xwi);
  }else{
    k_xwi_mfma<<<64,256,0,stream>>>(seq1,len1,out,(long)NW*SZ,nullptr,nullptr,
                                    Wi_f,b_f,Wi_b,b_b,wifrag,1,(short*)xwi);
  }
  k_lstm_w8<<<2,512,147968,stream>>>(whb,(const short*)xwi,(short*)hglob);
  k_enc_mfma<<<BB*LL/64,256,0,stream>>>(seq1,len1,u2l,(const short*)hglob,wefrag,benc,
                                        (unsigned int*)lembuf,(unsigned int*)flags);
  k_rowgemm<<<BB*NLEM/16,256,0,stream>>>(lembuf,Wg+(long)SZ*SZ,Q,
                                         (const unsigned int*)flags);  // Q = nw@Wg2
  if(sparse_ok){
    long nb=((long)BB*NW*SZ/4+255)/256;
    k_gate1e<<<(int)nb,256,0,stream>>>(we,ctxtT,P0,Ptouch,idxmap,Q,lembuf,u2l,
                                       (const unsigned int*)flags,bg,out);
  }else{
    k_gate1<<<BB*NW/64,256,0,stream>>>(out,Wg,Q,lembuf,u2l,
                                       (const unsigned int*)flags,bg,out);
  }
}

// Round 12
// 1346.353 us; speedup vs baseline: 1.1773x; 1.1773x over previous
//
#include <hip/hip_runtime.h>

#define NW    10000
#define INDIM 300
#define SZ    256
#define BB    16
#define LL    128
#define NLEM  3000
#define FH    1024   // 4*SZ
#define NCAP  8192

typedef short  bf16x8 __attribute__((ext_vector_type(8)));
typedef float  f32x4  __attribute__((ext_vector_type(4)));

__device__ __forceinline__ float sigf(float x){
  return __builtin_amdgcn_rcpf(1.f+__builtin_amdgcn_exp2f(-1.442695041f*x));
}
__device__ __forceinline__ float tanhf_(float x){
  return fmaf(-2.f, __builtin_amdgcn_rcpf(1.f+__builtin_amdgcn_exp2f(2.885390082f*x)), 1.f);
}
__device__ __forceinline__ short f2b(float f){
  unsigned u=__float_as_uint(f); u += 0x7FFFu + ((u>>16)&1u); return (short)(u>>16);
}
__device__ __forceinline__ int pack2(float a, float b){
  return ((int)(unsigned short)f2b(a)) | (((int)(unsigned short)f2b(b))<<16);
}
#define B2F(s) __uint_as_float(((unsigned)(unsigned short)(s))<<16)
#define MFA(a,b,c) __builtin_amdgcn_mfma_f32_16x16x32_bf16(a,b,c,0,0,0)

// ---------------- we = relu(emb @ Wp + bp) : [10000,300]@[300,256] ----------
__global__ void k_we(const float* __restrict__ emb, const float* __restrict__ Wp,
                     const float* __restrict__ bp, float* __restrict__ we){
  __shared__ __align__(16) float As[16][INDIM];
  int r0 = blockIdx.x*16, tid = threadIdx.x;
  for(int i=tid;i<16*INDIM;i+=256){int lr=i/INDIM,d=i-lr*INDIM;
    As[lr][d]=emb[(long)(r0+lr)*INDIM+d];}
  __syncthreads();
  int cl=tid&63, rg=tid>>6;
  float acc[4][4];
  #pragma unroll
  for(int i=0;i<4;i++){acc[i][0]=acc[i][1]=acc[i][2]=acc[i][3]=0.f;}
  for(int k=0;k<INDIM;k+=4){
    float4 a4[4];
    #pragma unroll
    for(int i=0;i<4;i++) a4[i]=*(const float4*)&As[rg*4+i][k];
    #pragma unroll
    for(int j=0;j<4;j++){
      const float* wr=Wp+(long)(k+j)*SZ+cl;
      float w0=wr[0],w1=wr[64],w2=wr[128],w3=wr[192];
      #pragma unroll
      for(int i=0;i<4;i++){
        float a=(j==0)?a4[i].x:(j==1)?a4[i].y:(j==2)?a4[i].z:a4[i].w;
        acc[i][0]=fmaf(a,w0,acc[i][0]);acc[i][1]=fmaf(a,w1,acc[i][1]);
        acc[i][2]=fmaf(a,w2,acc[i][2]);acc[i][3]=fmaf(a,w3,acc[i][3]);
      }
    }
  }
  #pragma unroll
  for(int i=0;i<4;i++){
    int r=r0+rg*4+i;
    #pragma unroll
    for(int cc=0;cc<4;cc++){int col=cl+cc*64;
      we[(long)r*SZ+col]=fmaxf(acc[i][cc]+bp[col],0.f);}
  }
}

// ---- prep: Wh -> bf16 MFMA B-fragments, (dir,w,T2=s*4+g,ks,lane) tiling ----
__global__ void k_prep(const float* __restrict__ Wh_f, const float* __restrict__ Wh_b,
                       short* __restrict__ frag){
  int tid = blockIdx.x*256 + threadIdx.x;   // 65536 total
  int l=tid&63, f=(tid>>6)&63, w=(tid>>12)&7, dir=tid>>15;
  const float* Wh = dir? Wh_b : Wh_f;
  int ks=f&7, T2=f>>3, s2=T2>>2, g=T2&3;
  int col = g*256 + w*32 + s2*16 + (l&15);
  int k0  = ks*32 + (l>>4)*8;
  short v[8];
  #pragma unroll
  for(int j=0;j<8;j++) v[j]=f2b(Wh[(long)(k0+j)*FH + col]);
  *(bf16x8*)(frag + (long)tid*8) = *(bf16x8*)v;
}

// ---- prep: Wi -> bf16 B-frags: wf[((dir*64+ct)*8+ks)*512 + l*8 + j] --------
__global__ void k_prepwi(const float* __restrict__ Wi_f, const float* __restrict__ Wi_b,
                         short* __restrict__ wf){
  int tid = blockIdx.x*256 + threadIdx.x;   // 65536
  int l=tid&63, ks=(tid>>6)&7, ct=(tid>>9)&63, dir=tid>>15;
  const float* Wi = dir? Wi_b : Wi_f;
  int col = ct*16 + (l&15);
  int k0  = ks*32 + (l>>4)*8;
  short v[8];
  #pragma unroll
  for(int j=0;j<8;j++) v[j]=f2b(Wi[(long)(k0+j)*FH + col]);
  *(bf16x8*)(wf + (long)tid*8) = *(bf16x8*)v;
}

// ---- prep: Wenc -> bf16 B-frags: wef[(ct*16+ks)*512 + l*8 + j], K=512 ------
__global__ void k_prepenc(const float* __restrict__ Wenc, short* __restrict__ wef){
  int tid = blockIdx.x*256 + threadIdx.x;   // 16384
  int l=tid&63, ks=(tid>>6)&15, ct=tid>>10;
  int col = ct*16 + (l&15);
  int k0  = ks*32 + (l>>4)*8;
  short v[8];
  #pragma unroll
  for(int j=0;j<8;j++) v[j]=f2b(Wenc[(long)(k0+j)*SZ + col]);
  *(bf16x8*)(wef + (long)tid*8) = *(bf16x8*)v;
}

// ---- MFMA xwi: [64 rows]@[256x1024] bf16, epilogue writes LSTM frag layout -
__global__ void k_xwi_mfma(const int* __restrict__ seq, const int* __restrict__ len,
                      const float* __restrict__ srcw, long bstride,
                      const float* __restrict__ ctxtT, const int* __restrict__ idxmap,
                      const float* __restrict__ Wi_f, const float* __restrict__ bvf,
                      const float* __restrict__ Wi_b, const float* __restrict__ bvb,
                      const short* __restrict__ wf, int iseq, short* __restrict__ xwo){
  __shared__ __align__(16) short As[64*264];
  __shared__ const float* rowp[64];
  int bx=blockIdx.x, dir=bx>>5, blk=bx&31, tid=threadIdx.x;
  int w=tid>>6, l=tid&63;
  if(tid<64){
    int t = blk*4 + (tid>>4), b = tid&15;
    int lb=len[b];
    int tt=(dir==0)? t : ((t<lb)? (lb-1-t) : t);
    int tok=seq[b*LL+tt];
    const float* rp;
    if(idxmap){
      int im=idxmap[b*NW+tok];
      rp = (im>=0)? ctxtT+(long)im*SZ : srcw+(long)tok*SZ;
    }else{
      rp = srcw + (long)b*bstride + (long)tok*SZ;
    }
    rowp[tid]=rp;
  }
  __syncthreads();
  for(int i2=tid;i2<64*64;i2+=256){
    int lr=i2>>6, c4=(i2&63)*4;
    float4 v=*(const float4*)(rowp[lr]+c4);
    int2 pk; pk.x=pack2(v.x,v.y); pk.y=pack2(v.z,v.w);
    *(int2*)&As[lr*264+c4]=pk;
  }
  __syncthreads();
  const float* __restrict__ Wi = dir? Wi_b : Wi_f;
  const float* __restrict__ bv = dir? bvb : bvf;
  const short* wfd = wf + (long)dir*262144;
  for(int n2=0;n2<16;n2++){
    int ct = w*16 + n2;
    const short* bfp = wfd + ((long)ct*8)*512 + l*8;
    f32x4 Z={0.f,0.f,0.f,0.f};
    f32x4 C0=Z,C1=Z,C2=Z,C3=Z;
    #pragma unroll
    for(int ks=0;ks<8;ks++){
      bf16x8 bb=*(const bf16x8*)(bfp + ks*512);
      int ao = ks*32 + (l>>4)*8;
      bf16x8 a0=*(const bf16x8*)(&As[((l&15)    )*264 + ao]);
      bf16x8 a1=*(const bf16x8*)(&As[((l&15)+16 )*264 + ao]);
      bf16x8 a2=*(const bf16x8*)(&As[((l&15)+32 )*264 + ao]);
      bf16x8 a3=*(const bf16x8*)(&As[((l&15)+48 )*264 + ao]);
      C0=MFA(a0,bb,C0); C1=MFA(a1,bb,C1); C2=MFA(a2,bb,C2); C3=MFA(a3,bb,C3);
    }
    int g=ct>>4, w2=(ct&15)>>1, s2=ct&1;
    int col = g*256 + w2*32 + s2*16 + (l&15);
    float be = Wi[(long)(SZ+iseq)*FH+col] + bv[col];
    #pragma unroll
    for(int m=0;m<4;m++){
      f32x4 Cm = (m==0)?C0:(m==1)?C1:(m==2)?C2:C3;
      long base=((((long)dir*128 + blk*4 + m)*8 + w2)*64 + (l>>4)*16 + (l&15))*32
                + s2*16 + g*4;
      int2 pk; pk.x=pack2(Cm[0]+be,Cm[1]+be); pk.y=pack2(Cm[2]+be,Cm[3]+be);
      *(int2*)(xwo+base)=pk;
    }
  }
}

// --------- single-CU-per-dir persistent LSTM: 512 thr, 8 waves, 2/SIMD ------
#define LDFW(f)    (*(const bf16x8*)(fr + (long)(f)*512 + l*8))
#define LDLW(i2,ks) (*(const bf16x8*)(bl + ((i2)*8+(ks))*512 + l*8))
#define DECLWT(T) bf16x8 W##T##_0=LDFW((T)*8+0),W##T##_1=LDFW((T)*8+1),W##T##_2=LDFW((T)*8+2),W##T##_3=LDFW((T)*8+3),W##T##_4=LDFW((T)*8+4),W##T##_5=LDFW((T)*8+5),W##T##_6=LDFW((T)*8+6),W##T##_7=LDFW((T)*8+7);
#define MMRT(T,Cv) { Cv=MFA(A0,W##T##_0,Cv); Cv=MFA(A1,W##T##_1,Cv); Cv=MFA(A2,W##T##_2,Cv); Cv=MFA(A3,W##T##_3,Cv); Cv=MFA(A4,W##T##_4,Cv); Cv=MFA(A5,W##T##_5,Cv); Cv=MFA(A6,W##T##_6,Cv); Cv=MFA(A7,W##T##_7,Cv); }
#define MMLT(i2,Cv) { Cv=MFA(A0,LDLW(i2,0),Cv); Cv=MFA(A1,LDLW(i2,1),Cv); Cv=MFA(A2,LDLW(i2,2),Cv); Cv=MFA(A3,LDLW(i2,3),Cv); Cv=MFA(A4,LDLW(i2,4),Cv); Cv=MFA(A5,LDLW(i2,5),Cv); Cv=MFA(A6,LDLW(i2,6),Cv); Cv=MFA(A7,LDLW(i2,7),Cv); }
#define MMST(Cv) { Cv=MFA(A0,S0,Cv); Cv=MFA(A1,S1,Cv); Cv=MFA(A2,S2,Cv); Cv=MFA(A3,S3,Cv); Cv=MFA(A4,S4,Cv); Cv=MFA(A5,S5,Cv); Cv=MFA(A6,S6,Cv); Cv=MFA(A7,S7,Cv); }
#define LOADST(f0) S0=LDFW((f0)+0); S1=LDFW((f0)+1); S2=LDFW((f0)+2); S3=LDFW((f0)+3); S4=LDFW((f0)+4); S5=LDFW((f0)+5); S6=LDFW((f0)+6); S7=LDFW((f0)+7);
#define G1(s,r,CA,CB,CC,CD,XA,XB) { \
  float zi=CA[r]+B2F(XA[r]), zf=CB[r]+B2F(XA[4+(r)]), zg=CC[r]+B2F(XB[r]), zo=CD[r]+B2F(XB[4+(r)]); \
  cst_##s##_##r = sigf(zf)*cst_##s##_##r + sigf(zi)*tanhf_(zg); \
  float hv = sigf(zo)*tanhf_(cst_##s##_##r); \
  int b_=4*(l>>4)+(r); int u_=w*32+(s)*16+(l&15); \
  hbn[b_*264+u_]=f2b(hv); }
#define GP(s,CA,CB,CC,CD,XA,XB) \
  G1(s,0,CA,CB,CC,CD,XA,XB) G1(s,1,CA,CB,CC,CD,XA,XB) \
  G1(s,2,CA,CB,CC,CD,XA,XB) G1(s,3,CA,CB,CC,CD,XA,XB)

extern __shared__ char smem_raw[];

__global__ __launch_bounds__(512,2) void k_lstm_w8(
    const short* __restrict__ frag, const short* __restrict__ xq,
    short* __restrict__ hgs){
  const int dir=blockIdx.x, tid=threadIdx.x, w=tid>>6, l=tid&63;
  short* hb=(short*)smem_raw;                      // 2 x 16 x 264 shorts
  short* bl=(short*)(smem_raw+16896)+w*8192;       // per-wave LDS frags T2=4,5
  const short* fr = frag + (long)(dir*8+w)*32768;  // 64 frags * 512
  for(int i=tid;i<4224;i+=512) ((int*)smem_raw)[i]=0;
  #pragma unroll
  for(int c2=0;c2<16;c2++)
    *(f32x4*)(bl+c2*512+l*8) = *(const f32x4*)(fr+(long)(32+c2)*512+l*8);
  DECLWT(0) DECLWT(1) DECLWT(2) DECLWT(3)          // 32 resident frags
  float cst_0_0=0,cst_0_1=0,cst_0_2=0,cst_0_3=0,
        cst_1_0=0,cst_1_1=0,cst_1_2=0,cst_1_3=0;
  __syncthreads();
  const short* xwb = xq + ((long)dir*128*8 + w)*2048 + (long)l*32;
  short* hgb = hgs + (long)dir*524288;             // bf16 h-out [t][16][256]
  const int db=tid>>5, du=(tid&31)*8;              // dump coords
  bf16x8 S0,S1,S2,S3,S4,S5,S6,S7;
  for(int t=0;t<LL;t++){
    const int cur=t&1, nxt=cur^1;
    LOADST(48)                                     // stream T2=6 (early issue)
    const short* xp = xwb + (long)t*16384;
    bf16x8 X0=*(const bf16x8*)(xp+0), X1=*(const bf16x8*)(xp+8);
    const short* hr = hb + cur*4224 + (l&15)*264 + (l>>4)*8;
    bf16x8 A0=*(const bf16x8*)(hr+0),   A1=*(const bf16x8*)(hr+32),
           A2=*(const bf16x8*)(hr+64),  A3=*(const bf16x8*)(hr+96),
           A4=*(const bf16x8*)(hr+128), A5=*(const bf16x8*)(hr+160),
           A6=*(const bf16x8*)(hr+192), A7=*(const bf16x8*)(hr+224);
    f32x4 Z={0.f,0.f,0.f,0.f};
    f32x4 C00=Z,C01=Z,C02=Z,C03=Z,C10=Z,C11=Z,C12=Z,C13=Z;
    MMRT(0,C00) MMRT(1,C01) MMRT(2,C02) MMRT(3,C03)   // resident (32 MFMA)
    MMLT(0,C10) MMLT(1,C11)                           // LDS tiles (16 MFMA)
    MMST(C12)                                         // T2=6 streamed
    LOADST(56)                                        // stream T2=7 (issue)
    bf16x8 X2=*(const bf16x8*)(xp+16), X3=*(const bf16x8*)(xp+24);
    short* hbn = hb + nxt*4224;
    GP(0, C00,C01,C02,C03, X0,X1)                     // hides T2=7 latency
    MMST(C13)                                         // T2=7 streamed
    GP(1, C10,C11,C12,C13, X2,X3)
    __syncthreads();
    // coalesced bf16 h dump; store retires during next step (no drain stall)
    f32x4 hv4 = *(const f32x4*)(hbn + db*264 + du);
    *(f32x4*)(hgb + ((long)t*16 + db)*256 + du) = hv4;
  }
}

// ---- MFMA enc: [64 rows][K=512] @ Wenc frags -> relu(max) atomic scatter ---
__global__ void k_enc_mfma(const int* __restrict__ seq, const int* __restrict__ len,
                      const int* __restrict__ u2l, const short* __restrict__ hgs,
                      const short* __restrict__ wef, const float* __restrict__ benc,
                      unsigned int* __restrict__ lembuf, unsigned int* __restrict__ flags){
  __shared__ __align__(16) short As[64*520];
  __shared__ const short* pf16[64]; __shared__ const short* pb16[64];
  __shared__ int lem_s[64], val_s[64], b_s[64];
  int r0=blockIdx.x*64, tid=threadIdx.x, w=tid>>6, l=tid&63;
  if(tid<64){
    int r=r0+tid, b=r>>7, t=r&127, lb=len[b];
    int v=(t<lb); val_s[tid]=v; b_s[tid]=b;
    int lem=u2l[seq[r]]; lem_s[tid]=lem;
    pf16[tid]=hgs+((long)t*BB+b)*SZ;
    int tr=v? (lb-1-t) : t;
    pb16[tid]=hgs+((long)(LL+tr)*BB+b)*SZ;
    if(v) flags[(long)b*NLEM+lem]=1u;
  }
  __syncthreads();
  for(int i2=tid;i2<64*128;i2+=256){
    int lr=i2>>7, cc=(i2&127)*4;
    const short* sp=(cc<256)? pf16[lr]+cc : pb16[lr]+(cc-256);
    *(int2*)&As[lr*520+cc]=*(const int2*)sp;
  }
  __syncthreads();
  for(int n2=0;n2<4;n2++){
    int ct=w*4+n2;
    f32x4 Z={0.f,0.f,0.f,0.f};
    f32x4 C0=Z,C1=Z,C2=Z,C3=Z;
    #pragma unroll
    for(int ks=0;ks<16;ks++){
      bf16x8 bb=*(const bf16x8*)(wef+((long)(ct*16+ks))*512+l*8);
      int ao=ks*32+(l>>4)*8;
      bf16x8 a0=*(const bf16x8*)(&As[((l&15)    )*520+ao]);
      bf16x8 a1=*(const bf16x8*)(&As[((l&15)+16 )*520+ao]);
      bf16x8 a2=*(const bf16x8*)(&As[((l&15)+32 )*520+ao]);
      bf16x8 a3=*(const bf16x8*)(&As[((l&15)+48 )*520+ao]);
      C0=MFA(a0,bb,C0); C1=MFA(a1,bb,C1); C2=MFA(a2,bb,C2); C3=MFA(a3,bb,C3);
    }
    int col=ct*16+(l&15);
    float be=benc[col];
    #pragma unroll
    for(int m=0;m<4;m++){
      f32x4 Cm=(m==0)?C0:(m==1)?C1:(m==2)?C2:C3;
      #pragma unroll
      for(int reg=0;reg<4;reg++){
        int row=m*16+(l>>4)*4+reg;
        if(val_s[row]){
          float e=fmaxf(Cm[reg]+be,0.f);
          atomicMax(&lembuf[((long)b_s[row]*NLEM+lem_s[row])*SZ+col], __float_as_uint(e));
        }
      }
    }
  }
}

// ------------ generic C[r] = A[r] @ W  (K=256), optional touched-flags ------
__global__ void k_rowgemm(const float* __restrict__ A, const float* __restrict__ W,
                          float* __restrict__ C, const unsigned int* __restrict__ flags){
  __shared__ __align__(16) float As[16][SZ];
  __shared__ int any_s;
  int r0=blockIdx.x*16, tid=threadIdx.x;
  if(tid==0){
    int a = flags? 0 : 1;
    if(flags){ for(int i=0;i<16;i++) a |= (int)flags[r0+i]; }
    any_s=a;
  }
  __syncthreads();
  if(!any_s) return;
  for(int i=tid;i<16*SZ;i+=256){int lr=i>>8,j=i&(SZ-1);As[lr][j]=A[(long)(r0+lr)*SZ+j];}
  __syncthreads();
  int cl=tid&63, rg=tid>>6;
  float acc[4][4];
  #pragma unroll
  for(int i=0;i<4;i++){acc[i][0]=acc[i][1]=acc[i][2]=acc[i][3]=0.f;}
  for(int k=0;k<SZ;k+=4){
    float4 a4[4];
    #pragma unroll
    for(int i=0;i<4;i++) a4[i]=*(const float4*)&As[rg*4+i][k];
    #pragma unroll
    for(int j=0;j<4;j++){
      const float* wr=W+(long)(k+j)*SZ+cl;
      float w0=wr[0],w1=wr[64],w2=wr[128],w3=wr[192];
      #pragma unroll
      for(int i=0;i<4;i++){
        float a=(j==0)?a4[i].x:(j==1)?a4[i].y:(j==2)?a4[i].z:a4[i].w;
        acc[i][0]=fmaf(a,w0,acc[i][0]);acc[i][1]=fmaf(a,w1,acc[i][1]);
        acc[i][2]=fmaf(a,w2,acc[i][2]);acc[i][3]=fmaf(a,w3,acc[i][3]);
      }
    }
  }
  #pragma unroll
  for(int i=0;i<4;i++){
    int r=r0+rg*4+i;
    #pragma unroll
    for(int cc=0;cc<4;cc++) C[(long)r*SZ+cl+cc*64]=acc[i][cc];
  }
}

// ------------ rowgemm over *cnt rows (compacted): C[i] = A[i] @ W -----------
__global__ void k_rowgemm_n(const float* __restrict__ A, const float* __restrict__ W,
                            float* __restrict__ C, const int* __restrict__ cnt, int ncap){
  __shared__ __align__(16) float As[16][SZ];
  int n=*cnt; if(n>ncap)n=ncap;
  int r0=blockIdx.x*16, tid=threadIdx.x;
  if(r0>=n) return;
  for(int i=tid;i<16*SZ;i+=256){int lr=i>>8,j=i&(SZ-1);
    As[lr][j]= (r0+lr<n)? A[(long)(r0+lr)*SZ+j] : 0.f;}
  __syncthreads();
  int cl=tid&63, rg=tid>>6;
  float acc[4][4];
  #pragma unroll
  for(int i=0;i<4;i++){acc[i][0]=acc[i][1]=acc[i][2]=acc[i][3]=0.f;}
  for(int k=0;k<SZ;k+=4){
    float4 a4[4];
    #pragma unroll
    for(int i=0;i<4;i++) a4[i]=*(const float4*)&As[rg*4+i][k];
    #pragma unroll
    for(int j=0;j<4;j++){
      const float* wr=W+(long)(k+j)*SZ+cl;
      float w0=wr[0],w1=wr[64],w2=wr[128],w3=wr[192];
      #pragma unroll
      for(int i=0;i<4;i++){
        float a=(j==0)?a4[i].x:(j==1)?a4[i].y:(j==2)?a4[i].z:a4[i].w;
        acc[i][0]=fmaf(a,w0,acc[i][0]);acc[i][1]=fmaf(a,w1,acc[i][1]);
        acc[i][2]=fmaf(a,w2,acc[i][2]);acc[i][3]=fmaf(a,w3,acc[i][3]);
      }
    }
  }
  #pragma unroll
  for(int i=0;i<4;i++){
    int r=r0+rg*4+i;
    if(r<n){
      #pragma unroll
      for(int cc=0;cc<4;cc++) C[(long)r*SZ+cl+cc*64]=acc[i][cc];
    }
  }
}

// ---- compact list of rows whose lemma was touched in iter 0 ----------------
__global__ void k_compact(const int* __restrict__ u2l, const unsigned int* __restrict__ flags,
                          int* __restrict__ cnt, int* __restrict__ list,
                          int* __restrict__ idxmap, int ncap){
  int r = blockIdx.x*256+threadIdx.x;
  if(r>=BB*NW) return;
  int b=r/NW, w=r-b*NW;
  int im=-1;
  if(flags[(long)b*NLEM+u2l[w]]){
    int idx=atomicAdd(cnt,1);
    if(idx<ncap){ list[idx]=r; im=idx; }
  }
  idxmap[r]=im;
}

// ---- gate for touched-only rows -> compact ctxtT ---------------------------
__global__ void k_gate0c(const float* __restrict__ we, const float* __restrict__ P0,
                         const float* __restrict__ Q, const float* __restrict__ lembuf,
                         const int* __restrict__ u2l, const float* __restrict__ bg,
                         const int* __restrict__ cnt, const int* __restrict__ list,
                         float* __restrict__ ctxtT, int ncap){
  int n=*cnt; if(n>ncap)n=ncap;
  long idx=(long)blockIdx.x*256+threadIdx.x;
  long i=idx>>6; int k4=(int)(idx&63);
  if(i>=n) return;
  int r=list[i]; int b=r/NW, w=r-b*NW;
  int lem=u2l[w];
  long qb=((long)b*NLEM+lem)*SZ;
  float4 p =((const float4*)(P0+(long)w*SZ))[k4];
  float4 wv=((const float4*)(we+(long)w*SZ))[k4];
  float4 bgv=((const float4*)bg)[k4];
  float4 q =((const float4*)(Q+qb))[k4];
  float4 nw=((const float4*)(lembuf+qb))[k4];
  float4 o;
  { float g=sigf(p.x+q.x+bgv.x); o.x=wv.x*g+(1.f-g)*nw.x; }
  { float g=sigf(p.y+q.y+bgv.y); o.y=wv.y*g+(1.f-g)*nw.y; }
  { float g=sigf(p.z+q.z+bgv.z); o.z=wv.z*g+(1.f-g)*nw.z; }
  { float g=sigf(p.w+q.w+bgv.w); o.w=wv.w*g+(1.f-g)*nw.w; }
  ((float4*)ctxtT)[i*64+k4]=o;
}

// ---- we <- we*sig(P0+bg)  (base0 in place; run after gate0c) ---------------
__global__ void k_base0ip(float* __restrict__ we, const float* __restrict__ P0,
                          const float* __restrict__ bg){
  long idx=(long)blockIdx.x*256+threadIdx.x;
  if(idx>=(long)NW*SZ/4) return;
  int k4=(int)(idx&63);
  float4 wv=((float4*)we)[idx];
  float4 p =((const float4*)P0)[idx];
  float4 bgv=((const float4*)bg)[k4];
  wv.x*=sigf(p.x+bgv.x); wv.y*=sigf(p.y+bgv.y);
  wv.z*=sigf(p.z+bgv.z); wv.w*=sigf(p.w+bgv.w);
  ((float4*)we)[idx]=wv;
}

// ------- iter-0 gate DENSE (fallback): full out write -----------------------
__global__ void k_gate0(const float* __restrict__ we, const float* __restrict__ P0,
                        const float* __restrict__ Q, const float* __restrict__ lembuf,
                        const int* __restrict__ u2l, const unsigned int* __restrict__ flags,
                        const float* __restrict__ bg, float* __restrict__ out){
  long idx=(long)blockIdx.x*256+threadIdx.x;
  const long TOTAL4=(long)BB*NW*SZ/4;
  if(idx>=TOTAL4) return;
  long row=idx>>6; int k4=(int)(idx&63);
  int r32=(int)row;
  int b=r32/NW, w=r32-b*NW;
  int lem=u2l[w];
  long qb=((long)b*NLEM+lem)*SZ;
  unsigned int fl=flags[(long)b*NLEM+lem];
  float4 p =((const float4*)(P0+(long)w*SZ))[k4];
  float4 wv=((const float4*)(we+(long)w*SZ))[k4];
  float4 bgv=((const float4*)bg)[k4];
  float4 q, nw;
  if(fl){ q=((const float4*)(Q+qb))[k4]; nw=((const float4*)(lembuf+qb))[k4]; }
  else  { q=make_float4(0.f,0.f,0.f,0.f); nw=q; }
  float4 o;
  { float g=sigf(p.x+q.x+bgv.x); o.x=wv.x*g+(1.f-g)*nw.x; }
  { float g=sigf(p.y+q.y+bgv.y); o.y=wv.y*g+(1.f-g)*nw.y; }
  { float g=sigf(p.z+q.z+bgv.z); o.z=wv.z*g+(1.f-g)*nw.z; }
  { float g=sigf(p.w+q.w+bgv.w); o.w=wv.w*g+(1.f-g)*nw.w; }
  ((float4*)out)[idx]=o;
}

// ------- iter-1 gate: cv from base0/ctxtT, p from P1b/Pt, write final out ---
__global__ void k_gate1e(const float* __restrict__ base0, const float* __restrict__ ctxtT,
                         const float* __restrict__ P1b, const float* __restrict__ Pt,
                         const int* __restrict__ idxmap,
                         const float* __restrict__ Q, const float* __restrict__ lembuf,
                         const int* __restrict__ u2l, const unsigned int* __restrict__ flags,
                         const float* __restrict__ bg, float* __restrict__ out){
  long idx=(long)blockIdx.x*256+threadIdx.x;
  const long TOTAL4=(long)BB*NW*SZ/4;
  if(idx>=TOTAL4) return;
  long row=idx>>6; int k4=(int)(idx&63);
  int r32=(int)row;
  int b=r32/NW, w=r32-b*NW;
  int im=idxmap[r32];
  int lem=u2l[w];
  long qb=((long)b*NLEM+lem)*SZ;
  unsigned int fl=flags[(long)b*NLEM+lem];
  float4 p, cv;
  if(im>=0){ p=((const float4*)(Pt+(long)im*SZ))[k4]; cv=((const float4*)(ctxtT+(long)im*SZ))[k4]; }
  else     { p=((const float4*)(P1b+(long)w*SZ))[k4]; cv=((const float4*)(base0+(long)w*SZ))[k4]; }
  float4 bgv=((const float4*)bg)[k4];
  float4 q, nw;
  if(fl){ q=((const float4*)(Q+qb))[k4]; nw=((const float4*)(lembuf+qb))[k4]; }
  else  { q=make_float4(0.f,0.f,0.f,0.f); nw=q; }
  float4 o;
  { float g=sigf(p.x+q.x+bgv.x); o.x=cv.x*g+(1.f-g)*nw.x; }
  { float g=sigf(p.y+q.y+bgv.y); o.y=cv.y*g+(1.f-g)*nw.y; }
  { float g=sigf(p.z+q.z+bgv.z); o.z=cv.z*g+(1.f-g)*nw.z; }
  { float g=sigf(p.w+q.w+bgv.w); o.w=cv.w*g+(1.f-g)*nw.w; }
  ((float4*)out)[idx]=o;
}

// ------- legacy dense iter-1 gate (fallback if ws too small) ----------------
__global__ void k_gate1(const float* __restrict__ ctxt, const float* __restrict__ Wg,
                        const float* __restrict__ Q, const float* __restrict__ lembuf,
                        const int* __restrict__ u2l, const unsigned int* __restrict__ flags,
                        const float* __restrict__ bg, float* __restrict__ out){
  __shared__ __align__(16) float As[64][SZ];
  __shared__ __align__(16) float Ws[64][SZ];
  __shared__ int lem_s[64];
  int r0=blockIdx.x*64, tid=threadIdx.x;
  for(int i=tid;i<64*SZ;i+=256){int lr=i>>8,j=i&(SZ-1);
    As[lr][j]=ctxt[(long)(r0+lr)*SZ+j];}
  if(tid<64){int r=r0+tid; lem_s[tid]=u2l[r%NW];}
  int cl=tid&63, rg=tid>>6;
  float acc[16][4];
  #pragma unroll
  for(int i=0;i<16;i++){acc[i][0]=acc[i][1]=acc[i][2]=acc[i][3]=0.f;}
  for(int kb=0;kb<4;kb++){
    __syncthreads();
    for(int i=tid;i<64*SZ;i+=256){int lr=i>>8,j=i&(SZ-1);
      Ws[lr][j]=Wg[(long)(kb*64+lr)*SZ+j];}
    __syncthreads();
    for(int k=0;k<64;k+=4){
      float4 a4[16];
      #pragma unroll
      for(int i=0;i<16;i++) a4[i]=*(const float4*)&As[rg*16+i][kb*64+k];
      #pragma unroll
      for(int j=0;j<4;j++){
        float w0=Ws[k+j][cl],w1=Ws[k+j][cl+64],w2=Ws[k+j][cl+128],w3=Ws[k+j][cl+192];
        #pragma unroll
        for(int i=0;i<16;i++){
          float a=(j==0)?a4[i].x:(j==1)?a4[i].y:(j==2)?a4[i].z:a4[i].w;
          acc[i][0]=fmaf(a,w0,acc[i][0]);acc[i][1]=fmaf(a,w1,acc[i][1]);
          acc[i][2]=fmaf(a,w2,acc[i][2]);acc[i][3]=fmaf(a,w3,acc[i][3]);
        }
      }
    }
  }
  #pragma unroll
  for(int i=0;i<16;i++){
    int lr=rg*16+i, r=r0+lr, b=r/NW;
    long base=((long)b*NLEM+lem_s[lr])*SZ;
    unsigned int fl=flags[(long)b*NLEM+lem_s[lr]];
    #pragma unroll
    for(int cc=0;cc<4;cc++){
      int col=cl+cc*64;
      float qv=0.f, nw=0.f;
      if(fl){ qv=Q[base+col]; nw=lembuf[base+col]; }
      float g=sigf(acc[i][cc]+qv+bg[col]);
      out[(long)r*SZ+col]=As[lr][col]*g+(1.f-g)*nw;
    }
  }
}

extern "C" void kernel_launch(void* const* d_in, const int* in_sizes, int n_in,
                              void* d_out, int out_size, void* d_ws, size_t ws_size,
                              hipStream_t stream){
  const float* emb  =(const float*)d_in[0];
  const float* Wp   =(const float*)d_in[1];
  const float* bp   =(const float*)d_in[2];
  const float* Wi_f =(const float*)d_in[3];
  const float* Wh_f =(const float*)d_in[4];
  const float* b_f  =(const float*)d_in[5];
  const float* Wi_b =(const float*)d_in[6];
  const float* Wh_b =(const float*)d_in[7];
  const float* b_b  =(const float*)d_in[8];
  const float* Wenc =(const float*)d_in[9];
  const float* benc =(const float*)d_in[10];
  const float* Wg   =(const float*)d_in[11];
  const float* bg   =(const float*)d_in[12];
  const int*   seq0 =(const int*)d_in[13];
  const int*   seq1 =(const int*)d_in[14];
  const int*   len0 =(const int*)d_in[15];
  const int*   len1 =(const int*)d_in[16];
  const int*   u2l  =(const int*)d_in[17];

  float* ws    = (float*)d_ws;
  float* we    = ws;                       // 2,560,000 (becomes base0 after iter0)
  float* xwi   = we    + 2560000;          // region 4,194,304 floats:
  float* ctxtT = xwi   + 2097152;          //   xq bf16 first half; ctxtT second
  float* hglob = xwi   + 4194304;          // 1,048,576 (bf16 h uses half)
  float* lembuf= hglob + 1048576;          // 12,288,000
  float* flags = lembuf+ 12288000;         // 48,000 (uint)
  float* Q     = flags + 48000;            // 12,288,000
  float* P0    = Q     + 12288000;         // 2,560,000 (becomes P1b after iter0)
  short* whb   = (short*)(P0 + 2560000);   // 524,288 shorts = 262,144 floats
  short* wifrag= whb + 524288;             // 524,288 shorts = 262,144 floats
  short* wefrag= wifrag + 524288;          // 131,072 shorts = 65,536 floats
  int*   idxmap= (int*)(P0 + 2560000 + 262144 + 262144 + 65536);   // 160,000
  int*   list  = idxmap + 160000;          // NCAP
  int*   cnt   = list + NCAP;              // 1 (+3 pad)
  float* Ptouch= (float*)(cnt + 4);        // NCAP*256
  long base_floats = (long)(Ptouch - ws);
  long avail = ((long)(ws_size/4) - base_floats)/SZ;
  int sparse_ok = (avail >= NCAP);
  float* out   = (float*)d_out;

  hipFuncSetAttribute((const void*)k_lstm_w8,
                      hipFuncAttributeMaxDynamicSharedMemorySize, 147968);

  k_we<<<NW/16,256,0,stream>>>(emb,Wp,bp,we);
  k_rowgemm<<<NW/16,256,0,stream>>>(we,Wg,P0,nullptr);            // P0 = we@Wg1
  k_prep<<<256,256,0,stream>>>(Wh_f,Wh_b,whb);
  k_prepwi<<<256,256,0,stream>>>(Wi_f,Wi_b,wifrag);
  k_prepenc<<<64,256,0,stream>>>(Wenc,wefrag);

  // ---------------- iteration 0 ----------------
  hipMemsetAsync(lembuf,0,(size_t)(12288000+48000)*4,stream);
  k_xwi_mfma<<<64,256,0,stream>>>(seq0,len0,we,0L,nullptr,nullptr,
                                  Wi_f,b_f,Wi_b,b_b,wifrag,0,(short*)xwi);
  k_lstm_w8<<<2,512,147968,stream>>>(whb,(const short*)xwi,(short*)hglob);
  k_enc_mfma<<<BB*LL/64,256,0,stream>>>(seq0,len0,u2l,(const short*)hglob,wefrag,benc,
                                        (unsigned int*)lembuf,(unsigned int*)flags);
  k_rowgemm<<<BB*NLEM/16,256,0,stream>>>(lembuf,Wg+(long)SZ*SZ,Q,
                                         (const unsigned int*)flags);  // Q = nw@Wg2
  if(sparse_ok){
    hipMemsetAsync(cnt,0,4,stream);
    k_compact<<<(BB*NW+255)/256,256,0,stream>>>(u2l,(const unsigned int*)flags,
                                                cnt,list,idxmap,NCAP);
    k_gate0c<<<NCAP*64/256,256,0,stream>>>(we,P0,Q,lembuf,u2l,bg,cnt,list,ctxtT,NCAP);
    k_rowgemm_n<<<NCAP/16,256,0,stream>>>(ctxtT,Wg,Ptouch,cnt,NCAP); // Pt=ctxtT@Wg1
    k_base0ip<<<(NW*SZ/4+255)/256,256,0,stream>>>(we,P0,bg);         // we <- base0
    k_rowgemm<<<NW/16,256,0,stream>>>(we,Wg,P0,nullptr);             // P0 <- base0@Wg1
  }else{
    long nb=((long)BB*NW*SZ/4+255)/256;
    k_gate0<<<(int)nb,256,0,stream>>>(we,P0,Q,lembuf,u2l,
                                      (const unsigned int*)flags,bg,out);
  }

  // ---------------- iteration 1 ----------------
  hipMemsetAsync(lembuf,0,(size_t)(12288000+48000)*4,stream);
  if(sparse_ok){
    k_xwi_mfma<<<64,256,0,stream>>>(seq1,len1,we,0L,ctxtT,idxmap,
                                    Wi_f,b_f,Wi_b,b_b,wifrag,1,(short*)xwi);
  }else{
    k_xwi_mfma<<<64,256,0,stream>>>(seq1,len1,out,(long)NW*SZ,nullptr,nullptr,
                                    Wi_f,b_f,Wi_b,b_b,wifrag,1,(short*)xwi);
  }
  k_lstm_w8<<<2,512,147968,stream>>>(whb,(const short*)xwi,(short*)hglob);
  k_enc_mfma<<<BB*LL/64,256,0,stream>>>(seq1,len1,u2l,(const short*)hglob,wefrag,benc,
                                        (unsigned int*)lembuf,(unsigned int*)flags);
  k_rowgemm<<<BB*NLEM/16,256,0,stream>>>(lembuf,Wg+(long)SZ*SZ,Q,
                                         (const unsigned int*)flags);  // Q = nw@Wg2
  if(sparse_ok){
    long nb=((long)BB*NW*SZ/4+255)/256;
    k_gate1e<<<(int)nb,256,0,stream>>>(we,ctxtT,P0,Ptouch,idxmap,Q,lembuf,u2l,
                                       (const unsigned int*)flags,bg,out);
  }else{
    k_gate1<<<BB*NW/64,256,0,stream>>>(out,Wg,Q,lembuf,u2l,
                                       (const unsigned int*)flags,bg,out);
  }
}

// Round 13
// 1264.414 us; speedup vs baseline: 1.2536x; 1.0648x over previous
//
#include <hip/hip_runtime.h>

#define NW    10000
#define INDIM 300
#define SZ    256
#define BB    16
#define LL    128
#define NLEM  3000
#define FH    1024   // 4*SZ
#define NCAP  8192

typedef short  bf16x8 __attribute__((ext_vector_type(8)));
typedef float  f32x4  __attribute__((ext_vector_type(4)));

__device__ __forceinline__ float sigf(float x){
  return __builtin_amdgcn_rcpf(1.f+__builtin_amdgcn_exp2f(-1.442695041f*x));
}
__device__ __forceinline__ float tanhf_(float x){
  return fmaf(-2.f, __builtin_amdgcn_rcpf(1.f+__builtin_amdgcn_exp2f(2.885390082f*x)), 1.f);
}
__device__ __forceinline__ short f2b(float f){
  unsigned u=__float_as_uint(f); u += 0x7FFFu + ((u>>16)&1u); return (short)(u>>16);
}
__device__ __forceinline__ int pack2(float a, float b){
  return ((int)(unsigned short)f2b(a)) | (((int)(unsigned short)f2b(b))<<16);
}
#define B2F(s) __uint_as_float(((unsigned)(unsigned short)(s))<<16)
#define MFA(a,b,c) __builtin_amdgcn_mfma_f32_16x16x32_bf16(a,b,c,0,0,0)

// ---------------- we = relu(emb @ Wp + bp) : [10000,300]@[300,256] ----------
__global__ void k_we(const float* __restrict__ emb, const float* __restrict__ Wp,
                     const float* __restrict__ bp, float* __restrict__ we){
  __shared__ __align__(16) float As[16][INDIM];
  int r0 = blockIdx.x*16, tid = threadIdx.x;
  for(int i=tid;i<16*INDIM;i+=256){int lr=i/INDIM,d=i-lr*INDIM;
    As[lr][d]=emb[(long)(r0+lr)*INDIM+d];}
  __syncthreads();
  int cl=tid&63, rg=tid>>6;
  float acc[4][4];
  #pragma unroll
  for(int i=0;i<4;i++){acc[i][0]=acc[i][1]=acc[i][2]=acc[i][3]=0.f;}
  for(int k=0;k<INDIM;k+=4){
    float4 a4[4];
    #pragma unroll
    for(int i=0;i<4;i++) a4[i]=*(const float4*)&As[rg*4+i][k];
    #pragma unroll
    for(int j=0;j<4;j++){
      const float* wr=Wp+(long)(k+j)*SZ+cl;
      float w0=wr[0],w1=wr[64],w2=wr[128],w3=wr[192];
      #pragma unroll
      for(int i=0;i<4;i++){
        float a=(j==0)?a4[i].x:(j==1)?a4[i].y:(j==2)?a4[i].z:a4[i].w;
        acc[i][0]=fmaf(a,w0,acc[i][0]);acc[i][1]=fmaf(a,w1,acc[i][1]);
        acc[i][2]=fmaf(a,w2,acc[i][2]);acc[i][3]=fmaf(a,w3,acc[i][3]);
      }
    }
  }
  #pragma unroll
  for(int i=0;i<4;i++){
    int r=r0+rg*4+i;
    #pragma unroll
    for(int cc=0;cc<4;cc++){int col=cl+cc*64;
      we[(long)r*SZ+col]=fmaxf(acc[i][cc]+bp[col],0.f);}
  }
}

// ---- prep: Wh -> bf16 MFMA B-fragments, (dir,w,T2=s*4+g,ks,lane) tiling ----
__global__ void k_prep(const float* __restrict__ Wh_f, const float* __restrict__ Wh_b,
                       short* __restrict__ frag){
  int tid = blockIdx.x*256 + threadIdx.x;   // 65536 total
  int l=tid&63, f=(tid>>6)&63, w=(tid>>12)&7, dir=tid>>15;
  const float* Wh = dir? Wh_b : Wh_f;
  int ks=f&7, T2=f>>3, s2=T2>>2, g=T2&3;
  int col = g*256 + w*32 + s2*16 + (l&15);
  int k0  = ks*32 + (l>>4)*8;
  short v[8];
  #pragma unroll
  for(int j=0;j<8;j++) v[j]=f2b(Wh[(long)(k0+j)*FH + col]);
  *(bf16x8*)(frag + (long)tid*8) = *(bf16x8*)v;
}

// ---- prep: Wi -> bf16 B-frags: wf[((dir*64+ct)*8+ks)*512 + l*8 + j] --------
__global__ void k_prepwi(const float* __restrict__ Wi_f, const float* __restrict__ Wi_b,
                         short* __restrict__ wf){
  int tid = blockIdx.x*256 + threadIdx.x;   // 65536
  int l=tid&63, ks=(tid>>6)&7, ct=(tid>>9)&63, dir=tid>>15;
  const float* Wi = dir? Wi_b : Wi_f;
  int col = ct*16 + (l&15);
  int k0  = ks*32 + (l>>4)*8;
  short v[8];
  #pragma unroll
  for(int j=0;j<8;j++) v[j]=f2b(Wi[(long)(k0+j)*FH + col]);
  *(bf16x8*)(wf + (long)tid*8) = *(bf16x8*)v;
}

// ---- prep: Wenc -> bf16 B-frags: wef[(ct*16+ks)*512 + l*8 + j], K=512 ------
__global__ void k_prepenc(const float* __restrict__ Wenc, short* __restrict__ wef){
  int tid = blockIdx.x*256 + threadIdx.x;   // 16384
  int l=tid&63, ks=(tid>>6)&15, ct=tid>>10;
  int col = ct*16 + (l&15);
  int k0  = ks*32 + (l>>4)*8;
  short v[8];
  #pragma unroll
  for(int j=0;j<8;j++) v[j]=f2b(Wenc[(long)(k0+j)*SZ + col]);
  *(bf16x8*)(wef + (long)tid*8) = *(bf16x8*)v;
}

// ---- MFMA xwi: [64 rows]@[256x1024] bf16, epilogue writes LSTM frag layout -
__global__ void k_xwi_mfma(const int* __restrict__ seq, const int* __restrict__ len,
                      const float* __restrict__ srcw, long bstride,
                      const float* __restrict__ ctxtT, const int* __restrict__ idxmap,
                      const float* __restrict__ Wi_f, const float* __restrict__ bvf,
                      const float* __restrict__ Wi_b, const float* __restrict__ bvb,
                      const short* __restrict__ wf, int iseq, short* __restrict__ xwo){
  __shared__ __align__(16) short As[64*264];
  __shared__ const float* rowp[64];
  int bx=blockIdx.x, dir=bx>>5, blk=bx&31, tid=threadIdx.x;
  int w=tid>>6, l=tid&63;
  if(tid<64){
    int t = blk*4 + (tid>>4), b = tid&15;
    int lb=len[b];
    int tt=(dir==0)? t : ((t<lb)? (lb-1-t) : t);
    int tok=seq[b*LL+tt];
    const float* rp;
    if(idxmap){
      int im=idxmap[b*NW+tok];
      rp = (im>=0)? ctxtT+(long)im*SZ : srcw+(long)tok*SZ;
    }else{
      rp = srcw + (long)b*bstride + (long)tok*SZ;
    }
    rowp[tid]=rp;
  }
  __syncthreads();
  for(int i2=tid;i2<64*64;i2+=256){
    int lr=i2>>6, c4=(i2&63)*4;
    float4 v=*(const float4*)(rowp[lr]+c4);
    int2 pk; pk.x=pack2(v.x,v.y); pk.y=pack2(v.z,v.w);
    *(int2*)&As[lr*264+c4]=pk;
  }
  __syncthreads();
  const float* __restrict__ Wi = dir? Wi_b : Wi_f;
  const float* __restrict__ bv = dir? bvb : bvf;
  const short* wfd = wf + (long)dir*262144;
  for(int n2=0;n2<16;n2++){
    int ct = w*16 + n2;
    const short* bfp = wfd + ((long)ct*8)*512 + l*8;
    f32x4 Z={0.f,0.f,0.f,0.f};
    f32x4 C0=Z,C1=Z,C2=Z,C3=Z;
    #pragma unroll
    for(int ks=0;ks<8;ks++){
      bf16x8 bb=*(const bf16x8*)(bfp + ks*512);
      int ao = ks*32 + (l>>4)*8;
      bf16x8 a0=*(const bf16x8*)(&As[((l&15)    )*264 + ao]);
      bf16x8 a1=*(const bf16x8*)(&As[((l&15)+16 )*264 + ao]);
      bf16x8 a2=*(const bf16x8*)(&As[((l&15)+32 )*264 + ao]);
      bf16x8 a3=*(const bf16x8*)(&As[((l&15)+48 )*264 + ao]);
      C0=MFA(a0,bb,C0); C1=MFA(a1,bb,C1); C2=MFA(a2,bb,C2); C3=MFA(a3,bb,C3);
    }
    int g=ct>>4, w2=(ct&15)>>1, s2=ct&1;
    int col = g*256 + w2*32 + s2*16 + (l&15);
    float be = Wi[(long)(SZ+iseq)*FH+col] + bv[col];
    #pragma unroll
    for(int m=0;m<4;m++){
      f32x4 Cm = (m==0)?C0:(m==1)?C1:(m==2)?C2:C3;
      long base=((((long)dir*128 + blk*4 + m)*8 + w2)*64 + (l>>4)*16 + (l&15))*32
                + s2*16 + g*4;
      int2 pk; pk.x=pack2(Cm[0]+be,Cm[1]+be); pk.y=pack2(Cm[2]+be,Cm[3]+be);
      *(int2*)(xwo+base)=pk;
    }
  }
}

// ---- 64-row scalar rowgemm tile (used by fused-LSTM side blocks) -----------
__device__ __forceinline__ void rowgemm64(const float* __restrict__ A,
                                          const float* __restrict__ W,
                                          float* __restrict__ C,
                                          int n, int r0, int tid, float* Asf){
  for(int i=tid;i<64*SZ;i+=512){
    int lr=i>>8; int r=r0+lr;
    Asf[i]= (r<n)? A[(long)r*SZ+(i&255)] : 0.f;
  }
  __syncthreads();
  int cl=tid&63, rg=tid>>6;
  float acc[8][4];
  #pragma unroll
  for(int i=0;i<8;i++){acc[i][0]=acc[i][1]=acc[i][2]=acc[i][3]=0.f;}
  for(int k=0;k<SZ;k+=4){
    float4 a4[8];
    #pragma unroll
    for(int i=0;i<8;i++) a4[i]=*(const float4*)&Asf[(rg*8+i)*SZ+k];
    #pragma unroll
    for(int j=0;j<4;j++){
      const float* wr=W+(long)(k+j)*SZ+cl;
      float w0=wr[0],w1=wr[64],w2=wr[128],w3=wr[192];
      #pragma unroll
      for(int i=0;i<8;i++){
        float a=(j==0)?a4[i].x:(j==1)?a4[i].y:(j==2)?a4[i].z:a4[i].w;
        acc[i][0]=fmaf(a,w0,acc[i][0]);acc[i][1]=fmaf(a,w1,acc[i][1]);
        acc[i][2]=fmaf(a,w2,acc[i][2]);acc[i][3]=fmaf(a,w3,acc[i][3]);
      }
    }
  }
  #pragma unroll
  for(int i=0;i<8;i++){
    int r=r0+rg*8+i;
    if(r<n){
      #pragma unroll
      for(int cc=0;cc<4;cc++) C[(long)r*SZ+cl+cc*64]=acc[i][cc];
    }
  }
}

// --------- fused: blocks 0,1 = persistent LSTM; blocks 2+ = rowgemm tiles ---
#define LDFW(f)    (*(const bf16x8*)(fr + (long)(f)*512 + l*8))
#define LDLW(i2,ks) (*(const bf16x8*)(bl + ((i2)*8+(ks))*512 + l*8))
#define DECLWT(T) bf16x8 W##T##_0=LDFW((T)*8+0),W##T##_1=LDFW((T)*8+1),W##T##_2=LDFW((T)*8+2),W##T##_3=LDFW((T)*8+3),W##T##_4=LDFW((T)*8+4),W##T##_5=LDFW((T)*8+5),W##T##_6=LDFW((T)*8+6),W##T##_7=LDFW((T)*8+7);
#define MMRT(T,Cv) { Cv=MFA(A0,W##T##_0,Cv); Cv=MFA(A1,W##T##_1,Cv); Cv=MFA(A2,W##T##_2,Cv); Cv=MFA(A3,W##T##_3,Cv); Cv=MFA(A4,W##T##_4,Cv); Cv=MFA(A5,W##T##_5,Cv); Cv=MFA(A6,W##T##_6,Cv); Cv=MFA(A7,W##T##_7,Cv); }
#define MMLT(i2,Cv) { Cv=MFA(A0,LDLW(i2,0),Cv); Cv=MFA(A1,LDLW(i2,1),Cv); Cv=MFA(A2,LDLW(i2,2),Cv); Cv=MFA(A3,LDLW(i2,3),Cv); Cv=MFA(A4,LDLW(i2,4),Cv); Cv=MFA(A5,LDLW(i2,5),Cv); Cv=MFA(A6,LDLW(i2,6),Cv); Cv=MFA(A7,LDLW(i2,7),Cv); }
#define MMST(Cv) { Cv=MFA(A0,S0,Cv); Cv=MFA(A1,S1,Cv); Cv=MFA(A2,S2,Cv); Cv=MFA(A3,S3,Cv); Cv=MFA(A4,S4,Cv); Cv=MFA(A5,S5,Cv); Cv=MFA(A6,S6,Cv); Cv=MFA(A7,S7,Cv); }
#define LOADST(f0) S0=LDFW((f0)+0); S1=LDFW((f0)+1); S2=LDFW((f0)+2); S3=LDFW((f0)+3); S4=LDFW((f0)+4); S5=LDFW((f0)+5); S6=LDFW((f0)+6); S7=LDFW((f0)+7);
#define G1(s,r,CA,CB,CC,CD,XA,XB) { \
  float zi=CA[r]+B2F(XA[r]), zf=CB[r]+B2F(XA[4+(r)]), zg=CC[r]+B2F(XB[r]), zo=CD[r]+B2F(XB[4+(r)]); \
  cst_##s##_##r = sigf(zf)*cst_##s##_##r + sigf(zi)*tanhf_(zg); \
  float hv = sigf(zo)*tanhf_(cst_##s##_##r); \
  int b_=4*(l>>4)+(r); int u_=w*32+(s)*16+(l&15); \
  hbn[b_*264+u_]=f2b(hv); }
#define GP(s,CA,CB,CC,CD,XA,XB) \
  G1(s,0,CA,CB,CC,CD,XA,XB) G1(s,1,CA,CB,CC,CD,XA,XB) \
  G1(s,2,CA,CB,CC,CD,XA,XB) G1(s,3,CA,CB,CC,CD,XA,XB)

extern __shared__ char smem_raw[];

__global__ __launch_bounds__(512,2) void k_lstm_f(
    const short* __restrict__ frag, const short* __restrict__ xq,
    short* __restrict__ hgs,
    const float* __restrict__ gA1, const float* __restrict__ gW1,
    float* __restrict__ gC1, int n1,
    const float* __restrict__ gA2, const float* __restrict__ gW2,
    float* __restrict__ gC2, const int* __restrict__ cnt2, int ncap2){
  const int bid=blockIdx.x, tid=threadIdx.x;
  if(bid>=2){
    // independent dense GEMM tiles on otherwise-idle CUs
    float* Asf=(float*)smem_raw;
    int nb1=(n1+63)>>6;
    int gb=bid-2;
    if(gb<nb1){ rowgemm64(gA1,gW1,gC1,n1,gb*64,tid,Asf); }
    else if(cnt2){
      int n2=*cnt2; if(n2>ncap2)n2=ncap2;
      int r0=(gb-nb1)*64;
      if(r0<n2) rowgemm64(gA2,gW2,gC2,n2,r0,tid,Asf);
    }
    return;
  }
  const int dir=bid, w=tid>>6, l=tid&63;
  short* hb=(short*)smem_raw;                      // 2 x 16 x 264 shorts
  short* bl=(short*)(smem_raw+16896)+w*8192;       // per-wave LDS frags T2=4,5
  const short* fr = frag + (long)(dir*8+w)*32768;  // 64 frags * 512
  for(int i=tid;i<4224;i+=512) ((int*)smem_raw)[i]=0;
  #pragma unroll
  for(int c2=0;c2<16;c2++)
    *(f32x4*)(bl+c2*512+l*8) = *(const f32x4*)(fr+(long)(32+c2)*512+l*8);
  DECLWT(0) DECLWT(1) DECLWT(2) DECLWT(3)          // 32 resident frags
  float cst_0_0=0,cst_0_1=0,cst_0_2=0,cst_0_3=0,
        cst_1_0=0,cst_1_1=0,cst_1_2=0,cst_1_3=0;
  __syncthreads();
  const short* xwb = xq + ((long)dir*128*8 + w)*2048 + (long)l*32;
  short* hgb = hgs + (long)dir*524288;             // bf16 h-out [t][16][256]
  const int db=tid>>5, du=(tid&31)*8;              // dump coords
  bf16x8 S0,S1,S2,S3,S4,S5,S6,S7;
  for(int t=0;t<LL;t++){
    const int cur=t&1, nxt=cur^1;
    LOADST(48)                                     // stream T2=6 (early issue)
    const short* xp = xwb + (long)t*16384;
    bf16x8 X0=*(const bf16x8*)(xp+0), X1=*(const bf16x8*)(xp+8);
    const short* hr = hb + cur*4224 + (l&15)*264 + (l>>4)*8;
    bf16x8 A0=*(const bf16x8*)(hr+0),   A1=*(const bf16x8*)(hr+32),
           A2=*(const bf16x8*)(hr+64),  A3=*(const bf16x8*)(hr+96),
           A4=*(const bf16x8*)(hr+128), A5=*(const bf16x8*)(hr+160),
           A6=*(const bf16x8*)(hr+192), A7=*(const bf16x8*)(hr+224);
    f32x4 Z={0.f,0.f,0.f,0.f};
    f32x4 C00=Z,C01=Z,C02=Z,C03=Z,C10=Z,C11=Z,C12=Z,C13=Z;
    MMRT(0,C00) MMRT(1,C01) MMRT(2,C02) MMRT(3,C03)   // resident (32 MFMA)
    MMLT(0,C10) MMLT(1,C11)                           // LDS tiles (16 MFMA)
    MMST(C12)                                         // T2=6 streamed
    LOADST(56)                                        // stream T2=7 (issue)
    bf16x8 X2=*(const bf16x8*)(xp+16), X3=*(const bf16x8*)(xp+24);
    short* hbn = hb + nxt*4224;
    GP(0, C00,C01,C02,C03, X0,X1)                     // hides T2=7 latency
    MMST(C13)                                         // T2=7 streamed
    GP(1, C10,C11,C12,C13, X2,X3)
    __syncthreads();
    // coalesced bf16 h dump; store retires during next step (no drain stall)
    f32x4 hv4 = *(const f32x4*)(hbn + db*264 + du);
    *(f32x4*)(hgb + ((long)t*16 + db)*256 + du) = hv4;
  }
}

// ---- MFMA enc: [64 rows][K=512] @ Wenc frags -> relu(max) atomic scatter ---
__global__ void k_enc_mfma(const int* __restrict__ seq, const int* __restrict__ len,
                      const int* __restrict__ u2l, const short* __restrict__ hgs,
                      const short* __restrict__ wef, const float* __restrict__ benc,
                      unsigned int* __restrict__ lembuf, unsigned int* __restrict__ flags){
  __shared__ __align__(16) short As[64*520];
  __shared__ const short* pf16[64]; __shared__ const short* pb16[64];
  __shared__ int lem_s[64], val_s[64], b_s[64];
  int r0=blockIdx.x*64, tid=threadIdx.x, w=tid>>6, l=tid&63;
  if(tid<64){
    int r=r0+tid, b=r>>7, t=r&127, lb=len[b];
    int v=(t<lb); val_s[tid]=v; b_s[tid]=b;
    int lem=u2l[seq[r]]; lem_s[tid]=lem;
    pf16[tid]=hgs+((long)t*BB+b)*SZ;
    int tr=v? (lb-1-t) : t;
    pb16[tid]=hgs+((long)(LL+tr)*BB+b)*SZ;
    if(v) flags[(long)b*NLEM+lem]=1u;
  }
  __syncthreads();
  for(int i2=tid;i2<64*128;i2+=256){
    int lr=i2>>7, cc=(i2&127)*4;
    const short* sp=(cc<256)? pf16[lr]+cc : pb16[lr]+(cc-256);
    *(int2*)&As[lr*520+cc]=*(const int2*)sp;
  }
  __syncthreads();
  for(int n2=0;n2<4;n2++){
    int ct=w*4+n2;
    f32x4 Z={0.f,0.f,0.f,0.f};
    f32x4 C0=Z,C1=Z,C2=Z,C3=Z;
    #pragma unroll
    for(int ks=0;ks<16;ks++){
      bf16x8 bb=*(const bf16x8*)(wef+((long)(ct*16+ks))*512+l*8);
      int ao=ks*32+(l>>4)*8;
      bf16x8 a0=*(const bf16x8*)(&As[((l&15)    )*520+ao]);
      bf16x8 a1=*(const bf16x8*)(&As[((l&15)+16 )*520+ao]);
      bf16x8 a2=*(const bf16x8*)(&As[((l&15)+32 )*520+ao]);
      bf16x8 a3=*(const bf16x8*)(&As[((l&15)+48 )*520+ao]);
      C0=MFA(a0,bb,C0); C1=MFA(a1,bb,C1); C2=MFA(a2,bb,C2); C3=MFA(a3,bb,C3);
    }
    int col=ct*16+(l&15);
    float be=benc[col];
    #pragma unroll
    for(int m=0;m<4;m++){
      f32x4 Cm=(m==0)?C0:(m==1)?C1:(m==2)?C2:C3;
      #pragma unroll
      for(int reg=0;reg<4;reg++){
        int row=m*16+(l>>4)*4+reg;
        if(val_s[row]){
          float e=fmaxf(Cm[reg]+be,0.f);
          atomicMax(&lembuf[((long)b_s[row]*NLEM+lem_s[row])*SZ+col], __float_as_uint(e));
        }
      }
    }
  }
}

// ------------ generic C[r] = A[r] @ W  (K=256), optional touched-flags ------
__global__ void k_rowgemm(const float* __restrict__ A, const float* __restrict__ W,
                          float* __restrict__ C, const unsigned int* __restrict__ flags){
  __shared__ __align__(16) float As[16][SZ];
  __shared__ int any_s;
  int r0=blockIdx.x*16, tid=threadIdx.x;
  if(tid==0){
    int a = flags? 0 : 1;
    if(flags){ for(int i=0;i<16;i++) a |= (int)flags[r0+i]; }
    any_s=a;
  }
  __syncthreads();
  if(!any_s) return;
  for(int i=tid;i<16*SZ;i+=256){int lr=i>>8,j=i&(SZ-1);As[lr][j]=A[(long)(r0+lr)*SZ+j];}
  __syncthreads();
  int cl=tid&63, rg=tid>>6;
  float acc[4][4];
  #pragma unroll
  for(int i=0;i<4;i++){acc[i][0]=acc[i][1]=acc[i][2]=acc[i][3]=0.f;}
  for(int k=0;k<SZ;k+=4){
    float4 a4[4];
    #pragma unroll
    for(int i=0;i<4;i++) a4[i]=*(const float4*)&As[rg*4+i][k];
    #pragma unroll
    for(int j=0;j<4;j++){
      const float* wr=W+(long)(k+j)*SZ+cl;
      float w0=wr[0],w1=wr[64],w2=wr[128],w3=wr[192];
      #pragma unroll
      for(int i=0;i<4;i++){
        float a=(j==0)?a4[i].x:(j==1)?a4[i].y:(j==2)?a4[i].z:a4[i].w;
        acc[i][0]=fmaf(a,w0,acc[i][0]);acc[i][1]=fmaf(a,w1,acc[i][1]);
        acc[i][2]=fmaf(a,w2,acc[i][2]);acc[i][3]=fmaf(a,w3,acc[i][3]);
      }
    }
  }
  #pragma unroll
  for(int i=0;i<4;i++){
    int r=r0+rg*4+i;
    #pragma unroll
    for(int cc=0;cc<4;cc++) C[(long)r*SZ+cl+cc*64]=acc[i][cc];
  }
}

// ---- compact list of rows whose lemma was touched in iter 0 ----------------
__global__ void k_compact(const int* __restrict__ u2l, const unsigned int* __restrict__ flags,
                          int* __restrict__ cnt, int* __restrict__ list,
                          int* __restrict__ idxmap, int ncap){
  int r = blockIdx.x*256+threadIdx.x;
  if(r>=BB*NW) return;
  int b=r/NW, w=r-b*NW;
  int im=-1;
  if(flags[(long)b*NLEM+u2l[w]]){
    int idx=atomicAdd(cnt,1);
    if(idx<ncap){ list[idx]=r; im=idx; }
  }
  idxmap[r]=im;
}

// ---- gate for touched-only rows -> compact ctxtT ---------------------------
__global__ void k_gate0c(const float* __restrict__ we, const float* __restrict__ P0,
                         const float* __restrict__ Q, const float* __restrict__ lembuf,
                         const int* __restrict__ u2l, const float* __restrict__ bg,
                         const int* __restrict__ cnt, const int* __restrict__ list,
                         float* __restrict__ ctxtT, int ncap){
  int n=*cnt; if(n>ncap)n=ncap;
  long idx=(long)blockIdx.x*256+threadIdx.x;
  long i=idx>>6; int k4=(int)(idx&63);
  if(i>=n) return;
  int r=list[i]; int b=r/NW, w=r-b*NW;
  int lem=u2l[w];
  long qb=((long)b*NLEM+lem)*SZ;
  float4 p =((const float4*)(P0+(long)w*SZ))[k4];
  float4 wv=((const float4*)(we+(long)w*SZ))[k4];
  float4 bgv=((const float4*)bg)[k4];
  float4 q =((const float4*)(Q+qb))[k4];
  float4 nw=((const float4*)(lembuf+qb))[k4];
  float4 o;
  { float g=sigf(p.x+q.x+bgv.x); o.x=wv.x*g+(1.f-g)*nw.x; }
  { float g=sigf(p.y+q.y+bgv.y); o.y=wv.y*g+(1.f-g)*nw.y; }
  { float g=sigf(p.z+q.z+bgv.z); o.z=wv.z*g+(1.f-g)*nw.z; }
  { float g=sigf(p.w+q.w+bgv.w); o.w=wv.w*g+(1.f-g)*nw.w; }
  ((float4*)ctxtT)[i*64+k4]=o;
}

// ---- we <- we*sig(P0+bg)  (base0 in place; run after gate0c) ---------------
__global__ void k_base0ip(float* __restrict__ we, const float* __restrict__ P0,
                          const float* __restrict__ bg){
  long idx=(long)blockIdx.x*256+threadIdx.x;
  if(idx>=(long)NW*SZ/4) return;
  int k4=(int)(idx&63);
  float4 wv=((float4*)we)[idx];
  float4 p =((const float4*)P0)[idx];
  float4 bgv=((const float4*)bg)[k4];
  wv.x*=sigf(p.x+bgv.x); wv.y*=sigf(p.y+bgv.y);
  wv.z*=sigf(p.z+bgv.z); wv.w*=sigf(p.w+bgv.w);
  ((float4*)we)[idx]=wv;
}

// ------- iter-0 gate DENSE (fallback): full out write -----------------------
__global__ void k_gate0(const float* __restrict__ we, const float* __restrict__ P0,
                        const float* __restrict__ Q, const float* __restrict__ lembuf,
                        const int* __restrict__ u2l, const unsigned int* __restrict__ flags,
                        const float* __restrict__ bg, float* __restrict__ out){
  long idx=(long)blockIdx.x*256+threadIdx.x;
  const long TOTAL4=(long)BB*NW*SZ/4;
  if(idx>=TOTAL4) return;
  long row=idx>>6; int k4=(int)(idx&63);
  int r32=(int)row;
  int b=r32/NW, w=r32-b*NW;
  int lem=u2l[w];
  long qb=((long)b*NLEM+lem)*SZ;
  unsigned int fl=flags[(long)b*NLEM+lem];
  float4 p =((const float4*)(P0+(long)w*SZ))[k4];
  float4 wv=((const float4*)(we+(long)w*SZ))[k4];
  float4 bgv=((const float4*)bg)[k4];
  float4 q, nw;
  if(fl){ q=((const float4*)(Q+qb))[k4]; nw=((const float4*)(lembuf+qb))[k4]; }
  else  { q=make_float4(0.f,0.f,0.f,0.f); nw=q; }
  float4 o;
  { float g=sigf(p.x+q.x+bgv.x); o.x=wv.x*g+(1.f-g)*nw.x; }
  { float g=sigf(p.y+q.y+bgv.y); o.y=wv.y*g+(1.f-g)*nw.y; }
  { float g=sigf(p.z+q.z+bgv.z); o.z=wv.z*g+(1.f-g)*nw.z; }
  { float g=sigf(p.w+q.w+bgv.w); o.w=wv.w*g+(1.f-g)*nw.w; }
  ((float4*)out)[idx]=o;
}

// ------- iter-1 gate: cv from base0/ctxtT, p from P1b/Pt, write final out ---
__global__ void k_gate1e(const float* __restrict__ base0, const float* __restrict__ ctxtT,
                         const float* __restrict__ P1b, const float* __restrict__ Pt,
                         const int* __restrict__ idxmap,
                         const float* __restrict__ Q, const float* __restrict__ lembuf,
                         const int* __restrict__ u2l, const unsigned int* __restrict__ flags,
                         const float* __restrict__ bg, float* __restrict__ out){
  long idx=(long)blockIdx.x*256+threadIdx.x;
  const long TOTAL4=(long)BB*NW*SZ/4;
  if(idx>=TOTAL4) return;
  long row=idx>>6; int k4=(int)(idx&63);
  int r32=(int)row;
  int b=r32/NW, w=r32-b*NW;
  int im=idxmap[r32];
  int lem=u2l[w];
  long qb=((long)b*NLEM+lem)*SZ;
  unsigned int fl=flags[(long)b*NLEM+lem];
  float4 p, cv;
  if(im>=0){ p=((const float4*)(Pt+(long)im*SZ))[k4]; cv=((const float4*)(ctxtT+(long)im*SZ))[k4]; }
  else     { p=((const float4*)(P1b+(long)w*SZ))[k4]; cv=((const float4*)(base0+(long)w*SZ))[k4]; }
  float4 bgv=((const float4*)bg)[k4];
  float4 q, nw;
  if(fl){ q=((const float4*)(Q+qb))[k4]; nw=((const float4*)(lembuf+qb))[k4]; }
  else  { q=make_float4(0.f,0.f,0.f,0.f); nw=q; }
  float4 o;
  { float g=sigf(p.x+q.x+bgv.x); o.x=cv.x*g+(1.f-g)*nw.x; }
  { float g=sigf(p.y+q.y+bgv.y); o.y=cv.y*g+(1.f-g)*nw.y; }
  { float g=sigf(p.z+q.z+bgv.z); o.z=cv.z*g+(1.f-g)*nw.z; }
  { float g=sigf(p.w+q.w+bgv.w); o.w=cv.w*g+(1.f-g)*nw.w; }
  ((float4*)out)[idx]=o;
}

// ------- legacy dense iter-1 gate (fallback if ws too small) ----------------
__global__ void k_gate1(const float* __restrict__ ctxt, const float* __restrict__ Wg,
                        const float* __restrict__ Q, const float* __restrict__ lembuf,
                        const int* __restrict__ u2l, const unsigned int* __restrict__ flags,
                        const float* __restrict__ bg, float* __restrict__ out){
  __shared__ __align__(16) float As[64][SZ];
  __shared__ __align__(16) float Ws[64][SZ];
  __shared__ int lem_s[64];
  int r0=blockIdx.x*64, tid=threadIdx.x;
  for(int i=tid;i<64*SZ;i+=256){int lr=i>>8,j=i&(SZ-1);
    As[lr][j]=ctxt[(long)(r0+lr)*SZ+j];}
  if(tid<64){int r=r0+tid; lem_s[tid]=u2l[r%NW];}
  int cl=tid&63, rg=tid>>6;
  float acc[16][4];
  #pragma unroll
  for(int i=0;i<16;i++){acc[i][0]=acc[i][1]=acc[i][2]=acc[i][3]=0.f;}
  for(int kb=0;kb<4;kb++){
    __syncthreads();
    for(int i=tid;i<64*SZ;i+=256){int lr=i>>8,j=i&(SZ-1);
      Ws[lr][j]=Wg[(long)(kb*64+lr)*SZ+j];}
    __syncthreads();
    for(int k=0;k<64;k+=4){
      float4 a4[16];
      #pragma unroll
      for(int i=0;i<16;i++) a4[i]=*(const float4*)&As[rg*16+i][kb*64+k];
      #pragma unroll
      for(int j=0;j<4;j++){
        float w0=Ws[k+j][cl],w1=Ws[k+j][cl+64],w2=Ws[k+j][cl+128],w3=Ws[k+j][cl+192];
        #pragma unroll
        for(int i=0;i<16;i++){
          float a=(j==0)?a4[i].x:(j==1)?a4[i].y:(j==2)?a4[i].z:a4[i].w;
          acc[i][0]=fmaf(a,w0,acc[i][0]);acc[i][1]=fmaf(a,w1,acc[i][1]);
          acc[i][2]=fmaf(a,w2,acc[i][2]);acc[i][3]=fmaf(a,w3,acc[i][3]);
        }
      }
    }
  }
  #pragma unroll
  for(int i=0;i<16;i++){
    int lr=rg*16+i, r=r0+lr, b=r/NW;
    long base=((long)b*NLEM+lem_s[lr])*SZ;
    unsigned int fl=flags[(long)b*NLEM+lem_s[lr]];
    #pragma unroll
    for(int cc=0;cc<4;cc++){
      int col=cl+cc*64;
      float qv=0.f, nw=0.f;
      if(fl){ qv=Q[base+col]; nw=lembuf[base+col]; }
      float g=sigf(acc[i][cc]+qv+bg[col]);
      out[(long)r*SZ+col]=As[lr][col]*g+(1.f-g)*nw;
    }
  }
}

extern "C" void kernel_launch(void* const* d_in, const int* in_sizes, int n_in,
                              void* d_out, int out_size, void* d_ws, size_t ws_size,
                              hipStream_t stream){
  const float* emb  =(const float*)d_in[0];
  const float* Wp   =(const float*)d_in[1];
  const float* bp   =(const float*)d_in[2];
  const float* Wi_f =(const float*)d_in[3];
  const float* Wh_f =(const float*)d_in[4];
  const float* b_f  =(const float*)d_in[5];
  const float* Wi_b =(const float*)d_in[6];
  const float* Wh_b =(const float*)d_in[7];
  const float* b_b  =(const float*)d_in[8];
  const float* Wenc =(const float*)d_in[9];
  const float* benc =(const float*)d_in[10];
  const float* Wg   =(const float*)d_in[11];
  const float* bg   =(const float*)d_in[12];
  const int*   seq0 =(const int*)d_in[13];
  const int*   seq1 =(const int*)d_in[14];
  const int*   len0 =(const int*)d_in[15];
  const int*   len1 =(const int*)d_in[16];
  const int*   u2l  =(const int*)d_in[17];

  float* ws    = (float*)d_ws;
  float* we    = ws;                       // 2,560,000 (becomes base0 after iter0)
  float* xwi   = we    + 2560000;          // region 4,194,304 floats:
  float* ctxtT = xwi   + 2097152;          //   xq bf16 first half; ctxtT second
  float* hglob = xwi   + 4194304;          // 1,048,576 (bf16 h uses half)
  float* lembuf= hglob + 1048576;          // 12,288,000
  float* flags = lembuf+ 12288000;         // 48,000 (uint)
  float* Q     = flags + 48000;            // 12,288,000
  float* P0    = Q     + 12288000;         // 2,560,000 (becomes P1b after iter0)
  short* whb   = (short*)(P0 + 2560000);   // 524,288 shorts = 262,144 floats
  short* wifrag= whb + 524288;             // 524,288 shorts = 262,144 floats
  short* wefrag= wifrag + 524288;          // 131,072 shorts = 65,536 floats
  int*   idxmap= (int*)(P0 + 2560000 + 262144 + 262144 + 65536);   // 160,000
  int*   list  = idxmap + 160000;          // NCAP
  int*   cnt   = list + NCAP;              // 1 (+3 pad)
  float* Ptouch= (float*)(cnt + 4);        // NCAP*256
  long base_floats = (long)(Ptouch - ws);
  long avail = ((long)(ws_size/4) - base_floats)/SZ;
  int sparse_ok = (avail >= NCAP);
  float* out   = (float*)d_out;

  hipFuncSetAttribute((const void*)k_lstm_f,
                      hipFuncAttributeMaxDynamicSharedMemorySize, 147968);

  k_we<<<NW/16,256,0,stream>>>(emb,Wp,bp,we);
  k_prep<<<256,256,0,stream>>>(Wh_f,Wh_b,whb);
  k_prepwi<<<256,256,0,stream>>>(Wi_f,Wi_b,wifrag);
  k_prepenc<<<64,256,0,stream>>>(Wenc,wefrag);

  const int NB1=(NW+63)/64;  // 157

  // ---------------- iteration 0 ----------------
  hipMemsetAsync(lembuf,0,(size_t)(12288000+48000)*4,stream);
  k_xwi_mfma<<<64,256,0,stream>>>(seq0,len0,we,0L,nullptr,nullptr,
                                  Wi_f,b_f,Wi_b,b_b,wifrag,0,(short*)xwi);
  // LSTM0 on 2 CUs  ||  P0 = we@Wg1 on the other CUs
  k_lstm_f<<<2+NB1,512,147968,stream>>>(whb,(const short*)xwi,(short*)hglob,
                                        we,Wg,P0,NW,
                                        nullptr,nullptr,nullptr,nullptr,0);
  k_enc_mfma<<<BB*LL/64,256,0,stream>>>(seq0,len0,u2l,(const short*)hglob,wefrag,benc,
                                        (unsigned int*)lembuf,(unsigned int*)flags);
  k_rowgemm<<<BB*NLEM/16,256,0,stream>>>(lembuf,Wg+(long)SZ*SZ,Q,
                                         (const unsigned int*)flags);  // Q = nw@Wg2
  if(sparse_ok){
    hipMemsetAsync(cnt,0,4,stream);
    k_compact<<<(BB*NW+255)/256,256,0,stream>>>(u2l,(const unsigned int*)flags,
                                                cnt,list,idxmap,NCAP);
    k_gate0c<<<NCAP*64/256,256,0,stream>>>(we,P0,Q,lembuf,u2l,bg,cnt,list,ctxtT,NCAP);
    k_base0ip<<<(NW*SZ/4+255)/256,256,0,stream>>>(we,P0,bg);         // we <- base0
  }else{
    long nb=((long)BB*NW*SZ/4+255)/256;
    k_gate0<<<(int)nb,256,0,stream>>>(we,P0,Q,lembuf,u2l,
                                      (const unsigned int*)flags,bg,out);
  }

  // ---------------- iteration 1 ----------------
  hipMemsetAsync(lembuf,0,(size_t)(12288000+48000)*4,stream);
  if(sparse_ok){
    k_xwi_mfma<<<64,256,0,stream>>>(seq1,len1,we,0L,ctxtT,idxmap,
                                    Wi_f,b_f,Wi_b,b_b,wifrag,1,(short*)xwi);
    // LSTM1 on 2 CUs || P0 <- base0@Wg1 || Ptouch <- ctxtT@Wg1
    k_lstm_f<<<2+NB1+NCAP/64,512,147968,stream>>>(whb,(const short*)xwi,(short*)hglob,
                                                  we,Wg,P0,NW,
                                                  ctxtT,Wg,Ptouch,cnt,NCAP);
  }else{
    k_xwi_mfma<<<64,256,0,stream>>>(seq1,len1,out,(long)NW*SZ,nullptr,nullptr,
                                    Wi_f,b_f,Wi_b,b_b,wifrag,1,(short*)xwi);
    k_lstm_f<<<2,512,147968,stream>>>(whb,(const short*)xwi,(short*)hglob,
                                      nullptr,nullptr,nullptr,0,
                                      nullptr,nullptr,nullptr,nullptr,0);
  }
  k_enc_mfma<<<BB*LL/64,256,0,stream>>>(seq1,len1,u2l,(const short*)hglob,wefrag,benc,
                                        (unsigned int*)lembuf,(unsigned int*)flags);
  k_rowgemm<<<BB*NLEM/16,256,0,stream>>>(lembuf,Wg+(long)SZ*SZ,Q,
                                         (const unsigned int*)flags);  // Q = nw@Wg2
  if(sparse_ok){
    long nb=((long)BB*NW*SZ/4+255)/256;
    k_gate1e<<<(int)nb,256,0,stream>>>(we,ctxtT,P0,Ptouch,idxmap,Q,lembuf,u2l,
                                       (const unsigned int*)flags,bg,out);
  }else{
    k_gate1<<<BB*NW/64,256,0,stream>>>(out,Wg,Q,lembuf,u2l,
                                       (const unsigned int*)flags,bg,out);
  }
}

// Round 14
// 1261.073 us; speedup vs baseline: 1.2569x; 1.0026x over previous
//
#include <hip/hip_runtime.h>

#define NW    10000
#define INDIM 300
#define SZ    256
#define BB    16
#define LL    128
#define NLEM  3000
#define FH    1024   // 4*SZ
#define NCAP  8192
#define NB1   157    // (NW+63)/64

typedef short  bf16x8 __attribute__((ext_vector_type(8)));
typedef float  f32x4  __attribute__((ext_vector_type(4)));

__device__ __forceinline__ float sigf(float x){
  return __builtin_amdgcn_rcpf(1.f+__builtin_amdgcn_exp2f(-1.442695041f*x));
}
__device__ __forceinline__ float tanhf_(float x){
  return fmaf(-2.f, __builtin_amdgcn_rcpf(1.f+__builtin_amdgcn_exp2f(2.885390082f*x)), 1.f);
}
__device__ __forceinline__ short f2b(float f){
  unsigned u=__float_as_uint(f); u += 0x7FFFu + ((u>>16)&1u); return (short)(u>>16);
}
__device__ __forceinline__ int pack2(float a, float b){
  return ((int)(unsigned short)f2b(a)) | (((int)(unsigned short)f2b(b))<<16);
}
#define B2F(s) __uint_as_float(((unsigned)(unsigned short)(s))<<16)
#define MFA(a,b,c) __builtin_amdgcn_mfma_f32_16x16x32_bf16(a,b,c,0,0,0)

// ---- unified prep: Wh / Wi / Wenc / Wp -> bf16 MFMA B-fragments ------------
__global__ void k_prepall(const float* __restrict__ Wh_f, const float* __restrict__ Wh_b,
                          short* __restrict__ whb,
                          const float* __restrict__ Wi_f, const float* __restrict__ Wi_b,
                          short* __restrict__ wif,
                          const float* __restrict__ Wenc, short* __restrict__ wef,
                          const float* __restrict__ Wp, short* __restrict__ wpf){
  int bx=blockIdx.x, thr=threadIdx.x;
  if(bx<256){                       // Wh frags
    int tid=bx*256+thr;
    int l=tid&63, f=(tid>>6)&63, w=(tid>>12)&7, dir=tid>>15;
    const float* Wh = dir? Wh_b : Wh_f;
    int ks=f&7, T2=f>>3, s2=T2>>2, g=T2&3;
    int col = g*256 + w*32 + s2*16 + (l&15);
    int k0  = ks*32 + (l>>4)*8;
    short v[8];
    #pragma unroll
    for(int j=0;j<8;j++) v[j]=f2b(Wh[(long)(k0+j)*FH + col]);
    *(bf16x8*)(whb + (long)tid*8) = *(bf16x8*)v;
  }else if(bx<512){                 // Wi frags
    int tid=(bx-256)*256+thr;
    int l=tid&63, ks=(tid>>6)&7, ct=(tid>>9)&63, dir=tid>>15;
    const float* Wi = dir? Wi_b : Wi_f;
    int col = ct*16 + (l&15);
    int k0  = ks*32 + (l>>4)*8;
    short v[8];
    #pragma unroll
    for(int j=0;j<8;j++) v[j]=f2b(Wi[(long)(k0+j)*FH + col]);
    *(bf16x8*)(wif + (long)tid*8) = *(bf16x8*)v;
  }else if(bx<576){                 // Wenc frags (K=512)
    int tid=(bx-512)*256+thr;
    int l=tid&63, ks=(tid>>6)&15, ct=tid>>10;
    int col = ct*16 + (l&15);
    int k0  = ks*32 + (l>>4)*8;
    short v[8];
    #pragma unroll
    for(int j=0;j<8;j++) v[j]=f2b(Wenc[(long)(k0+j)*SZ + col]);
    *(bf16x8*)(wef + (long)tid*8) = *(bf16x8*)v;
  }else{                            // Wp frags (K=300 padded to 320)
    int tid2=(bx-576)*256+thr;      // 0..10239
    int l=tid2&63, frow=tid2>>6;    // frow 0..159: ct=frow/10, ks=frow%10
    int ct=frow/10, ks=frow-ct*10;
    int col=ct*16+(l&15);
    int k0=ks*32+(l>>4)*8;
    short v[8];
    #pragma unroll
    for(int j=0;j<8;j++){ int k=k0+j; v[j]=(k<INDIM)? f2b(Wp[(long)k*SZ+col]) : (short)0; }
    *(bf16x8*)(wpf + (long)frow*512 + l*8) = *(bf16x8*)v;
  }
}

// ---- MFMA we: relu(emb@Wp + bp), 64 rows/block, K padded to 320 ------------
__global__ void k_we_mfma(const float* __restrict__ emb, const short* __restrict__ wpf,
                          const float* __restrict__ bp, float* __restrict__ we){
  __shared__ __align__(16) short As[64*328];
  int r0=blockIdx.x*64, tid=threadIdx.x, w=tid>>6, l=tid&63;
  for(int i=tid;i<64*160;i+=256){
    int lr=i/160, c2=(i-lr*160)*2;
    int row=r0+lr;
    float e0=0.f,e1=0.f;
    if(row<NW){
      if(c2<INDIM)   e0=emb[(long)row*INDIM+c2];
      if(c2+1<INDIM) e1=emb[(long)row*INDIM+c2+1];
    }
    *(int*)&As[lr*328+c2]=pack2(e0,e1);
  }
  __syncthreads();
  for(int n2=0;n2<4;n2++){
    int ct=w*4+n2;
    f32x4 Z={0.f,0.f,0.f,0.f};
    f32x4 C0=Z,C1=Z,C2=Z,C3=Z;
    #pragma unroll
    for(int ks=0;ks<10;ks++){
      bf16x8 bb=*(const bf16x8*)(wpf+((long)(ct*10+ks))*512+l*8);
      int ao=ks*32+(l>>4)*8;
      bf16x8 a0=*(const bf16x8*)(&As[((l&15)    )*328+ao]);
      bf16x8 a1=*(const bf16x8*)(&As[((l&15)+16 )*328+ao]);
      bf16x8 a2=*(const bf16x8*)(&As[((l&15)+32 )*328+ao]);
      bf16x8 a3=*(const bf16x8*)(&As[((l&15)+48 )*328+ao]);
      C0=MFA(a0,bb,C0); C1=MFA(a1,bb,C1); C2=MFA(a2,bb,C2); C3=MFA(a3,bb,C3);
    }
    int col=ct*16+(l&15);
    float be=bp[col];
    #pragma unroll
    for(int m=0;m<4;m++){
      f32x4 Cm=(m==0)?C0:(m==1)?C1:(m==2)?C2:C3;
      #pragma unroll
      for(int reg=0;reg<4;reg++){
        int row=r0+m*16+(l>>4)*4+reg;
        if(row<NW) we[(long)row*SZ+col]=fmaxf(Cm[reg]+be,0.f);
      }
    }
  }
}

// ---- MFMA xwi: [64 rows]@[256x1024] bf16, epilogue writes LSTM frag layout -
__global__ void k_xwi_mfma(const int* __restrict__ seq, const int* __restrict__ len,
                      const float* __restrict__ srcw, long bstride,
                      const float* __restrict__ ctxtT, const int* __restrict__ idxmap,
                      const float* __restrict__ Wi_f, const float* __restrict__ bvf,
                      const float* __restrict__ Wi_b, const float* __restrict__ bvb,
                      const short* __restrict__ wf, int iseq, short* __restrict__ xwo){
  __shared__ __align__(16) short As[64*264];
  __shared__ const float* rowp[64];
  int bx=blockIdx.x, dir=bx>>5, blk=bx&31, tid=threadIdx.x;
  int w=tid>>6, l=tid&63;
  if(tid<64){
    int t = blk*4 + (tid>>4), b = tid&15;
    int lb=len[b];
    int tt=(dir==0)? t : ((t<lb)? (lb-1-t) : t);
    int tok=seq[b*LL+tt];
    const float* rp;
    if(idxmap){
      int im=idxmap[b*NW+tok];
      rp = (im>=0)? ctxtT+(long)im*SZ : srcw+(long)tok*SZ;
    }else{
      rp = srcw + (long)b*bstride + (long)tok*SZ;
    }
    rowp[tid]=rp;
  }
  __syncthreads();
  for(int i2=tid;i2<64*64;i2+=256){
    int lr=i2>>6, c4=(i2&63)*4;
    float4 v=*(const float4*)(rowp[lr]+c4);
    int2 pk; pk.x=pack2(v.x,v.y); pk.y=pack2(v.z,v.w);
    *(int2*)&As[lr*264+c4]=pk;
  }
  __syncthreads();
  const float* __restrict__ Wi = dir? Wi_b : Wi_f;
  const float* __restrict__ bv = dir? bvb : bvf;
  const short* wfd = wf + (long)dir*262144;
  for(int n2=0;n2<16;n2++){
    int ct = w*16 + n2;
    const short* bfp = wfd + ((long)ct*8)*512 + l*8;
    f32x4 Z={0.f,0.f,0.f,0.f};
    f32x4 C0=Z,C1=Z,C2=Z,C3=Z;
    #pragma unroll
    for(int ks=0;ks<8;ks++){
      bf16x8 bb=*(const bf16x8*)(bfp + ks*512);
      int ao = ks*32 + (l>>4)*8;
      bf16x8 a0=*(const bf16x8*)(&As[((l&15)    )*264 + ao]);
      bf16x8 a1=*(const bf16x8*)(&As[((l&15)+16 )*264 + ao]);
      bf16x8 a2=*(const bf16x8*)(&As[((l&15)+32 )*264 + ao]);
      bf16x8 a3=*(const bf16x8*)(&As[((l&15)+48 )*264 + ao]);
      C0=MFA(a0,bb,C0); C1=MFA(a1,bb,C1); C2=MFA(a2,bb,C2); C3=MFA(a3,bb,C3);
    }
    int g=ct>>4, w2=(ct&15)>>1, s2=ct&1;
    int col = g*256 + w2*32 + s2*16 + (l&15);
    float be = Wi[(long)(SZ+iseq)*FH+col] + bv[col];
    #pragma unroll
    for(int m=0;m<4;m++){
      f32x4 Cm = (m==0)?C0:(m==1)?C1:(m==2)?C2:C3;
      long base=((((long)dir*128 + blk*4 + m)*8 + w2)*64 + (l>>4)*16 + (l&15))*32
                + s2*16 + g*4;
      int2 pk; pk.x=pack2(Cm[0]+be,Cm[1]+be); pk.y=pack2(Cm[2]+be,Cm[3]+be);
      *(int2*)(xwo+base)=pk;
    }
  }
}

// ---- 64-row scalar rowgemm tile (used by fused-LSTM side blocks) -----------
__device__ __forceinline__ void rowgemm64(const float* __restrict__ A,
                                          const float* __restrict__ W,
                                          float* __restrict__ C,
                                          int n, int r0, int tid, float* Asf){
  for(int i=tid;i<64*SZ;i+=512){
    int lr=i>>8; int r=r0+lr;
    Asf[i]= (r<n)? A[(long)r*SZ+(i&255)] : 0.f;
  }
  __syncthreads();
  int cl=tid&63, rg=tid>>6;
  float acc[8][4];
  #pragma unroll
  for(int i=0;i<8;i++){acc[i][0]=acc[i][1]=acc[i][2]=acc[i][3]=0.f;}
  for(int k=0;k<SZ;k+=4){
    float4 a4[8];
    #pragma unroll
    for(int i=0;i<8;i++) a4[i]=*(const float4*)&Asf[(rg*8+i)*SZ+k];
    #pragma unroll
    for(int j=0;j<4;j++){
      const float* wr=W+(long)(k+j)*SZ+cl;
      float w0=wr[0],w1=wr[64],w2=wr[128],w3=wr[192];
      #pragma unroll
      for(int i=0;i<8;i++){
        float a=(j==0)?a4[i].x:(j==1)?a4[i].y:(j==2)?a4[i].z:a4[i].w;
        acc[i][0]=fmaf(a,w0,acc[i][0]);acc[i][1]=fmaf(a,w1,acc[i][1]);
        acc[i][2]=fmaf(a,w2,acc[i][2]);acc[i][3]=fmaf(a,w3,acc[i][3]);
      }
    }
  }
  #pragma unroll
  for(int i=0;i<8;i++){
    int r=r0+rg*8+i;
    if(r<n){
      #pragma unroll
      for(int cc=0;cc<4;cc++) C[(long)r*SZ+cl+cc*64]=acc[i][cc];
    }
  }
}

// --------- fused: blocks 0,1 = LSTM; others = gemm tiles / targeted zeroing -
#define LDFW(f)    (*(const bf16x8*)(fr + (long)(f)*512 + l*8))
#define LDLW(i2,ks) (*(const bf16x8*)(bl + ((i2)*8+(ks))*512 + l*8))
#define DECLWT(T) bf16x8 W##T##_0=LDFW((T)*8+0),W##T##_1=LDFW((T)*8+1),W##T##_2=LDFW((T)*8+2),W##T##_3=LDFW((T)*8+3),W##T##_4=LDFW((T)*8+4),W##T##_5=LDFW((T)*8+5),W##T##_6=LDFW((T)*8+6),W##T##_7=LDFW((T)*8+7);
#define MMRT(T,Cv) { Cv=MFA(A0,W##T##_0,Cv); Cv=MFA(A1,W##T##_1,Cv); Cv=MFA(A2,W##T##_2,Cv); Cv=MFA(A3,W##T##_3,Cv); Cv=MFA(A4,W##T##_4,Cv); Cv=MFA(A5,W##T##_5,Cv); Cv=MFA(A6,W##T##_6,Cv); Cv=MFA(A7,W##T##_7,Cv); }
#define MMLT(i2,Cv) { Cv=MFA(A0,LDLW(i2,0),Cv); Cv=MFA(A1,LDLW(i2,1),Cv); Cv=MFA(A2,LDLW(i2,2),Cv); Cv=MFA(A3,LDLW(i2,3),Cv); Cv=MFA(A4,LDLW(i2,4),Cv); Cv=MFA(A5,LDLW(i2,5),Cv); Cv=MFA(A6,LDLW(i2,6),Cv); Cv=MFA(A7,LDLW(i2,7),Cv); }
#define MMST(Cv) { Cv=MFA(A0,S0,Cv); Cv=MFA(A1,S1,Cv); Cv=MFA(A2,S2,Cv); Cv=MFA(A3,S3,Cv); Cv=MFA(A4,S4,Cv); Cv=MFA(A5,S5,Cv); Cv=MFA(A6,S6,Cv); Cv=MFA(A7,S7,Cv); }
#define LOADST(f0) S0=LDFW((f0)+0); S1=LDFW((f0)+1); S2=LDFW((f0)+2); S3=LDFW((f0)+3); S4=LDFW((f0)+4); S5=LDFW((f0)+5); S6=LDFW((f0)+6); S7=LDFW((f0)+7);
#define G1(s,r,CA,CB,CC,CD,XA,XB) { \
  float zi=CA[r]+B2F(XA[r]), zf=CB[r]+B2F(XA[4+(r)]), zg=CC[r]+B2F(XB[r]), zo=CD[r]+B2F(XB[4+(r)]); \
  cst_##s##_##r = sigf(zf)*cst_##s##_##r + sigf(zi)*tanhf_(zg); \
  float hv = sigf(zo)*tanhf_(cst_##s##_##r); \
  int b_=4*(l>>4)+(r); int u_=w*32+(s)*16+(l&15); \
  hbn[b_*264+u_]=f2b(hv); }
#define GP(s,CA,CB,CC,CD,XA,XB) \
  G1(s,0,CA,CB,CC,CD,XA,XB) G1(s,1,CA,CB,CC,CD,XA,XB) \
  G1(s,2,CA,CB,CC,CD,XA,XB) G1(s,3,CA,CB,CC,CD,XA,XB)

extern __shared__ char smem_raw[];

__global__ __launch_bounds__(512,2) void k_lstm_f(
    const short* __restrict__ frag, const short* __restrict__ xq,
    short* __restrict__ hgs,
    const float* __restrict__ gA1, const float* __restrict__ gW1,
    float* __restrict__ gC1, int n1,
    const float* __restrict__ gA2, const float* __restrict__ gW2,
    float* __restrict__ gC2, const int* __restrict__ cnt2, int ncap2,
    const int* __restrict__ zsA, const int* __restrict__ zsB,
    const int* __restrict__ u2l, float* __restrict__ lemz,
    int* __restrict__ flagz, int* __restrict__ cntz){
  const int bid=blockIdx.x, tid=threadIdx.x;
  if(bid>=2){
    int gb=bid-2;
    float* Asf=(float*)smem_raw;
    int nb1 = gA1 ? (n1+63)>>6 : 0;
    if(gb<nb1){ rowgemm64(gA1,gW1,gC1,n1,gb*64,tid,Asf); return; }
    gb-=nb1;
    int nb2 = gA2 ? (ncap2>>6) : 0;
    if(gb<nb2){
      int n2=*cnt2; if(n2>ncap2)n2=ncap2;
      int r0=gb*64;
      if(r0<n2) rowgemm64(gA2,gW2,gC2,n2,r0,tid,Asf);
      return;
    }
    gb-=nb2;
    if(zsA){
      if(gb<256){
        int r8=gb*8+(tid>>6); int b=r8>>7, t=r8&127;
        int lem=u2l[zsA[b*LL+t]];
        *(float4*)(lemz+((long)b*NLEM+lem)*SZ+(tid&63)*4)=make_float4(0.f,0.f,0.f,0.f);
        return;
      }
      gb-=256;
    }
    if(zsB){
      if(gb<256){
        int r8=gb*8+(tid>>6); int b=r8>>7, t=r8&127;
        int lem=u2l[zsB[b*LL+t]];
        *(float4*)(lemz+((long)b*NLEM+lem)*SZ+(tid&63)*4)=make_float4(0.f,0.f,0.f,0.f);
        return;
      }
      gb-=256;
    }
    { // flags zero (24 blocks) + cnt
      int idx=gb*512+tid;
      if(idx<12000) ((int4*)flagz)[idx]=make_int4(0,0,0,0);
      if(cntz && gb==0 && tid==0) *cntz=0;
    }
    return;
  }
  const int dir=bid, w=tid>>6, l=tid&63;
  short* hb=(short*)smem_raw;                      // 2 x 16 x 264 shorts
  short* bl=(short*)(smem_raw+16896)+w*8192;       // per-wave LDS frags T2=4,5
  const short* fr = frag + (long)(dir*8+w)*32768;  // 64 frags * 512
  for(int i=tid;i<4224;i+=512) ((int*)smem_raw)[i]=0;
  #pragma unroll
  for(int c2=0;c2<16;c2++)
    *(f32x4*)(bl+c2*512+l*8) = *(const f32x4*)(fr+(long)(32+c2)*512+l*8);
  DECLWT(0) DECLWT(1) DECLWT(2) DECLWT(3)          // 32 resident frags
  float cst_0_0=0,cst_0_1=0,cst_0_2=0,cst_0_3=0,
        cst_1_0=0,cst_1_1=0,cst_1_2=0,cst_1_3=0;
  __syncthreads();
  const short* xwb = xq + ((long)dir*128*8 + w)*2048 + (long)l*32;
  short* hgb = hgs + (long)dir*524288;             // bf16 h-out [t][16][256]
  const int db=tid>>5, du=(tid&31)*8;              // dump coords
  bf16x8 S0,S1,S2,S3,S4,S5,S6,S7;
  for(int t=0;t<LL;t++){
    const int cur=t&1, nxt=cur^1;
    LOADST(48)                                     // stream T2=6 (early issue)
    const short* xp = xwb + (long)t*16384;
    bf16x8 X0=*(const bf16x8*)(xp+0), X1=*(const bf16x8*)(xp+8);
    const short* hr = hb + cur*4224 + (l&15)*264 + (l>>4)*8;
    bf16x8 A0=*(const bf16x8*)(hr+0),   A1=*(const bf16x8*)(hr+32),
           A2=*(const bf16x8*)(hr+64),  A3=*(const bf16x8*)(hr+96),
           A4=*(const bf16x8*)(hr+128), A5=*(const bf16x8*)(hr+160),
           A6=*(const bf16x8*)(hr+192), A7=*(const bf16x8*)(hr+224);
    f32x4 Z={0.f,0.f,0.f,0.f};
    f32x4 C00=Z,C01=Z,C02=Z,C03=Z,C10=Z,C11=Z,C12=Z,C13=Z;
    MMRT(0,C00) MMRT(1,C01) MMRT(2,C02) MMRT(3,C03)   // resident (32 MFMA)
    MMLT(0,C10) MMLT(1,C11)                           // LDS tiles (16 MFMA)
    MMST(C12)                                         // T2=6 streamed
    LOADST(56)                                        // stream T2=7 (issue)
    bf16x8 X2=*(const bf16x8*)(xp+16), X3=*(const bf16x8*)(xp+24);
    short* hbn = hb + nxt*4224;
    GP(0, C00,C01,C02,C03, X0,X1)                     // hides T2=7 latency
    MMST(C13)                                         // T2=7 streamed
    GP(1, C10,C11,C12,C13, X2,X3)
    __syncthreads();
    // coalesced bf16 h dump; store retires during next step (no drain stall)
    f32x4 hv4 = *(const f32x4*)(hbn + db*264 + du);
    *(f32x4*)(hgb + ((long)t*16 + db)*256 + du) = hv4;
  }
}

// ---- MFMA enc: [64 rows][K=512] @ Wenc frags -> relu(max) atomic scatter ---
__global__ void k_enc_mfma(const int* __restrict__ seq, const int* __restrict__ len,
                      const int* __restrict__ u2l, const short* __restrict__ hgs,
                      const short* __restrict__ wef, const float* __restrict__ benc,
                      unsigned int* __restrict__ lembuf, unsigned int* __restrict__ flags){
  __shared__ __align__(16) short As[64*520];
  __shared__ const short* pf16[64]; __shared__ const short* pb16[64];
  __shared__ int lem_s[64], val_s[64], b_s[64];
  int r0=blockIdx.x*64, tid=threadIdx.x, w=tid>>6, l=tid&63;
  if(tid<64){
    int r=r0+tid, b=r>>7, t=r&127, lb=len[b];
    int v=(t<lb); val_s[tid]=v; b_s[tid]=b;
    int lem=u2l[seq[r]]; lem_s[tid]=lem;
    pf16[tid]=hgs+((long)t*BB+b)*SZ;
    int tr=v? (lb-1-t) : t;
    pb16[tid]=hgs+((long)(LL+tr)*BB+b)*SZ;
    if(v) flags[(long)b*NLEM+lem]=1u;
  }
  __syncthreads();
  for(int i2=tid;i2<64*128;i2+=256){
    int lr=i2>>7, cc=(i2&127)*4;
    const short* sp=(cc<256)? pf16[lr]+cc : pb16[lr]+(cc-256);
    *(int2*)&As[lr*520+cc]=*(const int2*)sp;
  }
  __syncthreads();
  for(int n2=0;n2<4;n2++){
    int ct=w*4+n2;
    f32x4 Z={0.f,0.f,0.f,0.f};
    f32x4 C0=Z,C1=Z,C2=Z,C3=Z;
    #pragma unroll
    for(int ks=0;ks<16;ks++){
      bf16x8 bb=*(const bf16x8*)(wef+((long)(ct*16+ks))*512+l*8);
      int ao=ks*32+(l>>4)*8;
      bf16x8 a0=*(const bf16x8*)(&As[((l&15)    )*520+ao]);
      bf16x8 a1=*(const bf16x8*)(&As[((l&15)+16 )*520+ao]);
      bf16x8 a2=*(const bf16x8*)(&As[((l&15)+32 )*520+ao]);
      bf16x8 a3=*(const bf16x8*)(&As[((l&15)+48 )*520+ao]);
      C0=MFA(a0,bb,C0); C1=MFA(a1,bb,C1); C2=MFA(a2,bb,C2); C3=MFA(a3,bb,C3);
    }
    int col=ct*16+(l&15);
    float be=benc[col];
    #pragma unroll
    for(int m=0;m<4;m++){
      f32x4 Cm=(m==0)?C0:(m==1)?C1:(m==2)?C2:C3;
      #pragma unroll
      for(int reg=0;reg<4;reg++){
        int row=m*16+(l>>4)*4+reg;
        if(val_s[row]){
          float e=fmaxf(Cm[reg]+be,0.f);
          atomicMax(&lembuf[((long)b_s[row]*NLEM+lem_s[row])*SZ+col], __float_as_uint(e));
        }
      }
    }
  }
}

// ------------ generic C[r] = A[r] @ W  (K=256), optional touched-flags ------
__global__ void k_rowgemm(const float* __restrict__ A, const float* __restrict__ W,
                          float* __restrict__ C, const unsigned int* __restrict__ flags){
  __shared__ __align__(16) float As[16][SZ];
  __shared__ int any_s;
  int r0=blockIdx.x*16, tid=threadIdx.x;
  if(tid==0){
    int a = flags? 0 : 1;
    if(flags){ for(int i=0;i<16;i++) a |= (int)flags[r0+i]; }
    any_s=a;
  }
  __syncthreads();
  if(!any_s) return;
  for(int i=tid;i<16*SZ;i+=256){int lr=i>>8,j=i&(SZ-1);As[lr][j]=A[(long)(r0+lr)*SZ+j];}
  __syncthreads();
  int cl=tid&63, rg=tid>>6;
  float acc[4][4];
  #pragma unroll
  for(int i=0;i<4;i++){acc[i][0]=acc[i][1]=acc[i][2]=acc[i][3]=0.f;}
  for(int k=0;k<SZ;k+=4){
    float4 a4[4];
    #pragma unroll
    for(int i=0;i<4;i++) a4[i]=*(const float4*)&As[rg*4+i][k];
    #pragma unroll
    for(int j=0;j<4;j++){
      const float* wr=W+(long)(k+j)*SZ+cl;
      float w0=wr[0],w1=wr[64],w2=wr[128],w3=wr[192];
      #pragma unroll
      for(int i=0;i<4;i++){
        float a=(j==0)?a4[i].x:(j==1)?a4[i].y:(j==2)?a4[i].z:a4[i].w;
        acc[i][0]=fmaf(a,w0,acc[i][0]);acc[i][1]=fmaf(a,w1,acc[i][1]);
        acc[i][2]=fmaf(a,w2,acc[i][2]);acc[i][3]=fmaf(a,w3,acc[i][3]);
      }
    }
  }
  #pragma unroll
  for(int i=0;i<4;i++){
    int r=r0+rg*4+i;
    #pragma unroll
    for(int cc=0;cc<4;cc++) C[(long)r*SZ+cl+cc*64]=acc[i][cc];
  }
}

// ---- compact list of rows whose lemma was touched in iter 0 ----------------
__global__ void k_compact(const int* __restrict__ u2l, const unsigned int* __restrict__ flags,
                          int* __restrict__ cnt, int* __restrict__ list,
                          int* __restrict__ idxmap, int ncap){
  int r = blockIdx.x*256+threadIdx.x;
  if(r>=BB*NW) return;
  int b=r/NW, w=r-b*NW;
  int im=-1;
  if(flags[(long)b*NLEM+u2l[w]]){
    int idx=atomicAdd(cnt,1);
    if(idx<ncap){ list[idx]=r; im=idx; }
  }
  idxmap[r]=im;
}

// ---- gate for touched-only rows -> compact ctxtT ---------------------------
__global__ void k_gate0c(const float* __restrict__ we, const float* __restrict__ P0,
                         const float* __restrict__ Q, const float* __restrict__ lembuf,
                         const int* __restrict__ u2l, const float* __restrict__ bg,
                         const int* __restrict__ cnt, const int* __restrict__ list,
                         float* __restrict__ ctxtT, int ncap){
  int n=*cnt; if(n>ncap)n=ncap;
  long idx=(long)blockIdx.x*256+threadIdx.x;
  long i=idx>>6; int k4=(int)(idx&63);
  if(i>=n) return;
  int r=list[i]; int b=r/NW, w=r-b*NW;
  int lem=u2l[w];
  long qb=((long)b*NLEM+lem)*SZ;
  float4 p =((const float4*)(P0+(long)w*SZ))[k4];
  float4 wv=((const float4*)(we+(long)w*SZ))[k4];
  float4 bgv=((const float4*)bg)[k4];
  float4 q =((const float4*)(Q+qb))[k4];
  float4 nw=((const float4*)(lembuf+qb))[k4];
  float4 o;
  { float g=sigf(p.x+q.x+bgv.x); o.x=wv.x*g+(1.f-g)*nw.x; }
  { float g=sigf(p.y+q.y+bgv.y); o.y=wv.y*g+(1.f-g)*nw.y; }
  { float g=sigf(p.z+q.z+bgv.z); o.z=wv.z*g+(1.f-g)*nw.z; }
  { float g=sigf(p.w+q.w+bgv.w); o.w=wv.w*g+(1.f-g)*nw.w; }
  ((float4*)ctxtT)[i*64+k4]=o;
}

// ---- we <- we*sig(P0+bg)  (base0 in place; run after gate0c) ---------------
__global__ void k_base0ip(float* __restrict__ we, const float* __restrict__ P0,
                          const float* __restrict__ bg){
  long idx=(long)blockIdx.x*256+threadIdx.x;
  if(idx>=(long)NW*SZ/4) return;
  int k4=(int)(idx&63);
  float4 wv=((float4*)we)[idx];
  float4 p =((const float4*)P0)[idx];
  float4 bgv=((const float4*)bg)[k4];
  wv.x*=sigf(p.x+bgv.x); wv.y*=sigf(p.y+bgv.y);
  wv.z*=sigf(p.z+bgv.z); wv.w*=sigf(p.w+bgv.w);
  ((float4*)we)[idx]=wv;
}

// ------- iter-0 gate DENSE (fallback): full out write -----------------------
__global__ void k_gate0(const float* __restrict__ we, const float* __restrict__ P0,
                        const float* __restrict__ Q, const float* __restrict__ lembuf,
                        const int* __restrict__ u2l, const unsigned int* __restrict__ flags,
                        const float* __restrict__ bg, float* __restrict__ out){
  long idx=(long)blockIdx.x*256+threadIdx.x;
  const long TOTAL4=(long)BB*NW*SZ/4;
  if(idx>=TOTAL4) return;
  long row=idx>>6; int k4=(int)(idx&63);
  int r32=(int)row;
  int b=r32/NW, w=r32-b*NW;
  int lem=u2l[w];
  long qb=((long)b*NLEM+lem)*SZ;
  unsigned int fl=flags[(long)b*NLEM+lem];
  float4 p =((const float4*)(P0+(long)w*SZ))[k4];
  float4 wv=((const float4*)(we+(long)w*SZ))[k4];
  float4 bgv=((const float4*)bg)[k4];
  float4 q, nw;
  if(fl){ q=((const float4*)(Q+qb))[k4]; nw=((const float4*)(lembuf+qb))[k4]; }
  else  { q=make_float4(0.f,0.f,0.f,0.f); nw=q; }
  float4 o;
  { float g=sigf(p.x+q.x+bgv.x); o.x=wv.x*g+(1.f-g)*nw.x; }
  { float g=sigf(p.y+q.y+bgv.y); o.y=wv.y*g+(1.f-g)*nw.y; }
  { float g=sigf(p.z+q.z+bgv.z); o.z=wv.z*g+(1.f-g)*nw.z; }
  { float g=sigf(p.w+q.w+bgv.w); o.w=wv.w*g+(1.f-g)*nw.w; }
  ((float4*)out)[idx]=o;
}

// ------- iter-1 gate: cv from base0/ctxtT, p from P1b/Pt, write final out ---
__global__ void k_gate1e(const float* __restrict__ base0, const float* __restrict__ ctxtT,
                         const float* __restrict__ P1b, const float* __restrict__ Pt,
                         const int* __restrict__ idxmap,
                         const float* __restrict__ Q, const float* __restrict__ lembuf,
                         const int* __restrict__ u2l, const unsigned int* __restrict__ flags,
                         const float* __restrict__ bg, float* __restrict__ out){
  long idx=(long)blockIdx.x*256+threadIdx.x;
  const long TOTAL4=(long)BB*NW*SZ/4;
  if(idx>=TOTAL4) return;
  long row=idx>>6; int k4=(int)(idx&63);
  int r32=(int)row;
  int b=r32/NW, w=r32-b*NW;
  int im=idxmap[r32];
  int lem=u2l[w];
  long qb=((long)b*NLEM+lem)*SZ;
  unsigned int fl=flags[(long)b*NLEM+lem];
  float4 p, cv;
  if(im>=0){ p=((const float4*)(Pt+(long)im*SZ))[k4]; cv=((const float4*)(ctxtT+(long)im*SZ))[k4]; }
  else     { p=((const float4*)(P1b+(long)w*SZ))[k4]; cv=((const float4*)(base0+(long)w*SZ))[k4]; }
  float4 bgv=((const float4*)bg)[k4];
  float4 q, nw;
  if(fl){ q=((const float4*)(Q+qb))[k4]; nw=((const float4*)(lembuf+qb))[k4]; }
  else  { q=make_float4(0.f,0.f,0.f,0.f); nw=q; }
  float4 o;
  { float g=sigf(p.x+q.x+bgv.x); o.x=cv.x*g+(1.f-g)*nw.x; }
  { float g=sigf(p.y+q.y+bgv.y); o.y=cv.y*g+(1.f-g)*nw.y; }
  { float g=sigf(p.z+q.z+bgv.z); o.z=cv.z*g+(1.f-g)*nw.z; }
  { float g=sigf(p.w+q.w+bgv.w); o.w=cv.w*g+(1.f-g)*nw.w; }
  ((float4*)out)[idx]=o;
}

// ------- legacy dense iter-1 gate (fallback if ws too small) ----------------
__global__ void k_gate1(const float* __restrict__ ctxt, const float* __restrict__ Wg,
                        const float* __restrict__ Q, const float* __restrict__ lembuf,
                        const int* __restrict__ u2l, const unsigned int* __restrict__ flags,
                        const float* __restrict__ bg, float* __restrict__ out){
  __shared__ __align__(16) float As[64][SZ];
  __shared__ __align__(16) float Ws[64][SZ];
  __shared__ int lem_s[64];
  int r0=blockIdx.x*64, tid=threadIdx.x;
  for(int i=tid;i<64*SZ;i+=256){int lr=i>>8,j=i&(SZ-1);
    As[lr][j]=ctxt[(long)(r0+lr)*SZ+j];}
  if(tid<64){int r=r0+tid; lem_s[tid]=u2l[r%NW];}
  int cl=tid&63, rg=tid>>6;
  float acc[16][4];
  #pragma unroll
  for(int i=0;i<16;i++){acc[i][0]=acc[i][1]=acc[i][2]=acc[i][3]=0.f;}
  for(int kb=0;kb<4;kb++){
    __syncthreads();
    for(int i=tid;i<64*SZ;i+=256){int lr=i>>8,j=i&(SZ-1);
      Ws[lr][j]=Wg[(long)(kb*64+lr)*SZ+j];}
    __syncthreads();
    for(int k=0;k<64;k+=4){
      float4 a4[16];
      #pragma unroll
      for(int i=0;i<16;i++) a4[i]=*(const float4*)&As[rg*16+i][kb*64+k];
      #pragma unroll
      for(int j=0;j<4;j++){
        float w0=Ws[k+j][cl],w1=Ws[k+j][cl+64],w2=Ws[k+j][cl+128],w3=Ws[k+j][cl+192];
        #pragma unroll
        for(int i=0;i<16;i++){
          float a=(j==0)?a4[i].x:(j==1)?a4[i].y:(j==2)?a4[i].z:a4[i].w;
          acc[i][0]=fmaf(a,w0,acc[i][0]);acc[i][1]=fmaf(a,w1,acc[i][1]);
          acc[i][2]=fmaf(a,w2,acc[i][2]);acc[i][3]=fmaf(a,w3,acc[i][3]);
        }
      }
    }
  }
  #pragma unroll
  for(int i=0;i<16;i++){
    int lr=rg*16+i, r=r0+lr, b=r/NW;
    long base=((long)b*NLEM+lem_s[lr])*SZ;
    unsigned int fl=flags[(long)b*NLEM+lem_s[lr]];
    #pragma unroll
    for(int cc=0;cc<4;cc++){
      int col=cl+cc*64;
      float qv=0.f, nw=0.f;
      if(fl){ qv=Q[base+col]; nw=lembuf[base+col]; }
      float g=sigf(acc[i][cc]+qv+bg[col]);
      out[(long)r*SZ+col]=As[lr][col]*g+(1.f-g)*nw;
    }
  }
}

extern "C" void kernel_launch(void* const* d_in, const int* in_sizes, int n_in,
                              void* d_out, int out_size, void* d_ws, size_t ws_size,
                              hipStream_t stream){
  const float* emb  =(const float*)d_in[0];
  const float* Wp   =(const float*)d_in[1];
  const float* bp   =(const float*)d_in[2];
  const float* Wi_f =(const float*)d_in[3];
  const float* Wh_f =(const float*)d_in[4];
  const float* b_f  =(const float*)d_in[5];
  const float* Wi_b =(const float*)d_in[6];
  const float* Wh_b =(const float*)d_in[7];
  const float* b_b  =(const float*)d_in[8];
  const float* Wenc =(const float*)d_in[9];
  const float* benc =(const float*)d_in[10];
  const float* Wg   =(const float*)d_in[11];
  const float* bg   =(const float*)d_in[12];
  const int*   seq0 =(const int*)d_in[13];
  const int*   seq1 =(const int*)d_in[14];
  const int*   len0 =(const int*)d_in[15];
  const int*   len1 =(const int*)d_in[16];
  const int*   u2l  =(const int*)d_in[17];

  float* ws    = (float*)d_ws;
  float* we    = ws;                       // 2,560,000 (becomes base0 after iter0)
  float* xwi   = we    + 2560000;          // region 4,194,304 floats:
  float* ctxtT = xwi   + 2097152;          //   xq bf16 first half; ctxtT second
  float* hglob = xwi   + 4194304;          // 1,048,576 (bf16 h uses half)
  float* lembuf= hglob + 1048576;          // 12,288,000
  float* flags = lembuf+ 12288000;         // 48,000 (uint)
  float* Q     = flags + 48000;            // 12,288,000
  float* P0    = Q     + 12288000;         // 2,560,000 (becomes P1b after iter0)
  short* whb   = (short*)(P0 + 2560000);   // 524,288 shorts = 262,144 floats
  short* wifrag= whb + 524288;             // 524,288 shorts = 262,144 floats
  short* wefrag= wifrag + 524288;          // 131,072 shorts = 65,536 floats
  short* wpfrag= wefrag + 131072;          // 81,920 shorts = 40,960 floats
  int*   idxmap= (int*)(P0 + 2560000 + 262144 + 262144 + 65536 + 40960); // 160,000
  int*   list  = idxmap + 160000;          // NCAP
  int*   cnt   = list + NCAP;              // 1 (+3 pad)
  float* Ptouch= (float*)(cnt + 4);        // NCAP*256
  long base_floats = (long)(Ptouch - ws);
  long avail = ((long)(ws_size/4) - base_floats)/SZ;
  int sparse_ok = (avail >= NCAP);
  float* out   = (float*)d_out;

  hipFuncSetAttribute((const void*)k_lstm_f,
                      hipFuncAttributeMaxDynamicSharedMemorySize, 147968);

  k_prepall<<<616,256,0,stream>>>(Wh_f,Wh_b,whb, Wi_f,Wi_b,wifrag,
                                  Wenc,wefrag, Wp,wpfrag);
  k_we_mfma<<<NB1,256,0,stream>>>(emb,wpfrag,bp,we);

  // ---------------- iteration 0 ----------------
  k_xwi_mfma<<<64,256,0,stream>>>(seq0,len0,we,0L,nullptr,nullptr,
                                  Wi_f,b_f,Wi_b,b_b,wifrag,0,(short*)xwi);
  // LSTM0 || P0=we@Wg1 || zero lembuf(seq0 rows) || zero flags+cnt
  k_lstm_f<<<2+NB1+256+24,512,147968,stream>>>(whb,(const short*)xwi,(short*)hglob,
      we,Wg,P0,NW, nullptr,nullptr,nullptr,nullptr,0,
      seq0,nullptr,u2l,lembuf,(int*)flags,cnt);
  k_enc_mfma<<<BB*LL/64,256,0,stream>>>(seq0,len0,u2l,(const short*)hglob,wefrag,benc,
                                        (unsigned int*)lembuf,(unsigned int*)flags);
  k_rowgemm<<<BB*NLEM/16,256,0,stream>>>(lembuf,Wg+(long)SZ*SZ,Q,
                                         (const unsigned int*)flags);  // Q = nw@Wg2
  if(sparse_ok){
    k_compact<<<(BB*NW+255)/256,256,0,stream>>>(u2l,(const unsigned int*)flags,
                                                cnt,list,idxmap,NCAP);
    k_gate0c<<<NCAP*64/256,256,0,stream>>>(we,P0,Q,lembuf,u2l,bg,cnt,list,ctxtT,NCAP);
    k_base0ip<<<(NW*SZ/4+255)/256,256,0,stream>>>(we,P0,bg);         // we <- base0
  }else{
    long nb=((long)BB*NW*SZ/4+255)/256;
    k_gate0<<<(int)nb,256,0,stream>>>(we,P0,Q,lembuf,u2l,
                                      (const unsigned int*)flags,bg,out);
  }

  // ---------------- iteration 1 ----------------
  if(sparse_ok){
    k_xwi_mfma<<<64,256,0,stream>>>(seq1,len1,we,0L,ctxtT,idxmap,
                                    Wi_f,b_f,Wi_b,b_b,wifrag,1,(short*)xwi);
    // LSTM1 || P0<-base0@Wg1 || Ptouch<-ctxtT@Wg1 || zero lembuf(seq0+seq1) || zero flags
    k_lstm_f<<<2+NB1+NCAP/64+256+256+24,512,147968,stream>>>(whb,(const short*)xwi,
        (short*)hglob, we,Wg,P0,NW, ctxtT,Wg,Ptouch,cnt,NCAP,
        seq0,seq1,u2l,lembuf,(int*)flags,nullptr);
  }else{
    k_xwi_mfma<<<64,256,0,stream>>>(seq1,len1,out,(long)NW*SZ,nullptr,nullptr,
                                    Wi_f,b_f,Wi_b,b_b,wifrag,1,(short*)xwi);
    k_lstm_f<<<2+256+256+24,512,147968,stream>>>(whb,(const short*)xwi,(short*)hglob,
        nullptr,nullptr,nullptr,0, nullptr,nullptr,nullptr,nullptr,0,
        seq0,seq1,u2l,lembuf,(int*)flags,nullptr);
  }
  k_enc_mfma<<<BB*LL/64,256,0,stream>>>(seq1,len1,u2l,(const short*)hglob,wefrag,benc,
                                        (unsigned int*)lembuf,(unsigned int*)flags);
  k_rowgemm<<<BB*NLEM/16,256,0,stream>>>(lembuf,Wg+(long)SZ*SZ,Q,
                                         (const unsigned int*)flags);  // Q = nw@Wg2
  if(sparse_ok){
    long nb=((long)BB*NW*SZ/4+255)/256;
    k_gate1e<<<(int)nb,256,0,stream>>>(we,ctxtT,P0,Ptouch,idxmap,Q,lembuf,u2l,
                                       (const unsigned int*)flags,bg,out);
  }else{
    k_gate1<<<BB*NW/64,256,0,stream>>>(out,Wg,Q,lembuf,u2l,
                                       (const unsigned int*)flags,bg,out);
  }
}

// Round 16
// 1185.688 us; speedup vs baseline: 1.3368x; 1.0636x over previous
//
#include <hip/hip_runtime.h>

#define NW    10000
#define INDIM 300
#define SZ    256
#define BB    16
#define LL    128
#define NLEM  3000
#define FH    1024   // 4*SZ
#define NCAP  8192
#define NB1   157    // (NW+63)/64
#define LEMCAP 4096

typedef short  bf16x8 __attribute__((ext_vector_type(8)));
typedef float  f32x4  __attribute__((ext_vector_type(4)));

__device__ __forceinline__ float sigf(float x){
  return __builtin_amdgcn_rcpf(1.f+__builtin_amdgcn_exp2f(-1.442695041f*x));
}
__device__ __forceinline__ float tanhf_(float x){
  return fmaf(-2.f, __builtin_amdgcn_rcpf(1.f+__builtin_amdgcn_exp2f(2.885390082f*x)), 1.f);
}
__device__ __forceinline__ short f2b(float f){
  unsigned u=__float_as_uint(f); u += 0x7FFFu + ((u>>16)&1u); return (short)(u>>16);
}
__device__ __forceinline__ int pack2(float a, float b){
  return ((int)(unsigned short)f2b(a)) | (((int)(unsigned short)f2b(b))<<16);
}
#define B2F(s) __uint_as_float(((unsigned)(unsigned short)(s))<<16)
#define MFA(a,b,c) __builtin_amdgcn_mfma_f32_16x16x32_bf16(a,b,c,0,0,0)

// ---- unified prep: Wh / Wi / Wenc / Wp -> bf16 MFMA B-fragments ------------
__global__ void k_prepall(const float* __restrict__ Wh_f, const float* __restrict__ Wh_b,
                          short* __restrict__ whb,
                          const float* __restrict__ Wi_f, const float* __restrict__ Wi_b,
                          short* __restrict__ wif,
                          const float* __restrict__ Wenc, short* __restrict__ wef,
                          const float* __restrict__ Wp, short* __restrict__ wpf){
  int bx=blockIdx.x, thr=threadIdx.x;
  if(bx<256){                       // Wh frags
    int tid=bx*256+thr;
    int l=tid&63, f=(tid>>6)&63, w=(tid>>12)&7, dir=tid>>15;
    const float* Wh = dir? Wh_b : Wh_f;
    int ks=f&7, T2=f>>3, s2=T2>>2, g=T2&3;
    int col = g*256 + w*32 + s2*16 + (l&15);
    int k0  = ks*32 + (l>>4)*8;
    short v[8];
    #pragma unroll
    for(int j=0;j<8;j++) v[j]=f2b(Wh[(long)(k0+j)*FH + col]);
    *(bf16x8*)(whb + (long)tid*8) = *(bf16x8*)v;
  }else if(bx<512){                 // Wi frags
    int tid=(bx-256)*256+thr;
    int l=tid&63, ks=(tid>>6)&7, ct=(tid>>9)&63, dir=tid>>15;
    const float* Wi = dir? Wi_b : Wi_f;
    int col = ct*16 + (l&15);
    int k0  = ks*32 + (l>>4)*8;
    short v[8];
    #pragma unroll
    for(int j=0;j<8;j++) v[j]=f2b(Wi[(long)(k0+j)*FH + col]);
    *(bf16x8*)(wif + (long)tid*8) = *(bf16x8*)v;
  }else if(bx<576){                 // Wenc frags (K=512)
    int tid=(bx-512)*256+thr;
    int l=tid&63, ks=(tid>>6)&15, ct=tid>>10;
    int col = ct*16 + (l&15);
    int k0  = ks*32 + (l>>4)*8;
    short v[8];
    #pragma unroll
    for(int j=0;j<8;j++) v[j]=f2b(Wenc[(long)(k0+j)*SZ + col]);
    *(bf16x8*)(wef + (long)tid*8) = *(bf16x8*)v;
  }else{                            // Wp frags (K=300 padded to 320)
    int tid2=(bx-576)*256+thr;      // 0..10239
    int l=tid2&63, frow=tid2>>6;    // frow 0..159: ct=frow/10, ks=frow%10
    int ct=frow/10, ks=frow-ct*10;
    int col=ct*16+(l&15);
    int k0=ks*32+(l>>4)*8;
    short v[8];
    #pragma unroll
    for(int j=0;j<8;j++){ int k=k0+j; v[j]=(k<INDIM)? f2b(Wp[(long)k*SZ+col]) : (short)0; }
    *(bf16x8*)(wpf + (long)frow*512 + l*8) = *(bf16x8*)v;
  }
}

// ---- MFMA we: relu(emb@Wp + bp), 64 rows/block, K padded to 320 ------------
__global__ void k_we_mfma(const float* __restrict__ emb, const short* __restrict__ wpf,
                          const float* __restrict__ bp, float* __restrict__ we){
  __shared__ __align__(16) short As[64*328];
  int r0=blockIdx.x*64, tid=threadIdx.x, w=tid>>6, l=tid&63;
  for(int i=tid;i<64*160;i+=256){
    int lr=i/160, c2=(i-lr*160)*2;
    int row=r0+lr;
    float e0=0.f,e1=0.f;
    if(row<NW){
      if(c2<INDIM)   e0=emb[(long)row*INDIM+c2];
      if(c2+1<INDIM) e1=emb[(long)row*INDIM+c2+1];
    }
    *(int*)&As[lr*328+c2]=pack2(e0,e1);
  }
  __syncthreads();
  for(int n2=0;n2<4;n2++){
    int ct=w*4+n2;
    f32x4 Z={0.f,0.f,0.f,0.f};
    f32x4 C0=Z,C1=Z,C2=Z,C3=Z;
    #pragma unroll
    for(int ks=0;ks<10;ks++){
      bf16x8 bb=*(const bf16x8*)(wpf+((long)(ct*10+ks))*512+l*8);
      int ao=ks*32+(l>>4)*8;
      bf16x8 a0=*(const bf16x8*)(&As[((l&15)    )*328+ao]);
      bf16x8 a1=*(const bf16x8*)(&As[((l&15)+16 )*328+ao]);
      bf16x8 a2=*(const bf16x8*)(&As[((l&15)+32 )*328+ao]);
      bf16x8 a3=*(const bf16x8*)(&As[((l&15)+48 )*328+ao]);
      C0=MFA(a0,bb,C0); C1=MFA(a1,bb,C1); C2=MFA(a2,bb,C2); C3=MFA(a3,bb,C3);
    }
    int col=ct*16+(l&15);
    float be=bp[col];
    #pragma unroll
    for(int m=0;m<4;m++){
      f32x4 Cm=(m==0)?C0:(m==1)?C1:(m==2)?C2:C3;
      #pragma unroll
      for(int reg=0;reg<4;reg++){
        int row=r0+m*16+(l>>4)*4+reg;
        if(row<NW) we[(long)row*SZ+col]=fmaxf(Cm[reg]+be,0.f);
      }
    }
  }
}

// ---- MFMA xwi: [64 rows]@[256x1024] bf16, epilogue writes LSTM frag layout -
__global__ void k_xwi_mfma(const int* __restrict__ seq, const int* __restrict__ len,
                      const float* __restrict__ srcw, long bstride,
                      const float* __restrict__ ctxtT, const int* __restrict__ idxmap,
                      const float* __restrict__ Wi_f, const float* __restrict__ bvf,
                      const float* __restrict__ Wi_b, const float* __restrict__ bvb,
                      const short* __restrict__ wf, int iseq, short* __restrict__ xwo){
  __shared__ __align__(16) short As[64*264];
  __shared__ const float* rowp[64];
  int bx=blockIdx.x, dir=bx>>5, blk=bx&31, tid=threadIdx.x;
  int w=tid>>6, l=tid&63;
  if(tid<64){
    int t = blk*4 + (tid>>4), b = tid&15;
    int lb=len[b];
    int tt=(dir==0)? t : ((t<lb)? (lb-1-t) : t);
    int tok=seq[b*LL+tt];
    const float* rp;
    if(idxmap){
      int im=idxmap[b*NW+tok];
      rp = (im>=0)? ctxtT+(long)im*SZ : srcw+(long)tok*SZ;
    }else{
      rp = srcw + (long)b*bstride + (long)tok*SZ;
    }
    rowp[tid]=rp;
  }
  __syncthreads();
  for(int i2=tid;i2<64*64;i2+=256){
    int lr=i2>>6, c4=(i2&63)*4;
    float4 v=*(const float4*)(rowp[lr]+c4);
    int2 pk; pk.x=pack2(v.x,v.y); pk.y=pack2(v.z,v.w);
    *(int2*)&As[lr*264+c4]=pk;
  }
  __syncthreads();
  const float* __restrict__ Wi = dir? Wi_b : Wi_f;
  const float* __restrict__ bv = dir? bvb : bvf;
  const short* wfd = wf + (long)dir*262144;
  for(int n2=0;n2<16;n2++){
    int ct = w*16 + n2;
    const short* bfp = wfd + ((long)ct*8)*512 + l*8;
    f32x4 Z={0.f,0.f,0.f,0.f};
    f32x4 C0=Z,C1=Z,C2=Z,C3=Z;
    #pragma unroll
    for(int ks=0;ks<8;ks++){
      bf16x8 bb=*(const bf16x8*)(bfp + ks*512);
      int ao = ks*32 + (l>>4)*8;
      bf16x8 a0=*(const bf16x8*)(&As[((l&15)    )*264 + ao]);
      bf16x8 a1=*(const bf16x8*)(&As[((l&15)+16 )*264 + ao]);
      bf16x8 a2=*(const bf16x8*)(&As[((l&15)+32 )*264 + ao]);
      bf16x8 a3=*(const bf16x8*)(&As[((l&15)+48 )*264 + ao]);
      C0=MFA(a0,bb,C0); C1=MFA(a1,bb,C1); C2=MFA(a2,bb,C2); C3=MFA(a3,bb,C3);
    }
    int g=ct>>4, w2=(ct&15)>>1, s2=ct&1;
    int col = g*256 + w2*32 + s2*16 + (l&15);
    float be = Wi[(long)(SZ+iseq)*FH+col] + bv[col];
    #pragma unroll
    for(int m=0;m<4;m++){
      f32x4 Cm = (m==0)?C0:(m==1)?C1:(m==2)?C2:C3;
      long base=((((long)dir*128 + blk*4 + m)*8 + w2)*64 + (l>>4)*16 + (l&15))*32
                + s2*16 + g*4;
      int2 pk; pk.x=pack2(Cm[0]+be,Cm[1]+be); pk.y=pack2(Cm[2]+be,Cm[3]+be);
      *(int2*)(xwo+base)=pk;
    }
  }
}

// ---- 64-row scalar rowgemm tile (512 threads; fused-LSTM side blocks) ------
__device__ __forceinline__ void rowgemm64(const float* __restrict__ A,
                                          const float* __restrict__ W,
                                          float* __restrict__ C,
                                          int n, int r0, int tid, float* Asf){
  for(int i=tid;i<64*SZ;i+=512){
    int lr=i>>8; int r=r0+lr;
    Asf[i]= (r<n)? A[(long)r*SZ+(i&255)] : 0.f;
  }
  __syncthreads();
  int cl=tid&63, rg=tid>>6;
  float acc[8][4];
  #pragma unroll
  for(int i=0;i<8;i++){acc[i][0]=acc[i][1]=acc[i][2]=acc[i][3]=0.f;}
  for(int k=0;k<SZ;k+=4){
    float4 a4[8];
    #pragma unroll
    for(int i=0;i<8;i++) a4[i]=*(const float4*)&Asf[(rg*8+i)*SZ+k];
    #pragma unroll
    for(int j=0;j<4;j++){
      const float* wr=W+(long)(k+j)*SZ+cl;
      float w0=wr[0],w1=wr[64],w2=wr[128],w3=wr[192];
      #pragma unroll
      for(int i=0;i<8;i++){
        float a=(j==0)?a4[i].x:(j==1)?a4[i].y:(j==2)?a4[i].z:a4[i].w;
        acc[i][0]=fmaf(a,w0,acc[i][0]);acc[i][1]=fmaf(a,w1,acc[i][1]);
        acc[i][2]=fmaf(a,w2,acc[i][2]);acc[i][3]=fmaf(a,w3,acc[i][3]);
      }
    }
  }
  #pragma unroll
  for(int i=0;i<8;i++){
    int r=r0+rg*8+i;
    if(r<n){
      #pragma unroll
      for(int cc=0;cc<4;cc++) C[(long)r*SZ+cl+cc*64]=acc[i][cc];
    }
  }
}

// --------- fused: blocks 0,1 = LSTM; others = gemm tiles / targeted zeroing -
#define LDFW(f)    (*(const bf16x8*)(fr + (long)(f)*512 + l*8))
#define LDLW(i2,ks) (*(const bf16x8*)(bl + ((i2)*8+(ks))*512 + l*8))
#define DECLWT(T) bf16x8 W##T##_0=LDFW((T)*8+0),W##T##_1=LDFW((T)*8+1),W##T##_2=LDFW((T)*8+2),W##T##_3=LDFW((T)*8+3),W##T##_4=LDFW((T)*8+4),W##T##_5=LDFW((T)*8+5),W##T##_6=LDFW((T)*8+6),W##T##_7=LDFW((T)*8+7);
#define MMRT(T,Cv) { Cv=MFA(A0,W##T##_0,Cv); Cv=MFA(A1,W##T##_1,Cv); Cv=MFA(A2,W##T##_2,Cv); Cv=MFA(A3,W##T##_3,Cv); Cv=MFA(A4,W##T##_4,Cv); Cv=MFA(A5,W##T##_5,Cv); Cv=MFA(A6,W##T##_6,Cv); Cv=MFA(A7,W##T##_7,Cv); }
#define MMLT(i2,Cv) { Cv=MFA(A0,LDLW(i2,0),Cv); Cv=MFA(A1,LDLW(i2,1),Cv); Cv=MFA(A2,LDLW(i2,2),Cv); Cv=MFA(A3,LDLW(i2,3),Cv); Cv=MFA(A4,LDLW(i2,4),Cv); Cv=MFA(A5,LDLW(i2,5),Cv); Cv=MFA(A6,LDLW(i2,6),Cv); Cv=MFA(A7,LDLW(i2,7),Cv); }
#define MMST(Cv) { Cv=MFA(A0,S0,Cv); Cv=MFA(A1,S1,Cv); Cv=MFA(A2,S2,Cv); Cv=MFA(A3,S3,Cv); Cv=MFA(A4,S4,Cv); Cv=MFA(A5,S5,Cv); Cv=MFA(A6,S6,Cv); Cv=MFA(A7,S7,Cv); }
#define LOADST(f0) S0=LDFW((f0)+0); S1=LDFW((f0)+1); S2=LDFW((f0)+2); S3=LDFW((f0)+3); S4=LDFW((f0)+4); S5=LDFW((f0)+5); S6=LDFW((f0)+6); S7=LDFW((f0)+7);
#define G1(s,r,CA,CB,CC,CD,XA,XB) { \
  float zi=CA[r]+B2F(XA[r]), zf=CB[r]+B2F(XA[4+(r)]), zg=CC[r]+B2F(XB[r]), zo=CD[r]+B2F(XB[4+(r)]); \
  cst_##s##_##r = sigf(zf)*cst_##s##_##r + sigf(zi)*tanhf_(zg); \
  float hv = sigf(zo)*tanhf_(cst_##s##_##r); \
  int b_=4*(l>>4)+(r); int u_=w*32+(s)*16+(l&15); \
  hbn[b_*264+u_]=f2b(hv); }
#define GP(s,CA,CB,CC,CD,XA,XB) \
  G1(s,0,CA,CB,CC,CD,XA,XB) G1(s,1,CA,CB,CC,CD,XA,XB) \
  G1(s,2,CA,CB,CC,CD,XA,XB) G1(s,3,CA,CB,CC,CD,XA,XB)

extern __shared__ char smem_raw[];

__global__ __launch_bounds__(512,2) void k_lstm_f(
    const short* __restrict__ frag, const short* __restrict__ xq,
    short* __restrict__ hgs,
    const float* __restrict__ gA1, const float* __restrict__ gW1,
    float* __restrict__ gC1, int n1,
    const float* __restrict__ gA2, const float* __restrict__ gW2,
    float* __restrict__ gC2, const int* __restrict__ cnt2, int ncap2,
    const int* __restrict__ zsA, const int* __restrict__ zsB,
    const int* __restrict__ u2l, float* __restrict__ lemz,
    int* __restrict__ flagz, int* __restrict__ cntz, int* __restrict__ lemcntz){
  const int bid=blockIdx.x, tid=threadIdx.x;
  if(bid>=2){
    int gb=bid-2;
    float* Asf=(float*)smem_raw;
    int nb1 = gA1 ? (n1+63)>>6 : 0;
    if(gb<nb1){ rowgemm64(gA1,gW1,gC1,n1,gb*64,tid,Asf); return; }
    gb-=nb1;
    int nb2 = gA2 ? (ncap2>>6) : 0;
    if(gb<nb2){
      int n2=*cnt2; if(n2>ncap2)n2=ncap2;
      int r0=gb*64;
      if(r0<n2) rowgemm64(gA2,gW2,gC2,n2,r0,tid,Asf);
      return;
    }
    gb-=nb2;
    if(zsA){
      if(gb<256){
        int r8=gb*8+(tid>>6); int b=r8>>7, t=r8&127;
        int lem=u2l[zsA[b*LL+t]];
        *(float4*)(lemz+((long)b*NLEM+lem)*SZ+(tid&63)*4)=make_float4(0.f,0.f,0.f,0.f);
        return;
      }
      gb-=256;
    }
    if(zsB){
      if(gb<256){
        int r8=gb*8+(tid>>6); int b=r8>>7, t=r8&127;
        int lem=u2l[zsB[b*LL+t]];
        *(float4*)(lemz+((long)b*NLEM+lem)*SZ+(tid&63)*4)=make_float4(0.f,0.f,0.f,0.f);
        return;
      }
      gb-=256;
    }
    { // flags zero (24 blocks) + counters
      int idx=gb*512+tid;
      if(idx<12000) ((int4*)flagz)[idx]=make_int4(0,0,0,0);
      if(gb==0 && tid==0 && cntz) *cntz=0;
      if(gb==0 && tid==1 && lemcntz) *lemcntz=0;
    }
    return;
  }
  const int dir=bid, w=tid>>6, l=tid&63;
  short* hb=(short*)smem_raw;                      // 2 x 16 x 264 shorts
  short* bl=(short*)(smem_raw+16896)+w*8192;       // per-wave LDS frags T2=4,5
  const short* fr = frag + (long)(dir*8+w)*32768;  // 64 frags * 512
  for(int i=tid;i<4224;i+=512) ((int*)smem_raw)[i]=0;
  #pragma unroll
  for(int c2=0;c2<16;c2++)
    *(f32x4*)(bl+c2*512+l*8) = *(const f32x4*)(fr+(long)(32+c2)*512+l*8);
  DECLWT(0) DECLWT(1) DECLWT(2) DECLWT(3)          // 32 resident frags
  float cst_0_0=0,cst_0_1=0,cst_0_2=0,cst_0_3=0,
        cst_1_0=0,cst_1_1=0,cst_1_2=0,cst_1_3=0;
  __syncthreads();
  const short* xwb = xq + ((long)dir*128*8 + w)*2048 + (long)l*32;
  short* hgb = hgs + (long)dir*524288;             // bf16 h-out [t][16][256]
  const int db=tid>>5, du=(tid&31)*8;              // dump coords
  bf16x8 S0,S1,S2,S3,S4,S5,S6,S7;
  for(int t=0;t<LL;t++){
    const int cur=t&1, nxt=cur^1;
    LOADST(48)                                     // stream T2=6 (early issue)
    const short* xp = xwb + (long)t*16384;
    bf16x8 X0=*(const bf16x8*)(xp+0), X1=*(const bf16x8*)(xp+8);
    const short* hr = hb + cur*4224 + (l&15)*264 + (l>>4)*8;
    bf16x8 A0=*(const bf16x8*)(hr+0),   A1=*(const bf16x8*)(hr+32),
           A2=*(const bf16x8*)(hr+64),  A3=*(const bf16x8*)(hr+96),
           A4=*(const bf16x8*)(hr+128), A5=*(const bf16x8*)(hr+160),
           A6=*(const bf16x8*)(hr+192), A7=*(const bf16x8*)(hr+224);
    f32x4 Z={0.f,0.f,0.f,0.f};
    f32x4 C00=Z,C01=Z,C02=Z,C03=Z,C10=Z,C11=Z,C12=Z,C13=Z;
    MMRT(0,C00) MMRT(1,C01) MMRT(2,C02) MMRT(3,C03)   // resident (32 MFMA)
    MMLT(0,C10) MMLT(1,C11)                           // LDS tiles (16 MFMA)
    MMST(C12)                                         // T2=6 streamed
    LOADST(56)                                        // stream T2=7 (issue)
    bf16x8 X2=*(const bf16x8*)(xp+16), X3=*(const bf16x8*)(xp+24);
    short* hbn = hb + nxt*4224;
    GP(0, C00,C01,C02,C03, X0,X1)                     // hides T2=7 latency
    MMST(C13)                                         // T2=7 streamed
    GP(1, C10,C11,C12,C13, X2,X3)
    __syncthreads();
    // coalesced bf16 h dump; store retires during next step (no drain stall)
    f32x4 hv4 = *(const f32x4*)(hbn + db*264 + du);
    *(f32x4*)(hgb + ((long)t*16 + db)*256 + du) = hv4;
  }
}

// ---- MFMA enc: relu(max) atomic scatter + touched-lemma list build ---------
__global__ void k_enc_mfma(const int* __restrict__ seq, const int* __restrict__ len,
                      const int* __restrict__ u2l, const short* __restrict__ hgs,
                      const short* __restrict__ wef, const float* __restrict__ benc,
                      unsigned int* __restrict__ lembuf, unsigned int* __restrict__ flags,
                      int* __restrict__ lemcnt, int* __restrict__ lemlist){
  __shared__ __align__(16) short As[64*520];
  __shared__ const short* pf16[64]; __shared__ const short* pb16[64];
  __shared__ int lem_s[64], val_s[64], b_s[64];
  int r0=blockIdx.x*64, tid=threadIdx.x, w=tid>>6, l=tid&63;
  if(tid<64){
    int r=r0+tid, b=r>>7, t=r&127, lb=len[b];
    int v=(t<lb); val_s[tid]=v; b_s[tid]=b;
    int lem=u2l[seq[r]]; lem_s[tid]=lem;
    pf16[tid]=hgs+((long)t*BB+b)*SZ;
    int tr=v? (lb-1-t) : t;
    pb16[tid]=hgs+((long)(LL+tr)*BB+b)*SZ;
    if(v){
      int fi=b*NLEM+lem;
      if(atomicExch(&flags[fi],1u)==0u){
        int pos=atomicAdd(lemcnt,1);
        if(pos<LEMCAP) lemlist[pos]=fi;     // structurally <=2048 < LEMCAP
      }
    }
  }
  __syncthreads();
  for(int i2=tid;i2<64*128;i2+=256){
    int lr=i2>>7, cc=(i2&127)*4;
    const short* sp=(cc<256)? pf16[lr]+cc : pb16[lr]+(cc-256);
    *(int2*)&As[lr*520+cc]=*(const int2*)sp;
  }
  __syncthreads();
  for(int n2=0;n2<4;n2++){
    int ct=w*4+n2;
    f32x4 Z={0.f,0.f,0.f,0.f};
    f32x4 C0=Z,C1=Z,C2=Z,C3=Z;
    #pragma unroll
    for(int ks=0;ks<16;ks++){
      bf16x8 bb=*(const bf16x8*)(wef+((long)(ct*16+ks))*512+l*8);
      int ao=ks*32+(l>>4)*8;
      bf16x8 a0=*(const bf16x8*)(&As[((l&15)    )*520+ao]);
      bf16x8 a1=*(const bf16x8*)(&As[((l&15)+16 )*520+ao]);
      bf16x8 a2=*(const bf16x8*)(&As[((l&15)+32 )*520+ao]);
      bf16x8 a3=*(const bf16x8*)(&As[((l&15)+48 )*520+ao]);
      C0=MFA(a0,bb,C0); C1=MFA(a1,bb,C1); C2=MFA(a2,bb,C2); C3=MFA(a3,bb,C3);
    }
    int col=ct*16+(l&15);
    float be=benc[col];
    #pragma unroll
    for(int m=0;m<4;m++){
      f32x4 Cm=(m==0)?C0:(m==1)?C1:(m==2)?C2:C3;
      #pragma unroll
      for(int reg=0;reg<4;reg++){
        int row=m*16+(l>>4)*4+reg;
        if(val_s[row]){
          float e=fmaxf(Cm[reg]+be,0.f);
          atomicMax(&lembuf[((long)b_s[row]*NLEM+lem_s[row])*SZ+col], __float_as_uint(e));
        }
      }
    }
  }
}

// ---- 16-row gathered rowgemm over lemlist rows: Q[rl] = lembuf[rl] @ Wg2 ---
__device__ __forceinline__ void qgemm16(const float* __restrict__ lembuf,
                                        const float* __restrict__ W,
                                        float* __restrict__ Q,
                                        const int* __restrict__ lemcnt,
                                        const int* __restrict__ lemlist,
                                        int g0, int tid, float* Asf, int* rl_s){
  int n=*lemcnt; if(n>LEMCAP)n=LEMCAP;
  int r0=g0*16;
  if(r0>=n) return;
  if(tid<16){ int i=r0+tid; rl_s[tid]=(i<n)? lemlist[i] : -1; }
  __syncthreads();
  for(int i=tid;i<16*SZ;i+=256){int lr=i>>8,j=i&(SZ-1);
    Asf[i]= (rl_s[lr]>=0)? lembuf[(long)rl_s[lr]*SZ+j] : 0.f;}
  __syncthreads();
  int cl=tid&63, rg=tid>>6;
  float acc[4][4];
  #pragma unroll
  for(int i=0;i<4;i++){acc[i][0]=acc[i][1]=acc[i][2]=acc[i][3]=0.f;}
  for(int k=0;k<SZ;k+=4){
    float4 a4[4];
    #pragma unroll
    for(int i=0;i<4;i++) a4[i]=*(const float4*)&Asf[(rg*4+i)*SZ+k];
    #pragma unroll
    for(int j=0;j<4;j++){
      const float* wr=W+(long)(k+j)*SZ+cl;
      float w0=wr[0],w1=wr[64],w2=wr[128],w3=wr[192];
      #pragma unroll
      for(int i=0;i<4;i++){
        float a=(j==0)?a4[i].x:(j==1)?a4[i].y:(j==2)?a4[i].z:a4[i].w;
        acc[i][0]=fmaf(a,w0,acc[i][0]);acc[i][1]=fmaf(a,w1,acc[i][1]);
        acc[i][2]=fmaf(a,w2,acc[i][2]);acc[i][3]=fmaf(a,w3,acc[i][3]);
      }
    }
  }
  #pragma unroll
  for(int i=0;i<4;i++){
    int rl=rl_s[rg*4+i];
    if(rl>=0){
      #pragma unroll
      for(int cc=0;cc<4;cc++) Q[(long)rl*SZ+cl+cc*64]=acc[i][cc];
    }
  }
}

// ---- merged post-enc kernel: [Q-gemm | compact] sections (NO base0ip here:
// gate0c must read the ORIGINAL we — R15 bug) --------------------------------
__global__ void k_mid(const float* __restrict__ lembuf, const float* __restrict__ Wg2,
                      float* __restrict__ Q, const int* __restrict__ lemcnt,
                      const int* __restrict__ lemlist,
                      const int* __restrict__ u2l, const unsigned int* __restrict__ flags,
                      int* __restrict__ cnt, int* __restrict__ list,
                      int* __restrict__ idxmap, int docompact){
  __shared__ __align__(16) float Asf[16*SZ];
  __shared__ int rl_s[16];
  int bx=blockIdx.x, tid=threadIdx.x;
  if(bx<LEMCAP/16){           // Q section: 256 blocks
    qgemm16(lembuf,Wg2,Q,lemcnt,lemlist,bx,tid,Asf,rl_s);
    return;
  }
  bx-=LEMCAP/16;
  if(docompact && bx<625){    // compact section
    int r=bx*256+tid;
    if(r<BB*NW){
      int b=r/NW, w2=r-b*NW;
      int im=-1;
      if(flags[(long)b*NLEM+u2l[w2]]){
        int idx=atomicAdd(cnt,1);
        if(idx<NCAP){ list[idx]=r; im=idx; }
      }
      idxmap[r]=im;
    }
  }
}

// ---- we <- we*sig(P0+bg)  (run AFTER gate0c) -------------------------------
__global__ void k_base0ip(float* __restrict__ we, const float* __restrict__ P0,
                          const float* __restrict__ bg){
  long idx=(long)blockIdx.x*256+threadIdx.x;
  if(idx>=(long)NW*SZ/4) return;
  int k4=(int)(idx&63);
  float4 wv=((float4*)we)[idx];
  float4 p =((const float4*)P0)[idx];
  float4 bgv=((const float4*)bg)[k4];
  wv.x*=sigf(p.x+bgv.x); wv.y*=sigf(p.y+bgv.y);
  wv.z*=sigf(p.z+bgv.z); wv.w*=sigf(p.w+bgv.w);
  ((float4*)we)[idx]=wv;
}

// ---- gate for touched-only rows -> compact ctxtT ---------------------------
__global__ void k_gate0c(const float* __restrict__ we, const float* __restrict__ P0,
                         const float* __restrict__ Q, const float* __restrict__ lembuf,
                         const int* __restrict__ u2l, const float* __restrict__ bg,
                         const int* __restrict__ cnt, const int* __restrict__ list,
                         float* __restrict__ ctxtT, int ncap){
  int n=*cnt; if(n>ncap)n=ncap;
  long idx=(long)blockIdx.x*256+threadIdx.x;
  long i=idx>>6; int k4=(int)(idx&63);
  if(i>=n) return;
  int r=list[i]; int b=r/NW, w=r-b*NW;
  int lem=u2l[w];
  long qb=((long)b*NLEM+lem)*SZ;
  float4 p =((const float4*)(P0+(long)w*SZ))[k4];
  float4 wv=((const float4*)(we+(long)w*SZ))[k4];
  float4 bgv=((const float4*)bg)[k4];
  float4 q =((const float4*)(Q+qb))[k4];
  float4 nw=((const float4*)(lembuf+qb))[k4];
  float4 o;
  { float g=sigf(p.x+q.x+bgv.x); o.x=wv.x*g+(1.f-g)*nw.x; }
  { float g=sigf(p.y+q.y+bgv.y); o.y=wv.y*g+(1.f-g)*nw.y; }
  { float g=sigf(p.z+q.z+bgv.z); o.z=wv.z*g+(1.f-g)*nw.z; }
  { float g=sigf(p.w+q.w+bgv.w); o.w=wv.w*g+(1.f-g)*nw.w; }
  ((float4*)ctxtT)[i*64+k4]=o;
}

// ------- iter-0 gate DENSE (fallback): full out write -----------------------
__global__ void k_gate0(const float* __restrict__ we, const float* __restrict__ P0,
                        const float* __restrict__ Q, const float* __restrict__ lembuf,
                        const int* __restrict__ u2l, const unsigned int* __restrict__ flags,
                        const float* __restrict__ bg, float* __restrict__ out){
  long idx=(long)blockIdx.x*256+threadIdx.x;
  const long TOTAL4=(long)BB*NW*SZ/4;
  if(idx>=TOTAL4) return;
  long row=idx>>6; int k4=(int)(idx&63);
  int r32=(int)row;
  int b=r32/NW, w=r32-b*NW;
  int lem=u2l[w];
  long qb=((long)b*NLEM+lem)*SZ;
  unsigned int fl=flags[(long)b*NLEM+lem];
  float4 p =((const float4*)(P0+(long)w*SZ))[k4];
  float4 wv=((const float4*)(we+(long)w*SZ))[k4];
  float4 bgv=((const float4*)bg)[k4];
  float4 q, nw;
  if(fl){ q=((const float4*)(Q+qb))[k4]; nw=((const float4*)(lembuf+qb))[k4]; }
  else  { q=make_float4(0.f,0.f,0.f,0.f); nw=q; }
  float4 o;
  { float g=sigf(p.x+q.x+bgv.x); o.x=wv.x*g+(1.f-g)*nw.x; }
  { float g=sigf(p.y+q.y+bgv.y); o.y=wv.y*g+(1.f-g)*nw.y; }
  { float g=sigf(p.z+q.z+bgv.z); o.z=wv.z*g+(1.f-g)*nw.z; }
  { float g=sigf(p.w+q.w+bgv.w); o.w=wv.w*g+(1.f-g)*nw.w; }
  ((float4*)out)[idx]=o;
}

// ------- iter-1 gate: cv from base0/ctxtT, p from P1b/Pt, write final out ---
__global__ void k_gate1e(const float* __restrict__ base0, const float* __restrict__ ctxtT,
                         const float* __restrict__ P1b, const float* __restrict__ Pt,
                         const int* __restrict__ idxmap,
                         const float* __restrict__ Q, const float* __restrict__ lembuf,
                         const int* __restrict__ u2l, const unsigned int* __restrict__ flags,
                         const float* __restrict__ bg, float* __restrict__ out){
  long idx=(long)blockIdx.x*256+threadIdx.x;
  const long TOTAL4=(long)BB*NW*SZ/4;
  if(idx>=TOTAL4) return;
  long row=idx>>6; int k4=(int)(idx&63);
  int r32=(int)row;
  int b=r32/NW, w=r32-b*NW;
  int im=idxmap[r32];
  int lem=u2l[w];
  long qb=((long)b*NLEM+lem)*SZ;
  unsigned int fl=flags[(long)b*NLEM+lem];
  float4 p, cv;
  if(im>=0){ p=((const float4*)(Pt+(long)im*SZ))[k4]; cv=((const float4*)(ctxtT+(long)im*SZ))[k4]; }
  else     { p=((const float4*)(P1b+(long)w*SZ))[k4]; cv=((const float4*)(base0+(long)w*SZ))[k4]; }
  float4 bgv=((const float4*)bg)[k4];
  float4 q, nw;
  if(fl){ q=((const float4*)(Q+qb))[k4]; nw=((const float4*)(lembuf+qb))[k4]; }
  else  { q=make_float4(0.f,0.f,0.f,0.f); nw=q; }
  float4 o;
  { float g=sigf(p.x+q.x+bgv.x); o.x=cv.x*g+(1.f-g)*nw.x; }
  { float g=sigf(p.y+q.y+bgv.y); o.y=cv.y*g+(1.f-g)*nw.y; }
  { float g=sigf(p.z+q.z+bgv.z); o.z=cv.z*g+(1.f-g)*nw.z; }
  { float g=sigf(p.w+q.w+bgv.w); o.w=cv.w*g+(1.f-g)*nw.w; }
  ((float4*)out)[idx]=o;
}

// ------- legacy dense iter-1 gate (fallback if ws too small) ----------------
__global__ void k_gate1(const float* __restrict__ ctxt, const float* __restrict__ Wg,
                        const float* __restrict__ Q, const float* __restrict__ lembuf,
                        const int* __restrict__ u2l, const unsigned int* __restrict__ flags,
                        const float* __restrict__ bg, float* __restrict__ out){
  __shared__ __align__(16) float As[64][SZ];
  __shared__ __align__(16) float Ws[64][SZ];
  __shared__ int lem_s[64];
  int r0=blockIdx.x*64, tid=threadIdx.x;
  for(int i=tid;i<64*SZ;i+=256){int lr=i>>8,j=i&(SZ-1);
    As[lr][j]=ctxt[(long)(r0+lr)*SZ+j];}
  if(tid<64){int r=r0+tid; lem_s[tid]=u2l[r%NW];}
  int cl=tid&63, rg=tid>>6;
  float acc[16][4];
  #pragma unroll
  for(int i=0;i<16;i++){acc[i][0]=acc[i][1]=acc[i][2]=acc[i][3]=0.f;}
  for(int kb=0;kb<4;kb++){
    __syncthreads();
    for(int i=tid;i<64*SZ;i+=256){int lr=i>>8,j=i&(SZ-1);
      Ws[lr][j]=Wg[(long)(kb*64+lr)*SZ+j];}
    __syncthreads();
    for(int k=0;k<64;k+=4){
      float4 a4[16];
      #pragma unroll
      for(int i=0;i<16;i++) a4[i]=*(const float4*)&As[rg*16+i][kb*64+k];
      #pragma unroll
      for(int j=0;j<4;j++){
        float w0=Ws[k+j][cl],w1=Ws[k+j][cl+64],w2=Ws[k+j][cl+128],w3=Ws[k+j][cl+192];
        #pragma unroll
        for(int i=0;i<16;i++){
          float a=(j==0)?a4[i].x:(j==1)?a4[i].y:(j==2)?a4[i].z:a4[i].w;
          acc[i][0]=fmaf(a,w0,acc[i][0]);acc[i][1]=fmaf(a,w1,acc[i][1]);
          acc[i][2]=fmaf(a,w2,acc[i][2]);acc[i][3]=fmaf(a,w3,acc[i][3]);
        }
      }
    }
  }
  #pragma unroll
  for(int i=0;i<16;i++){
    int lr=rg*16+i, r=r0+lr, b=r/NW;
    long base=((long)b*NLEM+lem_s[lr])*SZ;
    unsigned int fl=flags[(long)b*NLEM+lem_s[lr]];
    #pragma unroll
    for(int cc=0;cc<4;cc++){
      int col=cl+cc*64;
      float qv=0.f, nw=0.f;
      if(fl){ qv=Q[base+col]; nw=lembuf[base+col]; }
      float g=sigf(acc[i][cc]+qv+bg[col]);
      out[(long)r*SZ+col]=As[lr][col]*g+(1.f-g)*nw;
    }
  }
}

extern "C" void kernel_launch(void* const* d_in, const int* in_sizes, int n_in,
                              void* d_out, int out_size, void* d_ws, size_t ws_size,
                              hipStream_t stream){
  const float* emb  =(const float*)d_in[0];
  const float* Wp   =(const float*)d_in[1];
  const float* bp   =(const float*)d_in[2];
  const float* Wi_f =(const float*)d_in[3];
  const float* Wh_f =(const float*)d_in[4];
  const float* b_f  =(const float*)d_in[5];
  const float* Wi_b =(const float*)d_in[6];
  const float* Wh_b =(const float*)d_in[7];
  const float* b_b  =(const float*)d_in[8];
  const float* Wenc =(const float*)d_in[9];
  const float* benc =(const float*)d_in[10];
  const float* Wg   =(const float*)d_in[11];
  const float* bg   =(const float*)d_in[12];
  const int*   seq0 =(const int*)d_in[13];
  const int*   seq1 =(const int*)d_in[14];
  const int*   len0 =(const int*)d_in[15];
  const int*   len1 =(const int*)d_in[16];
  const int*   u2l  =(const int*)d_in[17];

  float* ws    = (float*)d_ws;
  float* we    = ws;                       // 2,560,000 (becomes base0 after iter0)
  float* xwi   = we    + 2560000;          // region 4,194,304 floats:
  float* ctxtT = xwi   + 2097152;          //   xq bf16 first half; ctxtT second
  float* hglob = xwi   + 4194304;          // 1,048,576 (bf16 h uses half)
  float* lembuf= hglob + 1048576;          // 12,288,000
  float* flags = lembuf+ 12288000;         // 48,000 (uint)
  float* Q     = flags + 48000;            // 12,288,000
  float* P0    = Q     + 12288000;         // 2,560,000 (becomes P1b after iter0)
  short* whb   = (short*)(P0 + 2560000);   // 524,288 shorts = 262,144 floats
  short* wifrag= whb + 524288;             // 524,288 shorts = 262,144 floats
  short* wefrag= wifrag + 524288;          // 131,072 shorts = 65,536 floats
  short* wpfrag= wefrag + 131072;          // 81,920 shorts = 40,960 floats
  int*   idxmap= (int*)(P0 + 2560000 + 262144 + 262144 + 65536 + 40960); // 160,000
  int*   list  = idxmap + 160000;          // NCAP
  int*   cnt   = list + NCAP;              // 1
  int*   lemcnt= cnt + 1;                  // 1 (+2 pad)
  int*   lemlist=cnt + 4;                  // LEMCAP
  float* Ptouch= (float*)(lemlist + LEMCAP); // NCAP*256
  long base_floats = (long)(Ptouch - ws);
  long avail = ((long)(ws_size/4) - base_floats)/SZ;
  int sparse_ok = (avail >= NCAP);
  float* out   = (float*)d_out;

  hipFuncSetAttribute((const void*)k_lstm_f,
                      hipFuncAttributeMaxDynamicSharedMemorySize, 147968);

  k_prepall<<<616,256,0,stream>>>(Wh_f,Wh_b,whb, Wi_f,Wi_b,wifrag,
                                  Wenc,wefrag, Wp,wpfrag);
  k_we_mfma<<<NB1,256,0,stream>>>(emb,wpfrag,bp,we);

  // ---------------- iteration 0 ----------------
  k_xwi_mfma<<<64,256,0,stream>>>(seq0,len0,we,0L,nullptr,nullptr,
                                  Wi_f,b_f,Wi_b,b_b,wifrag,0,(short*)xwi);
  // LSTM0 || P0=we@Wg1 || zero lembuf(seq0 rows) || zero flags+cnt+lemcnt
  k_lstm_f<<<2+NB1+256+24,512,147968,stream>>>(whb,(const short*)xwi,(short*)hglob,
      we,Wg,P0,NW, nullptr,nullptr,nullptr,nullptr,0,
      seq0,nullptr,u2l,lembuf,(int*)flags,cnt,lemcnt);
  k_enc_mfma<<<BB*LL/64,256,0,stream>>>(seq0,len0,u2l,(const short*)hglob,wefrag,benc,
                                        (unsigned int*)lembuf,(unsigned int*)flags,
                                        lemcnt,lemlist);
  if(sparse_ok){
    // Q(lemlist) || compact   (base0ip must NOT run before gate0c)
    k_mid<<<LEMCAP/16+625,256,0,stream>>>(lembuf,Wg+(long)SZ*SZ,Q,lemcnt,lemlist,
        u2l,(const unsigned int*)flags,cnt,list,idxmap,1);
    k_gate0c<<<NCAP*64/256,256,0,stream>>>(we,P0,Q,lembuf,u2l,bg,cnt,list,ctxtT,NCAP);
    k_base0ip<<<(NW*SZ/4+255)/256,256,0,stream>>>(we,P0,bg);   // we <- base0 (after gate0c)
  }else{
    k_mid<<<LEMCAP/16,256,0,stream>>>(lembuf,Wg+(long)SZ*SZ,Q,lemcnt,lemlist,
        u2l,nullptr,nullptr,nullptr,nullptr,0);
    long nb=((long)BB*NW*SZ/4+255)/256;
    k_gate0<<<(int)nb,256,0,stream>>>(we,P0,Q,lembuf,u2l,
                                      (const unsigned int*)flags,bg,out);
  }

  // ---------------- iteration 1 ----------------
  if(sparse_ok){
    k_xwi_mfma<<<64,256,0,stream>>>(seq1,len1,we,0L,ctxtT,idxmap,
                                    Wi_f,b_f,Wi_b,b_b,wifrag,1,(short*)xwi);
    // LSTM1 || P0<-base0@Wg1 || Ptouch<-ctxtT@Wg1 || zero lembuf(seq0+seq1)+flags+lemcnt
    k_lstm_f<<<2+NB1+NCAP/64+256+256+24,512,147968,stream>>>(whb,(const short*)xwi,
        (short*)hglob, we,Wg,P0,NW, ctxtT,Wg,Ptouch,cnt,NCAP,
        seq0,seq1,u2l,lembuf,(int*)flags,nullptr,lemcnt);
  }else{
    k_xwi_mfma<<<64,256,0,stream>>>(seq1,len1,out,(long)NW*SZ,nullptr,nullptr,
                                    Wi_f,b_f,Wi_b,b_b,wifrag,1,(short*)xwi);
    k_lstm_f<<<2+256+256+24,512,147968,stream>>>(whb,(const short*)xwi,(short*)hglob,
        nullptr,nullptr,nullptr,0, nullptr,nullptr,nullptr,nullptr,0,
        seq0,seq1,u2l,lembuf,(int*)flags,nullptr,lemcnt);
  }
  k_enc_mfma<<<BB*LL/64,256,0,stream>>>(seq1,len1,u2l,(const short*)hglob,wefrag,benc,
                                        (unsigned int*)lembuf,(unsigned int*)flags,
                                        lemcnt,lemlist);
  k_mid<<<LEMCAP/16,256,0,stream>>>(lembuf,Wg+(long)SZ*SZ,Q,lemcnt,lemlist,
      u2l,nullptr,nullptr,nullptr,nullptr,0);
  if(sparse_ok){
    long nb=((long)BB*NW*SZ/4+255)/256;
    k_gate1e<<<(int)nb,256,0,stream>>>(we,ctxtT,P0,Ptouch,idxmap,Q,lembuf,u2l,
                                       (const unsigned int*)flags,bg,out);
  }else{
    k_gate1<<<BB*NW/64,256,0,stream>>>(out,Wg,Q,lembuf,u2l,
                                       (const unsigned int*)flags,bg,out);
  }
}

// Round 17
// 1166.914 us; speedup vs baseline: 1.3583x; 1.0161x over previous
//
#include <hip/hip_runtime.h>

#define NW    10000
#define INDIM 300
#define SZ    256
#define BB    16
#define LL    128
#define NLEM  3000
#define FH    1024   // 4*SZ
#define NCAP  8192
#define NB1   157    // (NW+63)/64
#define LEMCAP 4096
#define LOG2E 1.44269504f

typedef short  bf16x8 __attribute__((ext_vector_type(8)));
typedef float  f32x4  __attribute__((ext_vector_type(4)));

__device__ __forceinline__ float sigf(float x){
  return __builtin_amdgcn_rcpf(1.f+__builtin_amdgcn_exp2f(-LOG2E*x));
}
__device__ __forceinline__ float tanhf_(float x){
  return fmaf(-2.f, __builtin_amdgcn_rcpf(1.f+__builtin_amdgcn_exp2f(2.f*LOG2E*x)), 1.f);
}
// scaled-input versions: input is already z*LOG2E (weights/x pre-scaled)
__device__ __forceinline__ float sigs(float x){
  return __builtin_amdgcn_rcpf(1.f+__builtin_amdgcn_exp2f(-x));
}
__device__ __forceinline__ float tanhs(float x){
  return fmaf(-2.f, __builtin_amdgcn_rcpf(1.f+__builtin_amdgcn_exp2f(x+x)), 1.f);
}
__device__ __forceinline__ short f2b(float f){
  unsigned u=__float_as_uint(f); u += 0x7FFFu + ((u>>16)&1u); return (short)(u>>16);
}
__device__ __forceinline__ int pack2(float a, float b){
  return ((int)(unsigned short)f2b(a)) | (((int)(unsigned short)f2b(b))<<16);
}
#define B2F(s) __uint_as_float(((unsigned)(unsigned short)(s))<<16)
#define MFA(a,b,c) __builtin_amdgcn_mfma_f32_16x16x32_bf16(a,b,c,0,0,0)

// ---- unified prep: Wh(LOG2E-scaled) / Wi / Wenc / Wp -> bf16 MFMA B-frags --
__global__ void k_prepall(const float* __restrict__ Wh_f, const float* __restrict__ Wh_b,
                          short* __restrict__ whb,
                          const float* __restrict__ Wi_f, const float* __restrict__ Wi_b,
                          short* __restrict__ wif,
                          const float* __restrict__ Wenc, short* __restrict__ wef,
                          const float* __restrict__ Wp, short* __restrict__ wpf){
  int bx=blockIdx.x, thr=threadIdx.x;
  if(bx<256){                       // Wh frags (scaled by LOG2E for exp2 gates)
    int tid=bx*256+thr;
    int l=tid&63, f=(tid>>6)&63, w=(tid>>12)&7, dir=tid>>15;
    const float* Wh = dir? Wh_b : Wh_f;
    int ks=f&7, T2=f>>3, s2=T2>>2, g=T2&3;
    int col = g*256 + w*32 + s2*16 + (l&15);
    int k0  = ks*32 + (l>>4)*8;
    short v[8];
    #pragma unroll
    for(int j=0;j<8;j++) v[j]=f2b(LOG2E*Wh[(long)(k0+j)*FH + col]);
    *(bf16x8*)(whb + (long)tid*8) = *(bf16x8*)v;
  }else if(bx<512){                 // Wi frags (unscaled; xwi epilogue scales)
    int tid=(bx-256)*256+thr;
    int l=tid&63, ks=(tid>>6)&7, ct=(tid>>9)&63, dir=tid>>15;
    const float* Wi = dir? Wi_b : Wi_f;
    int col = ct*16 + (l&15);
    int k0  = ks*32 + (l>>4)*8;
    short v[8];
    #pragma unroll
    for(int j=0;j<8;j++) v[j]=f2b(Wi[(long)(k0+j)*FH + col]);
    *(bf16x8*)(wif + (long)tid*8) = *(bf16x8*)v;
  }else if(bx<576){                 // Wenc frags (K=512)
    int tid=(bx-512)*256+thr;
    int l=tid&63, ks=(tid>>6)&15, ct=tid>>10;
    int col = ct*16 + (l&15);
    int k0  = ks*32 + (l>>4)*8;
    short v[8];
    #pragma unroll
    for(int j=0;j<8;j++) v[j]=f2b(Wenc[(long)(k0+j)*SZ + col]);
    *(bf16x8*)(wef + (long)tid*8) = *(bf16x8*)v;
  }else{                            // Wp frags (K=300 padded to 320)
    int tid2=(bx-576)*256+thr;      // 0..10239
    int l=tid2&63, frow=tid2>>6;    // frow 0..159: ct=frow/10, ks=frow%10
    int ct=frow/10, ks=frow-ct*10;
    int col=ct*16+(l&15);
    int k0=ks*32+(l>>4)*8;
    short v[8];
    #pragma unroll
    for(int j=0;j<8;j++){ int k=k0+j; v[j]=(k<INDIM)? f2b(Wp[(long)k*SZ+col]) : (short)0; }
    *(bf16x8*)(wpf + (long)frow*512 + l*8) = *(bf16x8*)v;
  }
}

// ---- MFMA we: relu(emb@Wp + bp), 64 rows/block, K padded to 320 ------------
__global__ void k_we_mfma(const float* __restrict__ emb, const short* __restrict__ wpf,
                          const float* __restrict__ bp, float* __restrict__ we){
  __shared__ __align__(16) short As[64*328];
  int r0=blockIdx.x*64, tid=threadIdx.x, w=tid>>6, l=tid&63;
  for(int i=tid;i<64*160;i+=256){
    int lr=i/160, c2=(i-lr*160)*2;
    int row=r0+lr;
    float e0=0.f,e1=0.f;
    if(row<NW){
      if(c2<INDIM)   e0=emb[(long)row*INDIM+c2];
      if(c2+1<INDIM) e1=emb[(long)row*INDIM+c2+1];
    }
    *(int*)&As[lr*328+c2]=pack2(e0,e1);
  }
  __syncthreads();
  for(int n2=0;n2<4;n2++){
    int ct=w*4+n2;
    f32x4 Z={0.f,0.f,0.f,0.f};
    f32x4 C0=Z,C1=Z,C2=Z,C3=Z;
    #pragma unroll
    for(int ks=0;ks<10;ks++){
      bf16x8 bb=*(const bf16x8*)(wpf+((long)(ct*10+ks))*512+l*8);
      int ao=ks*32+(l>>4)*8;
      bf16x8 a0=*(const bf16x8*)(&As[((l&15)    )*328+ao]);
      bf16x8 a1=*(const bf16x8*)(&As[((l&15)+16 )*328+ao]);
      bf16x8 a2=*(const bf16x8*)(&As[((l&15)+32 )*328+ao]);
      bf16x8 a3=*(const bf16x8*)(&As[((l&15)+48 )*328+ao]);
      C0=MFA(a0,bb,C0); C1=MFA(a1,bb,C1); C2=MFA(a2,bb,C2); C3=MFA(a3,bb,C3);
    }
    int col=ct*16+(l&15);
    float be=bp[col];
    #pragma unroll
    for(int m=0;m<4;m++){
      f32x4 Cm=(m==0)?C0:(m==1)?C1:(m==2)?C2:C3;
      #pragma unroll
      for(int reg=0;reg<4;reg++){
        int row=r0+m*16+(l>>4)*4+reg;
        if(row<NW) we[(long)row*SZ+col]=fmaxf(Cm[reg]+be,0.f);
      }
    }
  }
}

// ---- MFMA xwi: epilogue writes LOG2E-scaled bf16 in LSTM frag layout -------
__global__ void k_xwi_mfma(const int* __restrict__ seq, const int* __restrict__ len,
                      const float* __restrict__ srcw, long bstride,
                      const float* __restrict__ ctxtT, const int* __restrict__ idxmap,
                      const float* __restrict__ Wi_f, const float* __restrict__ bvf,
                      const float* __restrict__ Wi_b, const float* __restrict__ bvb,
                      const short* __restrict__ wf, int iseq, short* __restrict__ xwo){
  __shared__ __align__(16) short As[64*264];
  __shared__ const float* rowp[64];
  int bx=blockIdx.x, dir=bx>>5, blk=bx&31, tid=threadIdx.x;
  int w=tid>>6, l=tid&63;
  if(tid<64){
    int t = blk*4 + (tid>>4), b = tid&15;
    int lb=len[b];
    int tt=(dir==0)? t : ((t<lb)? (lb-1-t) : t);
    int tok=seq[b*LL+tt];
    const float* rp;
    if(idxmap){
      int im=idxmap[b*NW+tok];
      rp = (im>=0)? ctxtT+(long)im*SZ : srcw+(long)tok*SZ;
    }else{
      rp = srcw + (long)b*bstride + (long)tok*SZ;
    }
    rowp[tid]=rp;
  }
  __syncthreads();
  for(int i2=tid;i2<64*64;i2+=256){
    int lr=i2>>6, c4=(i2&63)*4;
    float4 v=*(const float4*)(rowp[lr]+c4);
    int2 pk; pk.x=pack2(v.x,v.y); pk.y=pack2(v.z,v.w);
    *(int2*)&As[lr*264+c4]=pk;
  }
  __syncthreads();
  const float* __restrict__ Wi = dir? Wi_b : Wi_f;
  const float* __restrict__ bv = dir? bvb : bvf;
  const short* wfd = wf + (long)dir*262144;
  for(int n2=0;n2<16;n2++){
    int ct = w*16 + n2;
    const short* bfp = wfd + ((long)ct*8)*512 + l*8;
    f32x4 Z={0.f,0.f,0.f,0.f};
    f32x4 C0=Z,C1=Z,C2=Z,C3=Z;
    #pragma unroll
    for(int ks=0;ks<8;ks++){
      bf16x8 bb=*(const bf16x8*)(bfp + ks*512);
      int ao = ks*32 + (l>>4)*8;
      bf16x8 a0=*(const bf16x8*)(&As[((l&15)    )*264 + ao]);
      bf16x8 a1=*(const bf16x8*)(&As[((l&15)+16 )*264 + ao]);
      bf16x8 a2=*(const bf16x8*)(&As[((l&15)+32 )*264 + ao]);
      bf16x8 a3=*(const bf16x8*)(&As[((l&15)+48 )*264 + ao]);
      C0=MFA(a0,bb,C0); C1=MFA(a1,bb,C1); C2=MFA(a2,bb,C2); C3=MFA(a3,bb,C3);
    }
    int g=ct>>4, w2=(ct&15)>>1, s2=ct&1;
    int col = g*256 + w2*32 + s2*16 + (l&15);
    float be = Wi[(long)(SZ+iseq)*FH+col] + bv[col];
    #pragma unroll
    for(int m=0;m<4;m++){
      f32x4 Cm = (m==0)?C0:(m==1)?C1:(m==2)?C2:C3;
      long base=((((long)dir*128 + blk*4 + m)*8 + w2)*64 + (l>>4)*16 + (l&15))*32
                + s2*16 + g*4;
      int2 pk; pk.x=pack2(LOG2E*(Cm[0]+be),LOG2E*(Cm[1]+be));
               pk.y=pack2(LOG2E*(Cm[2]+be),LOG2E*(Cm[3]+be));
      *(int2*)(xwo+base)=pk;
    }
  }
}

// ---- 64-row scalar rowgemm tile (512 threads; fused-LSTM side blocks) ------
__device__ __forceinline__ void rowgemm64(const float* __restrict__ A,
                                          const float* __restrict__ W,
                                          float* __restrict__ C,
                                          int n, int r0, int tid, float* Asf){
  for(int i=tid;i<64*SZ;i+=512){
    int lr=i>>8; int r=r0+lr;
    Asf[i]= (r<n)? A[(long)r*SZ+(i&255)] : 0.f;
  }
  __syncthreads();
  int cl=tid&63, rg=tid>>6;
  float acc[8][4];
  #pragma unroll
  for(int i=0;i<8;i++){acc[i][0]=acc[i][1]=acc[i][2]=acc[i][3]=0.f;}
  for(int k=0;k<SZ;k+=4){
    float4 a4[8];
    #pragma unroll
    for(int i=0;i<8;i++) a4[i]=*(const float4*)&Asf[(rg*8+i)*SZ+k];
    #pragma unroll
    for(int j=0;j<4;j++){
      const float* wr=W+(long)(k+j)*SZ+cl;
      float w0=wr[0],w1=wr[64],w2=wr[128],w3=wr[192];
      #pragma unroll
      for(int i=0;i<8;i++){
        float a=(j==0)?a4[i].x:(j==1)?a4[i].y:(j==2)?a4[i].z:a4[i].w;
        acc[i][0]=fmaf(a,w0,acc[i][0]);acc[i][1]=fmaf(a,w1,acc[i][1]);
        acc[i][2]=fmaf(a,w2,acc[i][2]);acc[i][3]=fmaf(a,w3,acc[i][3]);
      }
    }
  }
  #pragma unroll
  for(int i=0;i<8;i++){
    int r=r0+rg*8+i;
    if(r<n){
      #pragma unroll
      for(int cc=0;cc<4;cc++) C[(long)r*SZ+cl+cc*64]=acc[i][cc];
    }
  }
}

// --------- fused: blocks 0,1 = LSTM; others = gemm tiles / targeted zeroing -
#define LDFW(f)    (*(const bf16x8*)(fr + (long)(f)*512 + l*8))
#define LDLW(i2,ks) (*(const bf16x8*)(bl + ((i2)*8+(ks))*512 + l*8))
#define DECLWT(T) bf16x8 W##T##_0=LDFW((T)*8+0),W##T##_1=LDFW((T)*8+1),W##T##_2=LDFW((T)*8+2),W##T##_3=LDFW((T)*8+3),W##T##_4=LDFW((T)*8+4),W##T##_5=LDFW((T)*8+5),W##T##_6=LDFW((T)*8+6),W##T##_7=LDFW((T)*8+7);
#define MMRT(T,Cv) { Cv=MFA(A0,W##T##_0,Cv); Cv=MFA(A1,W##T##_1,Cv); Cv=MFA(A2,W##T##_2,Cv); Cv=MFA(A3,W##T##_3,Cv); Cv=MFA(A4,W##T##_4,Cv); Cv=MFA(A5,W##T##_5,Cv); Cv=MFA(A6,W##T##_6,Cv); Cv=MFA(A7,W##T##_7,Cv); }
#define MMLT(i2,Cv) { Cv=MFA(A0,LDLW(i2,0),Cv); Cv=MFA(A1,LDLW(i2,1),Cv); Cv=MFA(A2,LDLW(i2,2),Cv); Cv=MFA(A3,LDLW(i2,3),Cv); Cv=MFA(A4,LDLW(i2,4),Cv); Cv=MFA(A5,LDLW(i2,5),Cv); Cv=MFA(A6,LDLW(i2,6),Cv); Cv=MFA(A7,LDLW(i2,7),Cv); }
#define MMST(Cv) { Cv=MFA(A0,S0,Cv); Cv=MFA(A1,S1,Cv); Cv=MFA(A2,S2,Cv); Cv=MFA(A3,S3,Cv); Cv=MFA(A4,S4,Cv); Cv=MFA(A5,S5,Cv); Cv=MFA(A6,S6,Cv); Cv=MFA(A7,S7,Cv); }
#define LOADST(f0) S0=LDFW((f0)+0); S1=LDFW((f0)+1); S2=LDFW((f0)+2); S3=LDFW((f0)+3); S4=LDFW((f0)+4); S5=LDFW((f0)+5); S6=LDFW((f0)+6); S7=LDFW((f0)+7);
// gates: z inputs are pre-scaled by LOG2E (Wh frags + xwi outputs)
#define G1(s,r,CA,CB,CC,CD,XA,XB) { \
  float zi=CA[r]+B2F(XA[r]), zf=CB[r]+B2F(XA[4+(r)]), zg=CC[r]+B2F(XB[r]), zo=CD[r]+B2F(XB[4+(r)]); \
  cst_##s##_##r = sigs(zf)*cst_##s##_##r + sigs(zi)*tanhs(zg); \
  float hv = sigs(zo)*tanhf_(cst_##s##_##r); \
  int b_=4*(l>>4)+(r); int u_=w*32+(s)*16+(l&15); \
  hbn[b_*264+u_]=f2b(hv); }
#define GP(s,CA,CB,CC,CD,XA,XB) \
  G1(s,0,CA,CB,CC,CD,XA,XB) G1(s,1,CA,CB,CC,CD,XA,XB) \
  G1(s,2,CA,CB,CC,CD,XA,XB) G1(s,3,CA,CB,CC,CD,XA,XB)

extern __shared__ char smem_raw[];

__global__ __launch_bounds__(512,2) void k_lstm_f(
    const short* __restrict__ frag, const short* __restrict__ xq,
    short* __restrict__ hgs,
    const float* __restrict__ gA1, const float* __restrict__ gW1,
    float* __restrict__ gC1, int n1,
    const float* __restrict__ gA2, const float* __restrict__ gW2,
    float* __restrict__ gC2, const int* __restrict__ cnt2, int ncap2,
    const int* __restrict__ zsA, const int* __restrict__ zsB,
    const int* __restrict__ u2l, float* __restrict__ lemz,
    int* __restrict__ flagz, int* __restrict__ cntz, int* __restrict__ lemcntz){
  const int bid=blockIdx.x, tid=threadIdx.x;
  if(bid>=2){
    int gb=bid-2;
    float* Asf=(float*)smem_raw;
    int nb1 = gA1 ? (n1+63)>>6 : 0;
    if(gb<nb1){ rowgemm64(gA1,gW1,gC1,n1,gb*64,tid,Asf); return; }
    gb-=nb1;
    int nb2 = gA2 ? (ncap2>>6) : 0;
    if(gb<nb2){
      int n2=*cnt2; if(n2>ncap2)n2=ncap2;
      int r0=gb*64;
      if(r0<n2) rowgemm64(gA2,gW2,gC2,n2,r0,tid,Asf);
      return;
    }
    gb-=nb2;
    if(zsA){
      if(gb<256){
        int r8=gb*8+(tid>>6); int b=r8>>7, t=r8&127;
        int lem=u2l[zsA[b*LL+t]];
        *(float4*)(lemz+((long)b*NLEM+lem)*SZ+(tid&63)*4)=make_float4(0.f,0.f,0.f,0.f);
        return;
      }
      gb-=256;
    }
    if(zsB){
      if(gb<256){
        int r8=gb*8+(tid>>6); int b=r8>>7, t=r8&127;
        int lem=u2l[zsB[b*LL+t]];
        *(float4*)(lemz+((long)b*NLEM+lem)*SZ+(tid&63)*4)=make_float4(0.f,0.f,0.f,0.f);
        return;
      }
      gb-=256;
    }
    { // flags zero (24 blocks) + counters
      int idx=gb*512+tid;
      if(idx<12000) ((int4*)flagz)[idx]=make_int4(0,0,0,0);
      if(gb==0 && tid==0 && cntz) *cntz=0;
      if(gb==0 && tid==1 && lemcntz) *lemcntz=0;
    }
    return;
  }
  const int dir=bid, w=tid>>6, l=tid&63;
  short* hb=(short*)smem_raw;                      // 2 x 16 x 264 shorts
  short* bl=(short*)(smem_raw+16896)+w*8192;       // per-wave LDS frags T2=4,5
  const short* fr = frag + (long)(dir*8+w)*32768;  // 64 frags * 512
  for(int i=tid;i<4224;i+=512) ((int*)smem_raw)[i]=0;
  #pragma unroll
  for(int c2=0;c2<16;c2++)
    *(f32x4*)(bl+c2*512+l*8) = *(const f32x4*)(fr+(long)(32+c2)*512+l*8);
  DECLWT(0) DECLWT(1) DECLWT(2) DECLWT(3)          // 32 resident frags
  float cst_0_0=0,cst_0_1=0,cst_0_2=0,cst_0_3=0,
        cst_1_0=0,cst_1_1=0,cst_1_2=0,cst_1_3=0;
  __syncthreads();
  const short* xwb = xq + ((long)dir*128*8 + w)*2048 + (long)l*32;
  short* hgb = hgs + (long)dir*524288;             // bf16 h-out [t][16][256]
  const int db=tid>>5, du=(tid&31)*8;              // dump coords
  bf16x8 S0,S1,S2,S3,S4,S5,S6,S7;
  for(int t=0;t<LL;t++){
    const int cur=t&1, nxt=cur^1;
    LOADST(48)                                     // stream T2=6 (early issue)
    const short* xp = xwb + (long)t*16384;
    bf16x8 X0=*(const bf16x8*)(xp+0), X1=*(const bf16x8*)(xp+8);
    const short* hr = hb + cur*4224 + (l&15)*264 + (l>>4)*8;
    bf16x8 A0=*(const bf16x8*)(hr+0),   A1=*(const bf16x8*)(hr+32),
           A2=*(const bf16x8*)(hr+64),  A3=*(const bf16x8*)(hr+96),
           A4=*(const bf16x8*)(hr+128), A5=*(const bf16x8*)(hr+160),
           A6=*(const bf16x8*)(hr+192), A7=*(const bf16x8*)(hr+224);
    f32x4 Z={0.f,0.f,0.f,0.f};
    f32x4 C00=Z,C01=Z,C02=Z,C03=Z,C10=Z,C11=Z,C12=Z,C13=Z;
    MMRT(0,C00) MMRT(1,C01) MMRT(2,C02) MMRT(3,C03)   // resident (32 MFMA)
    MMLT(0,C10) MMLT(1,C11)                           // LDS tiles (16 MFMA)
    MMST(C12)                                         // T2=6 streamed
    LOADST(56)                                        // stream T2=7 (issue)
    bf16x8 X2=*(const bf16x8*)(xp+16), X3=*(const bf16x8*)(xp+24);
    short* hbn = hb + nxt*4224;
    GP(0, C00,C01,C02,C03, X0,X1)                     // hides T2=7 latency
    MMST(C13)                                         // T2=7 streamed
    GP(1, C10,C11,C12,C13, X2,X3)
    __syncthreads();
    // coalesced bf16 h dump; store retires during next step (no drain stall)
    f32x4 hv4 = *(const f32x4*)(hbn + db*264 + du);
    *(f32x4*)(hgb + ((long)t*16 + db)*256 + du) = hv4;
  }
}

// ---- MFMA enc: relu(max) atomic scatter + touched-lemma list build ---------
__global__ void k_enc_mfma(const int* __restrict__ seq, const int* __restrict__ len,
                      const int* __restrict__ u2l, const short* __restrict__ hgs,
                      const short* __restrict__ wef, const float* __restrict__ benc,
                      unsigned int* __restrict__ lembuf, unsigned int* __restrict__ flags,
                      int* __restrict__ lemcnt, int* __restrict__ lemlist){
  __shared__ __align__(16) short As[64*520];
  __shared__ const short* pf16[64]; __shared__ const short* pb16[64];
  __shared__ int lem_s[64], val_s[64], b_s[64];
  int r0=blockIdx.x*64, tid=threadIdx.x, w=tid>>6, l=tid&63;
  if(tid<64){
    int r=r0+tid, b=r>>7, t=r&127, lb=len[b];
    int v=(t<lb); val_s[tid]=v; b_s[tid]=b;
    int lem=u2l[seq[r]]; lem_s[tid]=lem;
    pf16[tid]=hgs+((long)t*BB+b)*SZ;
    int tr=v? (lb-1-t) : t;
    pb16[tid]=hgs+((long)(LL+tr)*BB+b)*SZ;
    if(v){
      int fi=b*NLEM+lem;
      if(atomicExch(&flags[fi],1u)==0u){
        int pos=atomicAdd(lemcnt,1);
        if(pos<LEMCAP) lemlist[pos]=fi;     // structurally <=2048 < LEMCAP
      }
    }
  }
  __syncthreads();
  for(int i2=tid;i2<64*128;i2+=256){
    int lr=i2>>7, cc=(i2&127)*4;
    const short* sp=(cc<256)? pf16[lr]+cc : pb16[lr]+(cc-256);
    *(int2*)&As[lr*520+cc]=*(const int2*)sp;
  }
  __syncthreads();
  for(int n2=0;n2<4;n2++){
    int ct=w*4+n2;
    f32x4 Z={0.f,0.f,0.f,0.f};
    f32x4 C0=Z,C1=Z,C2=Z,C3=Z;
    #pragma unroll
    for(int ks=0;ks<16;ks++){
      bf16x8 bb=*(const bf16x8*)(wef+((long)(ct*16+ks))*512+l*8);
      int ao=ks*32+(l>>4)*8;
      bf16x8 a0=*(const bf16x8*)(&As[((l&15)    )*520+ao]);
      bf16x8 a1=*(const bf16x8*)(&As[((l&15)+16 )*520+ao]);
      bf16x8 a2=*(const bf16x8*)(&As[((l&15)+32 )*520+ao]);
      bf16x8 a3=*(const bf16x8*)(&As[((l&15)+48 )*520+ao]);
      C0=MFA(a0,bb,C0); C1=MFA(a1,bb,C1); C2=MFA(a2,bb,C2); C3=MFA(a3,bb,C3);
    }
    int col=ct*16+(l&15);
    float be=benc[col];
    #pragma unroll
    for(int m=0;m<4;m++){
      f32x4 Cm=(m==0)?C0:(m==1)?C1:(m==2)?C2:C3;
      #pragma unroll
      for(int reg=0;reg<4;reg++){
        int row=m*16+(l>>4)*4+reg;
        if(val_s[row]){
          float e=fmaxf(Cm[reg]+be,0.f);
          atomicMax(&lembuf[((long)b_s[row]*NLEM+lem_s[row])*SZ+col], __float_as_uint(e));
        }
      }
    }
  }
}

// ---- 16-row gathered rowgemm over lemlist rows: Q[rl] = lembuf[rl] @ Wg2 ---
__device__ __forceinline__ void qgemm16(const float* __restrict__ lembuf,
                                        const float* __restrict__ W,
                                        float* __restrict__ Q,
                                        const int* __restrict__ lemcnt,
                                        const int* __restrict__ lemlist,
                                        int g0, int tid, float* Asf, int* rl_s){
  int n=*lemcnt; if(n>LEMCAP)n=LEMCAP;
  int r0=g0*16;
  if(r0>=n) return;
  if(tid<16){ int i=r0+tid; rl_s[tid]=(i<n)? lemlist[i] : -1; }
  __syncthreads();
  for(int i=tid;i<16*SZ;i+=256){int lr=i>>8,j=i&(SZ-1);
    Asf[i]= (rl_s[lr]>=0)? lembuf[(long)rl_s[lr]*SZ+j] : 0.f;}
  __syncthreads();
  int cl=tid&63, rg=tid>>6;
  float acc[4][4];
  #pragma unroll
  for(int i=0;i<4;i++){acc[i][0]=acc[i][1]=acc[i][2]=acc[i][3]=0.f;}
  for(int k=0;k<SZ;k+=4){
    float4 a4[4];
    #pragma unroll
    for(int i=0;i<4;i++) a4[i]=*(const float4*)&Asf[(rg*4+i)*SZ+k];
    #pragma unroll
    for(int j=0;j<4;j++){
      const float* wr=W+(long)(k+j)*SZ+cl;
      float w0=wr[0],w1=wr[64],w2=wr[128],w3=wr[192];
      #pragma unroll
      for(int i=0;i<4;i++){
        float a=(j==0)?a4[i].x:(j==1)?a4[i].y:(j==2)?a4[i].z:a4[i].w;
        acc[i][0]=fmaf(a,w0,acc[i][0]);acc[i][1]=fmaf(a,w1,acc[i][1]);
        acc[i][2]=fmaf(a,w2,acc[i][2]);acc[i][3]=fmaf(a,w3,acc[i][3]);
      }
    }
  }
  #pragma unroll
  for(int i=0;i<4;i++){
    int rl=rl_s[rg*4+i];
    if(rl>=0){
      #pragma unroll
      for(int cc=0;cc<4;cc++) Q[(long)rl*SZ+cl+cc*64]=acc[i][cc];
    }
  }
}

// ---- merged post-enc kernel: [Q-gemm | compact | base0ip] sections.
// base0ip is safe here now: gate0c reconstructs original we by division. -----
__global__ void k_mid(const float* __restrict__ lembuf, const float* __restrict__ Wg2,
                      float* __restrict__ Q, const int* __restrict__ lemcnt,
                      const int* __restrict__ lemlist,
                      const int* __restrict__ u2l, const unsigned int* __restrict__ flags,
                      int* __restrict__ cnt, int* __restrict__ list,
                      int* __restrict__ idxmap, int docompact,
                      float* __restrict__ we, const float* __restrict__ P0,
                      const float* __restrict__ bg, int dobase){
  __shared__ __align__(16) float Asf[16*SZ];
  __shared__ int rl_s[16];
  int bx=blockIdx.x, tid=threadIdx.x;
  if(bx<LEMCAP/16){           // Q section: 256 blocks
    qgemm16(lembuf,Wg2,Q,lemcnt,lemlist,bx,tid,Asf,rl_s);
    return;
  }
  bx-=LEMCAP/16;
  if(docompact){
    if(bx<625){               // compact section
      int r=bx*256+tid;
      if(r<BB*NW){
        int b=r/NW, w2=r-b*NW;
        int im=-1;
        if(flags[(long)b*NLEM+u2l[w2]]){
          int idx=atomicAdd(cnt,1);
          if(idx<NCAP){ list[idx]=r; im=idx; }
        }
        idxmap[r]=im;
      }
      return;
    }
    bx-=625;
  }
  if(dobase){                 // base0ip section: 2500 blocks (we <- we*sig(P0+bg))
    long idx=(long)bx*256+tid;
    if(idx<(long)NW*SZ/4){
      int k4=(int)(idx&63);
      float4 wv=((float4*)we)[idx];
      float4 p =((const float4*)P0)[idx];
      float4 bgv=((const float4*)bg)[k4];
      wv.x*=sigf(p.x+bgv.x); wv.y*=sigf(p.y+bgv.y);
      wv.z*=sigf(p.z+bgv.z); wv.w*=sigf(p.w+bgv.w);
      ((float4*)we)[idx]=wv;
    }
  }
}

// ---- gate for touched-only rows -> compact ctxtT.
// `base0` holds we*sig(P0+bg); reconstruct we = base0 * rcp(sig(P0+bg)) ------
__global__ void k_gate0c(const float* __restrict__ base0, const float* __restrict__ P0,
                         const float* __restrict__ Q, const float* __restrict__ lembuf,
                         const int* __restrict__ u2l, const float* __restrict__ bg,
                         const int* __restrict__ cnt, const int* __restrict__ list,
                         float* __restrict__ ctxtT, int ncap){
  int n=*cnt; if(n>ncap)n=ncap;
  long idx=(long)blockIdx.x*256+threadIdx.x;
  long i=idx>>6; int k4=(int)(idx&63);
  if(i>=n) return;
  int r=list[i]; int b=r/NW, w=r-b*NW;
  int lem=u2l[w];
  long qb=((long)b*NLEM+lem)*SZ;
  float4 p =((const float4*)(P0+(long)w*SZ))[k4];
  float4 b0=((const float4*)(base0+(long)w*SZ))[k4];
  float4 bgv=((const float4*)bg)[k4];
  float4 q =((const float4*)(Q+qb))[k4];
  float4 nw=((const float4*)(lembuf+qb))[k4];
  // reconstruct original we (exact same sigf bits as base0ip used)
  float4 wv;
  wv.x=b0.x*__builtin_amdgcn_rcpf(fmaxf(sigf(p.x+bgv.x),1e-30f));
  wv.y=b0.y*__builtin_amdgcn_rcpf(fmaxf(sigf(p.y+bgv.y),1e-30f));
  wv.z=b0.z*__builtin_amdgcn_rcpf(fmaxf(sigf(p.z+bgv.z),1e-30f));
  wv.w=b0.w*__builtin_amdgcn_rcpf(fmaxf(sigf(p.w+bgv.w),1e-30f));
  float4 o;
  { float g=sigf(p.x+q.x+bgv.x); o.x=wv.x*g+(1.f-g)*nw.x; }
  { float g=sigf(p.y+q.y+bgv.y); o.y=wv.y*g+(1.f-g)*nw.y; }
  { float g=sigf(p.z+q.z+bgv.z); o.z=wv.z*g+(1.f-g)*nw.z; }
  { float g=sigf(p.w+q.w+bgv.w); o.w=wv.w*g+(1.f-g)*nw.w; }
  ((float4*)ctxtT)[i*64+k4]=o;
}

// ------- iter-0 gate DENSE (fallback): full out write -----------------------
__global__ void k_gate0(const float* __restrict__ we, const float* __restrict__ P0,
                        const float* __restrict__ Q, const float* __restrict__ lembuf,
                        const int* __restrict__ u2l, const unsigned int* __restrict__ flags,
                        const float* __restrict__ bg, float* __restrict__ out){
  long idx=(long)blockIdx.x*256+threadIdx.x;
  const long TOTAL4=(long)BB*NW*SZ/4;
  if(idx>=TOTAL4) return;
  long row=idx>>6; int k4=(int)(idx&63);
  int r32=(int)row;
  int b=r32/NW, w=r32-b*NW;
  int lem=u2l[w];
  long qb=((long)b*NLEM+lem)*SZ;
  unsigned int fl=flags[(long)b*NLEM+lem];
  float4 p =((const float4*)(P0+(long)w*SZ))[k4];
  float4 wv=((const float4*)(we+(long)w*SZ))[k4];
  float4 bgv=((const float4*)bg)[k4];
  float4 q, nw;
  if(fl){ q=((const float4*)(Q+qb))[k4]; nw=((const float4*)(lembuf+qb))[k4]; }
  else  { q=make_float4(0.f,0.f,0.f,0.f); nw=q; }
  float4 o;
  { float g=sigf(p.x+q.x+bgv.x); o.x=wv.x*g+(1.f-g)*nw.x; }
  { float g=sigf(p.y+q.y+bgv.y); o.y=wv.y*g+(1.f-g)*nw.y; }
  { float g=sigf(p.z+q.z+bgv.z); o.z=wv.z*g+(1.f-g)*nw.z; }
  { float g=sigf(p.w+q.w+bgv.w); o.w=wv.w*g+(1.f-g)*nw.w; }
  ((float4*)out)[idx]=o;
}

// ------- iter-1 gate: cv from base0/ctxtT, p from P1b/Pt, write final out ---
__global__ void k_gate1e(const float* __restrict__ base0, const float* __restrict__ ctxtT,
                         const float* __restrict__ P1b, const float* __restrict__ Pt,
                         const int* __restrict__ idxmap,
                         const float* __restrict__ Q, const float* __restrict__ lembuf,
                         const int* __restrict__ u2l, const unsigned int* __restrict__ flags,
                         const float* __restrict__ bg, float* __restrict__ out){
  long idx=(long)blockIdx.x*256+threadIdx.x;
  const long TOTAL4=(long)BB*NW*SZ/4;
  if(idx>=TOTAL4) return;
  long row=idx>>6; int k4=(int)(idx&63);
  int r32=(int)row;
  int b=r32/NW, w=r32-b*NW;
  int im=idxmap[r32];
  int lem=u2l[w];
  long qb=((long)b*NLEM+lem)*SZ;
  unsigned int fl=flags[(long)b*NLEM+lem];
  float4 p, cv;
  if(im>=0){ p=((const float4*)(Pt+(long)im*SZ))[k4]; cv=((const float4*)(ctxtT+(long)im*SZ))[k4]; }
  else     { p=((const float4*)(P1b+(long)w*SZ))[k4]; cv=((const float4*)(base0+(long)w*SZ))[k4]; }
  float4 bgv=((const float4*)bg)[k4];
  float4 q, nw;
  if(fl){ q=((const float4*)(Q+qb))[k4]; nw=((const float4*)(lembuf+qb))[k4]; }
  else  { q=make_float4(0.f,0.f,0.f,0.f); nw=q; }
  float4 o;
  { float g=sigf(p.x+q.x+bgv.x); o.x=cv.x*g+(1.f-g)*nw.x; }
  { float g=sigf(p.y+q.y+bgv.y); o.y=cv.y*g+(1.f-g)*nw.y; }
  { float g=sigf(p.z+q.z+bgv.z); o.z=cv.z*g+(1.f-g)*nw.z; }
  { float g=sigf(p.w+q.w+bgv.w); o.w=cv.w*g+(1.f-g)*nw.w; }
  ((float4*)out)[idx]=o;
}

// ------- legacy dense iter-1 gate (fallback if ws too small) ----------------
__global__ void k_gate1(const float* __restrict__ ctxt, const float* __restrict__ Wg,
                        const float* __restrict__ Q, const float* __restrict__ lembuf,
                        const int* __restrict__ u2l, const unsigned int* __restrict__ flags,
                        const float* __restrict__ bg, float* __restrict__ out){
  __shared__ __align__(16) float As[64][SZ];
  __shared__ __align__(16) float Ws[64][SZ];
  __shared__ int lem_s[64];
  int r0=blockIdx.x*64, tid=threadIdx.x;
  for(int i=tid;i<64*SZ;i+=256){int lr=i>>8,j=i&(SZ-1);
    As[lr][j]=ctxt[(long)(r0+lr)*SZ+j];}
  if(tid<64){int r=r0+tid; lem_s[tid]=u2l[r%NW];}
  int cl=tid&63, rg=tid>>6;
  float acc[16][4];
  #pragma unroll
  for(int i=0;i<16;i++){acc[i][0]=acc[i][1]=acc[i][2]=acc[i][3]=0.f;}
  for(int kb=0;kb<4;kb++){
    __syncthreads();
    for(int i=tid;i<64*SZ;i+=256){int lr=i>>8,j=i&(SZ-1);
      Ws[lr][j]=Wg[(long)(kb*64+lr)*SZ+j];}
    __syncthreads();
    for(int k=0;k<64;k+=4){
      float4 a4[16];
      #pragma unroll
      for(int i=0;i<16;i++) a4[i]=*(const float4*)&As[rg*16+i][kb*64+k];
      #pragma unroll
      for(int j=0;j<4;j++){
        float w0=Ws[k+j][cl],w1=Ws[k+j][cl+64],w2=Ws[k+j][cl+128],w3=Ws[k+j][cl+192];
        #pragma unroll
        for(int i=0;i<16;i++){
          float a=(j==0)?a4[i].x:(j==1)?a4[i].y:(j==2)?a4[i].z:a4[i].w;
          acc[i][0]=fmaf(a,w0,acc[i][0]);acc[i][1]=fmaf(a,w1,acc[i][1]);
          acc[i][2]=fmaf(a,w2,acc[i][2]);acc[i][3]=fmaf(a,w3,acc[i][3]);
        }
      }
    }
  }
  #pragma unroll
  for(int i=0;i<16;i++){
    int lr=rg*16+i, r=r0+lr, b=r/NW;
    long base=((long)b*NLEM+lem_s[lr])*SZ;
    unsigned int fl=flags[(long)b*NLEM+lem_s[lr]];
    #pragma unroll
    for(int cc=0;cc<4;cc++){
      int col=cl+cc*64;
      float qv=0.f, nw=0.f;
      if(fl){ qv=Q[base+col]; nw=lembuf[base+col]; }
      float g=sigf(acc[i][cc]+qv+bg[col]);
      out[(long)r*SZ+col]=As[lr][col]*g+(1.f-g)*nw;
    }
  }
}

extern "C" void kernel_launch(void* const* d_in, const int* in_sizes, int n_in,
                              void* d_out, int out_size, void* d_ws, size_t ws_size,
                              hipStream_t stream){
  const float* emb  =(const float*)d_in[0];
  const float* Wp   =(const float*)d_in[1];
  const float* bp   =(const float*)d_in[2];
  const float* Wi_f =(const float*)d_in[3];
  const float* Wh_f =(const float*)d_in[4];
  const float* b_f  =(const float*)d_in[5];
  const float* Wi_b =(const float*)d_in[6];
  const float* Wh_b =(const float*)d_in[7];
  const float* b_b  =(const float*)d_in[8];
  const float* Wenc =(const float*)d_in[9];
  const float* benc =(const float*)d_in[10];
  const float* Wg   =(const float*)d_in[11];
  const float* bg   =(const float*)d_in[12];
  const int*   seq0 =(const int*)d_in[13];
  const int*   seq1 =(const int*)d_in[14];
  const int*   len0 =(const int*)d_in[15];
  const int*   len1 =(const int*)d_in[16];
  const int*   u2l  =(const int*)d_in[17];

  float* ws    = (float*)d_ws;
  float* we    = ws;                       // 2,560,000 (becomes base0 after iter0)
  float* xwi   = we    + 2560000;          // region 4,194,304 floats:
  float* ctxtT = xwi   + 2097152;          //   xq bf16 first half; ctxtT second
  float* hglob = xwi   + 4194304;          // 1,048,576 (bf16 h uses half)
  float* lembuf= hglob + 1048576;          // 12,288,000
  float* flags = lembuf+ 12288000;         // 48,000 (uint)
  float* Q     = flags + 48000;            // 12,288,000
  float* P0    = Q     + 12288000;         // 2,560,000 (becomes P1b after iter0)
  short* whb   = (short*)(P0 + 2560000);   // 524,288 shorts = 262,144 floats
  short* wifrag= whb + 524288;             // 524,288 shorts = 262,144 floats
  short* wefrag= wifrag + 524288;          // 131,072 shorts = 65,536 floats
  short* wpfrag= wefrag + 131072;          // 81,920 shorts = 40,960 floats
  int*   idxmap= (int*)(P0 + 2560000 + 262144 + 262144 + 65536 + 40960); // 160,000
  int*   list  = idxmap + 160000;          // NCAP
  int*   cnt   = list + NCAP;              // 1
  int*   lemcnt= cnt + 1;                  // 1 (+2 pad)
  int*   lemlist=cnt + 4;                  // LEMCAP
  float* Ptouch= (float*)(lemlist + LEMCAP); // NCAP*256
  long base_floats = (long)(Ptouch - ws);
  long avail = ((long)(ws_size/4) - base_floats)/SZ;
  int sparse_ok = (avail >= NCAP);
  float* out   = (float*)d_out;

  hipFuncSetAttribute((const void*)k_lstm_f,
                      hipFuncAttributeMaxDynamicSharedMemorySize, 147968);

  k_prepall<<<616,256,0,stream>>>(Wh_f,Wh_b,whb, Wi_f,Wi_b,wifrag,
                                  Wenc,wefrag, Wp,wpfrag);
  k_we_mfma<<<NB1,256,0,stream>>>(emb,wpfrag,bp,we);

  // ---------------- iteration 0 ----------------
  k_xwi_mfma<<<64,256,0,stream>>>(seq0,len0,we,0L,nullptr,nullptr,
                                  Wi_f,b_f,Wi_b,b_b,wifrag,0,(short*)xwi);
  // LSTM0 || P0=we@Wg1 || zero lembuf(seq0 rows) || zero flags+cnt+lemcnt
  k_lstm_f<<<2+NB1+256+24,512,147968,stream>>>(whb,(const short*)xwi,(short*)hglob,
      we,Wg,P0,NW, nullptr,nullptr,nullptr,nullptr,0,
      seq0,nullptr,u2l,lembuf,(int*)flags,cnt,lemcnt);
  k_enc_mfma<<<BB*LL/64,256,0,stream>>>(seq0,len0,u2l,(const short*)hglob,wefrag,benc,
                                        (unsigned int*)lembuf,(unsigned int*)flags,
                                        lemcnt,lemlist);
  if(sparse_ok){
    // Q(lemlist) || compact || base0ip (gate0c reconstructs we by division)
    k_mid<<<LEMCAP/16+625+2500,256,0,stream>>>(lembuf,Wg+(long)SZ*SZ,Q,lemcnt,lemlist,
        u2l,(const unsigned int*)flags,cnt,list,idxmap,1, we,P0,bg,1);
    k_gate0c<<<NCAP*64/256,256,0,stream>>>(we,P0,Q,lembuf,u2l,bg,cnt,list,ctxtT,NCAP);
  }else{
    k_mid<<<LEMCAP/16,256,0,stream>>>(lembuf,Wg+(long)SZ*SZ,Q,lemcnt,lemlist,
        u2l,nullptr,nullptr,nullptr,nullptr,0, nullptr,nullptr,nullptr,0);
    long nb=((long)BB*NW*SZ/4+255)/256;
    k_gate0<<<(int)nb,256,0,stream>>>(we,P0,Q,lembuf,u2l,
                                      (const unsigned int*)flags,bg,out);
  }

  // ---------------- iteration 1 ----------------
  if(sparse_ok){
    k_xwi_mfma<<<64,256,0,stream>>>(seq1,len1,we,0L,ctxtT,idxmap,
                                    Wi_f,b_f,Wi_b,b_b,wifrag,1,(short*)xwi);
    // LSTM1 || P0<-base0@Wg1 || Ptouch<-ctxtT@Wg1 || zero lembuf(seq0+seq1)+flags+lemcnt
    k_lstm_f<<<2+NB1+NCAP/64+256+256+24,512,147968,stream>>>(whb,(const short*)xwi,
        (short*)hglob, we,Wg,P0,NW, ctxtT,Wg,Ptouch,cnt,NCAP,
        seq0,seq1,u2l,lembuf,(int*)flags,nullptr,lemcnt);
  }else{
    k_xwi_mfma<<<64,256,0,stream>>>(seq1,len1,out,(long)NW*SZ,nullptr,nullptr,
                                    Wi_f,b_f,Wi_b,b_b,wifrag,1,(short*)xwi);
    k_lstm_f<<<2+256+256+24,512,147968,stream>>>(whb,(const short*)xwi,(short*)hglob,
        nullptr,nullptr,nullptr,0, nullptr,nullptr,nullptr,nullptr,0,
        seq0,seq1,u2l,lembuf,(int*)flags,nullptr,lemcnt);
  }
  k_enc_mfma<<<BB*LL/64,256,0,stream>>>(seq1,len1,u2l,(const short*)hglob,wefrag,benc,
                                        (unsigned int*)lembuf,(unsigned int*)flags,
                                        lemcnt,lemlist);
  k_mid<<<LEMCAP/16,256,0,stream>>>(lembuf,Wg+(long)SZ*SZ,Q,lemcnt,lemlist,
      u2l,nullptr,nullptr,nullptr,nullptr,0, nullptr,nullptr,nullptr,0);
  if(sparse_ok){
    long nb=((long)BB*NW*SZ/4+255)/256;
    k_gate1e<<<(int)nb,256,0,stream>>>(we,ctxtT,P0,Ptouch,idxmap,Q,lembuf,u2l,
                                       (const unsigned int*)flags,bg,out);
  }else{
    k_gate1<<<BB*NW/64,256,0,stream>>>(out,Wg,Q,lembuf,u2l,
                                       (const unsigned int*)flags,bg,out);
  }
}